// Round 23
// baseline (137.229 us; speedup 1.0000x reference)
//
#include <hip/hip_runtime.h>
#include <cmath>

#define ROWS      16384
#define SEQLEN    8192
#define BATCH     2
#define NHEADS    24
#define HEADDIM   16
#define D_STATE   16
#define D_INNER   384
#define D_MODEL   192
#define D_IN_PROJ 808
#define CONV_DIM  400
#define NCHUNKS   32
#define CHUNK     256
#define EPS       1e-5f
#define LOG2E     1.44269504088896f

typedef short bf16x8 __attribute__((ext_vector_type(8)));
typedef short bf16x4 __attribute__((ext_vector_type(4)));
typedef float f32x4  __attribute__((ext_vector_type(4)));
typedef unsigned short us4v __attribute__((ext_vector_type(4)));
typedef unsigned short us8v __attribute__((ext_vector_type(8)));
typedef unsigned int  u32x4 __attribute__((ext_vector_type(4)));

#if __has_builtin(__builtin_amdgcn_mfma_f32_16x16x16bf16_1k)
#define MFMA16(a, b, c) __builtin_amdgcn_mfma_f32_16x16x16bf16_1k((a), (b), (c), 0, 0, 0)
#define HAVE_MFMA16 1
#elif __has_builtin(__builtin_amdgcn_mfma_f32_16x16x16_bf16)
#define MFMA16(a, b, c) __builtin_amdgcn_mfma_f32_16x16x16_bf16((a), (b), (c), 0, 0, 0)
#define HAVE_MFMA16 1
#else
#define HAVE_MFMA16 0
#endif

__device__ __forceinline__ float silu_f(float x) { return x / (1.0f + expf(-x)); }
__device__ __forceinline__ float softplus_f(float x) { return (x > 20.0f) ? x : log1pf(expf(x)); }
__device__ __forceinline__ unsigned short f2bf(float x) {
  unsigned u = __builtin_bit_cast(unsigned, x);
  u += 0x7fff + ((u >> 16) & 1);
  return (unsigned short)(u >> 16);
}
__device__ __forceinline__ float bf2f(unsigned short s) {
  unsigned u = (unsigned)s << 16;
  return __builtin_bit_cast(float, u);
}
__device__ __forceinline__ unsigned pk_bf(float a, float b) {
  unsigned ua = __builtin_bit_cast(unsigned, a) + 0x7fffu;
  unsigned ub = __builtin_bit_cast(unsigned, b) + 0x7fffu;
  return __builtin_amdgcn_perm(ub, ua, 0x07060302u);
}

// ---------------------------------------------------------------------------
// K0: fp32 -> bf16 weights (W_in, W_out, W_in_b)
// ---------------------------------------------------------------------------
__global__ __launch_bounds__(256)
void cvt3_kernel(const float* __restrict__ a, unsigned short* __restrict__ ao, long na,
                 const float* __restrict__ b, unsigned short* __restrict__ bo, long nb,
                 const float* __restrict__ c, unsigned short* __restrict__ co, long nc) {
  const long t0 = na >> 2, t1 = t0 + (nb >> 2), t2 = t1 + (nc >> 2);
  const long stride = (long)gridDim.x * blockDim.x;
  for (long i = (long)blockIdx.x * blockDim.x + threadIdx.x; i < t2; i += stride) {
    const float4* s; us4v* d; long j;
    if (i < t0)      { s = (const float4*)a; d = (us4v*)ao; j = i; }
    else if (i < t1) { s = (const float4*)b; d = (us4v*)bo; j = i - t0; }
    else             { s = (const float4*)c; d = (us4v*)co; j = i - t1; }
    float4 v = s[j];
    us4v o = { f2bf(v.x), f2bf(v.y), f2bf(v.z), f2bf(v.w) };
    d[j] = o;
  }
}

// ---------------------------------------------------------------------------
// MFMA bf16 GEMM. ROUTE=true: in-proj output split into consumer-native dense
// buffers (z->zbuf, x->head-major xT, Braw, draw).
// ---------------------------------------------------------------------------
template<bool A_F32, bool OUT_BF16, bool ROUTE>
__launch_bounds__(256, 3)
__global__ void gemm_bf16(const void* __restrict__ Ap,
                          const unsigned short* __restrict__ W,
                          void* __restrict__ Cp, int M, int N, int K,
                          unsigned short* __restrict__ zbuf,
                          unsigned short* __restrict__ xT,
                          unsigned short* __restrict__ Braw,
                          unsigned short* __restrict__ draw) {
  constexpr int BM = 128, BN = 128, BK = 32, LDK = 40;
  __shared__ unsigned short As[2][BM * LDK];
  __shared__ unsigned short Ws[2][BN * LDK];
  const int tid  = threadIdx.x;
  const int wid  = tid >> 6, lane = tid & 63;
  const int wr   = wid >> 1, wc = wid & 1;
  const int fr   = lane & 15, fq = lane >> 4;
  const long m0  = (long)blockIdx.y * BM;
  const int  n0  = blockIdx.x * BN;

  f32x4 acc[4][4] = {};

  auto stage = [&](int k0, int buf) {
    if (A_F32) {
      const float* A = (const float*)Ap;
#pragma unroll
      for (int p = 0; p < 2; ++p) {
        int flat = p * 2048 + tid * 8;
        int r = flat >> 5, c = flat & 31;
        const float4* src = (const float4*)(A + (m0 + r) * (long)K + k0 + c);
        float4 v0 = src[0], v1 = src[1];
        us8v o = { f2bf(v0.x), f2bf(v0.y), f2bf(v0.z), f2bf(v0.w),
                   f2bf(v1.x), f2bf(v1.y), f2bf(v1.z), f2bf(v1.w) };
        *(us8v*)&As[buf][r * LDK + c] = o;
      }
    } else {
      const unsigned short* A = (const unsigned short*)Ap;
#pragma unroll
      for (int p = 0; p < 2; ++p) {
        int flat = p * 2048 + tid * 8;
        int r = flat >> 5, c = flat & 31;
        us8v v = *(const us8v*)(A + (m0 + r) * (long)K + k0 + c);
        *(us8v*)&As[buf][r * LDK + c] = v;
      }
    }
#pragma unroll
    for (int p = 0; p < 2; ++p) {
      int flat = p * 2048 + tid * 8;
      int r = flat >> 5, c = flat & 31;
      int gn = n0 + r;
      us8v v = { 0, 0, 0, 0, 0, 0, 0, 0 };
      if (gn < N) v = *(const us8v*)(W + (long)gn * K + k0 + c);
      *(us8v*)&Ws[buf][r * LDK + c] = v;
    }
  };

  const int nk = K / BK;
  stage(0, 0);
  __syncthreads();
  for (int kt = 0; kt < nk; ++kt) {
    const int cur = kt & 1;
    if (kt + 1 < nk) stage((kt + 1) * BK, cur ^ 1);
    bf16x8 af[4], bfr[4];
#pragma unroll
    for (int m = 0; m < 4; ++m)
      af[m] = *(const bf16x8*)&As[cur][(wr * 64 + m * 16 + fr) * LDK + fq * 8];
#pragma unroll
    for (int n = 0; n < 4; ++n)
      bfr[n] = *(const bf16x8*)&Ws[cur][(wc * 64 + n * 16 + fr) * LDK + fq * 8];
#pragma unroll
    for (int m = 0; m < 4; ++m)
#pragma unroll
      for (int n = 0; n < 4; ++n)
        acc[m][n] = __builtin_amdgcn_mfma_f32_16x16x32_bf16(bfr[n], af[m], acc[m][n], 0, 0, 0);
    __syncthreads();
  }

#pragma unroll
  for (int m = 0; m < 4; ++m) {
    const long gm = m0 + wr * 64 + m * 16 + fr;
#pragma unroll
    for (int n = 0; n < 4; ++n) {
      const int gn = n0 + wc * 64 + n * 16 + fq * 4;
      if (gn < N) {
        if (ROUTE) {
          us4v o = { f2bf(acc[m][n][0]), f2bf(acc[m][n][1]),
                     f2bf(acc[m][n][2]), f2bf(acc[m][n][3]) };
          const int bb = (int)(gm >> 13);
          const long t = gm & 8191;
          if (gn < 384) {
            *(us4v*)(zbuf + gm * 384 + gn) = o;
          } else if (gn < 768) {
            const int c = gn - 384, hh = c >> 4, ii = c & 15;
            *(us4v*)(xT + (((size_t)(bb * NHEADS + hh) * SEQLEN + t) << 4) + ii) = o;
          } else if (gn < 784) {
            *(us4v*)(Braw + gm * 16 + (gn - 768)) = o;
          } else {
            *(us4v*)(draw + gm * 24 + (gn - 784)) = o;
          }
        } else if (OUT_BF16) {
          us4v o = { f2bf(acc[m][n][0]), f2bf(acc[m][n][1]),
                     f2bf(acc[m][n][2]), f2bf(acc[m][n][3]) };
          *(us4v*)((unsigned short*)Cp + gm * N + gn) = o;
        } else {
          float4 o = make_float4(acc[m][n][0], acc[m][n][1], acc[m][n][2], acc[m][n][3]);
          *(float4*)((float*)Cp + gm * N + gn) = o;
        }
      }
    }
  }
}

// ---------------------------------------------------------------------------
// K2: B/C conv + dt softplus, dense raw buffers. 448 role-pure blocks.
// ---------------------------------------------------------------------------
#define CBC_NB  (ROWS * 4 / 256)    // 256
#define CDT_NB  (ROWS * 3 / 256)    // 192

__global__ __launch_bounds__(256)
void conv_bcdt(const unsigned short* __restrict__ Braw, const unsigned short* __restrict__ craw,
               const unsigned short* __restrict__ draw,
               const float* __restrict__ conv_w, const float* __restrict__ conv_b,
               const float* __restrict__ conv_w_b, const float* __restrict__ conv_b_b,
               const float* __restrict__ dt_bias,
               unsigned short* __restrict__ Bo, unsigned short* __restrict__ Co,
               float* __restrict__ dtoT) {
  const int blk = blockIdx.x;
  const us8v z8 = { 0, 0, 0, 0, 0, 0, 0, 0 };

  if (blk < CBC_NB) {
    const int idx = blk * 256 + threadIdx.x;
    const int row = idx / 4, q = idx % 4;
    const int b = row / SEQLEN, t = row % SEQLEN;

    const unsigned short* src = (q < 2) ? Braw : craw;
    const float* cw = (q < 2) ? conv_w + 384 * 4 : conv_w_b;
    const float* cb = (q < 2) ? conv_b + 384 : conv_b_b;
    const int c0 = (q & 1) * 8;
    const unsigned short* base = src + (size_t)row * D_STATE + c0;
    us8v x0 = (t >= 3) ? *(const us8v*)(base - 3 * D_STATE) : z8;
    us8v x1 = (t >= 2) ? *(const us8v*)(base - 2 * D_STATE) : z8;
    us8v x2 = (t >= 1) ? *(const us8v*)(base - 1 * D_STATE) : z8;
    us8v x3 = *(const us8v*)base;
    us8v o;
#pragma unroll
    for (int ch = 0; ch < 8; ++ch) {
      const float4 wv = *(const float4*)(cw + (c0 + ch) * 4);
      float acc = cb[c0 + ch] + wv.x * bf2f(x0[ch]) + wv.y * bf2f(x1[ch])
                + wv.z * bf2f(x2[ch]) + wv.w * bf2f(x3[ch]);
      o[ch] = f2bf(silu_f(acc));
    }
    if (q < 2) *(us8v*)(Bo + (size_t)row * D_STATE + c0) = o;
    else       *(us8v*)(Co + (size_t)row * D_STATE + c0) = o;
  } else {
    const int idx = (blk - CBC_NB) * 256 + threadIdx.x;
    const int row = idx / 3, q = idx % 3;
    const int b = row / SEQLEN, t = row % SEQLEN;
    const int h0 = q * 8;
    us8v dv = *(const us8v*)(draw + (size_t)row * 24 + h0);
#pragma unroll
    for (int j = 0; j < 8; ++j) {
      float v = bf2f(dv[j]) + dt_bias[h0 + j];
      dtoT[(size_t)(b * NHEADS + h0 + j) * SEQLEN + t] = softplus_f(v);
    }
  }
}

// ---------------------------------------------------------------------------
// K3 (MFMA, 8 waves, fused x-conv, factored decay, K16 PV): unchanged.
// ---------------------------------------------------------------------------
__global__ __launch_bounds__(512, 4)
void ssd_mfma_kernel(const unsigned short* __restrict__ xT, const unsigned short* __restrict__ Bo,
                     const unsigned short* __restrict__ Co, const float* __restrict__ dtoT,
                     const float* __restrict__ A_log, const float* __restrict__ conv_w,
                     const float* __restrict__ conv_b, const float* __restrict__ Dvec,
                     unsigned short* __restrict__ YdT, float* __restrict__ acum_g,
                     float* __restrict__ csum_g, float* __restrict__ stloc) {
  const int h    = blockIdx.x;
  const int cidx = blockIdx.y;
  const int b    = blockIdx.z;
  const int tid  = threadIdx.x;
  const int wid  = tid >> 6, lane = tid & 63;
  const int fr   = lane & 15, g = lane >> 4;

  __shared__ unsigned short Bs[256 * 24 + 32];
  __shared__ unsigned short xsT[16 * 264];
  __shared__ unsigned short BwT[16 * 264];
  __shared__ unsigned short xraw[259 * 16 + 8];
  __shared__ float sc2[CHUNK];
  __shared__ float scE[16];
  __shared__ float wsum[4];

  const float Ah = -expf(A_log[h]);
  const us8v z8 = { 0, 0, 0, 0, 0, 0, 0, 0 };

  float v = 0.f;
  if (tid < CHUNK) {
    v = dtoT[(size_t)(b * NHEADS + h) * SEQLEN + (size_t)cidx * CHUNK + tid] * Ah;
#pragma unroll
    for (int off = 1; off < 64; off <<= 1) {
      float u = __shfl_up(v, off, 64);
      if (lane >= off) v += u;
    }
    if (lane == 63) wsum[wid] = v;
  }

  const int r  = tid >> 1;
  const int hf = tid & 1;
  const size_t rowbase = (size_t)b * SEQLEN + (size_t)cidx * CHUNK;
  const size_t rhrow = (size_t)(b * NHEADS + h) * SEQLEN + (size_t)cidx * CHUNK + r;
  const float rdtv = dtoT[rhrow];
  us8v bh = ((const us8v*)(Bo + (rowbase + r) * D_STATE))[hf];
  if (hf == 0) *(us8v*)&Bs[r * 24 + 16] = z8;
  if (tid < 32) Bs[256 * 24 + tid] = 0;
  {
    const int tg = cidx * CHUNK + r - 3;
    us8v xv = z8;
    if (tg >= 0)
      xv = *(const us8v*)(xT + (((size_t)(b * NHEADS + h) * SEQLEN + tg) << 4) + 8 * hf);
    *(us8v*)&xraw[r * 16 + 8 * hf] = xv;
    if (tid < 6) {
      const int rr2 = 256 + (tid >> 1);
      const int hf2 = tid & 1;
      const int tg2 = cidx * CHUNK + rr2 - 3;
      us8v xv2 = *(const us8v*)(xT + (((size_t)(b * NHEADS + h) * SEQLEN + tg2) << 4) + 8 * hf2);
      *(us8v*)&xraw[rr2 * 16 + 8 * hf2] = xv2;
    }
  }
  __syncthreads();   // #1

  us8v xsil, xdt8;
  {
    us8v tA = *(const us8v*)&xraw[(r + 0) * 16 + 8 * hf];
    us8v tB = *(const us8v*)&xraw[(r + 1) * 16 + 8 * hf];
    us8v tC = *(const us8v*)&xraw[(r + 2) * 16 + 8 * hf];
    us8v tD = *(const us8v*)&xraw[(r + 3) * 16 + 8 * hf];
    const int cbase = h * HEADDIM + 8 * hf;
#pragma unroll
    for (int ch = 0; ch < 8; ++ch) {
      const float4 wv = *(const float4*)(conv_w + (cbase + ch) * 4);
      float acc = conv_b[cbase + ch] + wv.x * bf2f(tA[ch]) + wv.y * bf2f(tB[ch])
                + wv.z * bf2f(tC[ch]) + wv.w * bf2f(tD[ch]);
      float sv = silu_f(acc);
      xsil[ch] = f2bf(sv);
      xdt8[ch] = f2bf(sv * rdtv);
    }
  }
  const float ctot  = wsum[0] + wsum[1] + wsum[2] + wsum[3];
  const float ctot2 = ctot * LOG2E;
  if (tid < CHUNK) {
    float pre = 0.f;
#pragma unroll
    for (int w = 0; w < 4; ++w) if (w < wid) pre += wsum[w];
    v += pre;
    sc2[tid] = v * LOG2E;
    acum_g[(size_t)(b * NHEADS + h) * SEQLEN + (size_t)cidx * CHUNK + tid] = v;
    if (tid == CHUNK - 1) csum_g[(b * NHEADS + h) * NCHUNKS + cidx] = v;
  }
  __syncthreads();   // #2

  *(us8v*)&xraw[(r + 3) * 16 + 8 * hf] = xsil;
#pragma unroll
  for (int q = 0; q < 8; ++q)
    xsT[(q + 8 * hf) * 264 + r] = xdt8[q];
  {
    const float wdv = exp2f(ctot2 - sc2[r]);
    const float ed  = exp2f(sc2[r | 15] - sc2[r]);   // <= 1
    us8v bscaled;
#pragma unroll
    for (int q = 0; q < 8; ++q) {
      BwT[(q + 8 * hf) * 264 + r] = f2bf(bf2f(bh[q]) * wdv);
      bscaled[q] = f2bf(bf2f(bh[q]) * ed);
    }
    *(us8v*)&Bs[r * 24 + 8 * hf] = bscaled;
  }
  if (tid < 16) scE[tid] = sc2[tid * 16 + 15];
  __syncthreads();   // #3 (last barrier)

  if (wid == 0) {
    f32x4 accS = {};
#pragma unroll
    for (int k2 = 0; k2 < 8; ++k2) {
      bf16x8 af = *(const bf16x8*)&BwT[fr * 264 + 32 * k2 + 8 * g];
      bf16x8 bb = *(const bf16x8*)&xsT[fr * 264 + 32 * k2 + 8 * g];
      accS = __builtin_amdgcn_mfma_f32_16x16x32_bf16(af, bb, accS, 0, 0, 0);
    }
    *(f32x4*)&stloc[((size_t)(b * NCHUNKS + cidx) * NHEADS + h) * 256 + fr * 16 + 4 * g] = accS;
  }

  const f32x4 zf = { 0.f, 0.f, 0.f, 0.f };
  const unsigned short* Cbase = Co + rowbase * D_STATE;
  const float Dh = Dvec[h];
  const int strips[2] = { wid, 15 - wid };

  bf16x8 brawq[2];
#pragma unroll
  for (int q = 0; q < 2; ++q) {
    us8v bv = z8;
    if (g < 2)
      bv = *(const us8v*)(Bo + (rowbase + strips[q] * 16 + fr) * D_STATE + 8 * g);
    brawq[q] = __builtin_bit_cast(bf16x8, bv);
  }

#if HAVE_MFMA16
#pragma unroll
  for (int q = 0; q < 2; ++q) {
    const int lt = strips[q];
    f32x4 acc = zf;
    bf16x8 cf = { 0, 0, 0, 0, 0, 0, 0, 0 };
    if (g < 2) cf = *(const bf16x8*)(Cbase + (size_t)(lt * 16 + fr) * D_STATE + 8 * g);
    const float acl2 = sc2[lt * 16 + fr];
    const int   lg   = lt * 16 + fr;
    for (int st = 0; st <= lt; ++st) {
      uint2 pp;
      if (st < lt) {
        bf16x8 bfg = *(const bf16x8*)&Bs[(st * 16 + fr) * 24 + 8 * g];
        f32x4 G = __builtin_amdgcn_mfma_f32_16x16x32_bf16(bfg, cf, zf, 0, 0, 0);
        const float wl = exp2f(acl2 - scE[st]);
        pp.x = pk_bf(G[0] * wl, G[1] * wl);
        pp.y = pk_bf(G[2] * wl, G[3] * wl);
      } else {
        f32x4 G = __builtin_amdgcn_mfma_f32_16x16x32_bf16(brawq[q], cf, zf, 0, 0, 0);
        f32x4 se2 = *(const f32x4*)&sc2[st * 16 + 4 * g];
        const int sbase = st * 16 + 4 * g;
        float w0 = (sbase + 0 <= lg) ? exp2f(acl2 - se2[0]) : 0.f;
        float w1 = (sbase + 1 <= lg) ? exp2f(acl2 - se2[1]) : 0.f;
        float w2 = (sbase + 2 <= lg) ? exp2f(acl2 - se2[2]) : 0.f;
        float w3 = (sbase + 3 <= lg) ? exp2f(acl2 - se2[3]) : 0.f;
        pp.x = pk_bf(G[0] * w0, G[1] * w1);
        pp.y = pk_bf(G[2] * w2, G[3] * w3);
      }
      const bf16x4 p4 = __builtin_bit_cast(bf16x4, pp);
      const bf16x4 x4 = *(const bf16x4*)&xsT[fr * 264 + st * 16 + 4 * g];
      acc = MFMA16(x4, p4, acc);
    }
    us4v xs4 = *(const us4v*)&xraw[(lt * 16 + fr + 3) * 16 + 4 * g];
    us4v o = { f2bf(acc[0] + Dh * bf2f(xs4[0])),
               f2bf(acc[1] + Dh * bf2f(xs4[1])),
               f2bf(acc[2] + Dh * bf2f(xs4[2])),
               f2bf(acc[3] + Dh * bf2f(xs4[3])) };
    *(us4v*)(YdT + (rhrow - r + (size_t)lt * 16 + fr) * HEADDIM + 4 * g) = o;
  }
#else
  const int Ls0 = fr + ((g & 1) << 5);
  const int Ls1 = Ls0 + 16;
  const bool hiq = (g >= 2);
#pragma unroll
  for (int q = 0; q < 2; ++q) {
    const int lt = strips[q];
    f32x4 acc = zf;
    bf16x8 cf = { 0, 0, 0, 0, 0, 0, 0, 0 };
    if (g < 2) cf = *(const bf16x8*)(Cbase + (size_t)(lt * 16 + fr) * D_STATE + 8 * g);
    const float acl2 = sc2[lt * 16 + fr];
    const int   lg   = lt * 16 + fr;
    const int npair = (lt + 2) >> 1;
    for (int sp = 0; sp < npair; ++sp) {
      uint2 pk[2];
#pragma unroll
      for (int ti = 0; ti < 2; ++ti) {
        const int st = 2 * sp + ti;
        if (st < lt) {
          bf16x8 bfg = *(const bf16x8*)&Bs[(st * 16 + fr) * 24 + 8 * g];
          f32x4 G = __builtin_amdgcn_mfma_f32_16x16x32_bf16(bfg, cf, zf, 0, 0, 0);
          const float wl = exp2f(acl2 - scE[st]);
          pk[ti].x = pk_bf(G[0] * wl, G[1] * wl);
          pk[ti].y = pk_bf(G[2] * wl, G[3] * wl);
        } else if (st == lt) {
          f32x4 G = __builtin_amdgcn_mfma_f32_16x16x32_bf16(brawq[q], cf, zf, 0, 0, 0);
          f32x4 se2 = *(const f32x4*)&sc2[st * 16 + 4 * g];
          const int sbase = st * 16 + 4 * g;
          float w0 = (sbase + 0 <= lg) ? exp2f(acl2 - se2[0]) : 0.f;
          float w1 = (sbase + 1 <= lg) ? exp2f(acl2 - se2[1]) : 0.f;
          float w2 = (sbase + 2 <= lg) ? exp2f(acl2 - se2[2]) : 0.f;
          float w3 = (sbase + 3 <= lg) ? exp2f(acl2 - se2[3]) : 0.f;
          pk[ti].x = pk_bf(G[0] * w0, G[1] * w1);
          pk[ti].y = pk_bf(G[2] * w2, G[3] * w3);
        } else {
          pk[ti].x = 0u; pk[ti].y = 0u;
        }
      }
      const int a00 = __shfl((int)pk[0].x, Ls0, 64);
      const int a10 = __shfl((int)pk[0].y, Ls0, 64);
      const int a01 = __shfl((int)pk[0].x, Ls1, 64);
      const int a11 = __shfl((int)pk[0].y, Ls1, 64);
      const int b00 = __shfl((int)pk[1].x, Ls0, 64);
      const int b10 = __shfl((int)pk[1].y, Ls0, 64);
      const int b01 = __shfl((int)pk[1].x, Ls1, 64);
      const int b11 = __shfl((int)pk[1].y, Ls1, 64);
      u32x4 pw;
      pw[0] = (unsigned)(hiq ? b00 : a00);
      pw[1] = (unsigned)(hiq ? b10 : a10);
      pw[2] = (unsigned)(hiq ? b01 : a01);
      pw[3] = (unsigned)(hiq ? b11 : a11);
      const bf16x8 pf = __builtin_bit_cast(bf16x8, pw);
      const bf16x8 xf = *(const bf16x8*)&xsT[fr * 264 + sp * 32 + 8 * g];
      acc = __builtin_amdgcn_mfma_f32_16x16x32_bf16(xf, pf, acc, 0, 0, 0);
    }
    us4v xs4 = *(const us4v*)&xraw[(lt * 16 + fr + 3) * 16 + 4 * g];
    us4v o = { f2bf(acc[0] + Dh * bf2f(xs4[0])),
               f2bf(acc[1] + Dh * bf2f(xs4[1])),
               f2bf(acc[2] + Dh * bf2f(xs4[2])),
               f2bf(acc[3] + Dh * bf2f(xs4[3])) };
    *(us4v*)(YdT + (rhrow - r + (size_t)lt * 16 + fr) * HEADDIM + 4 * g) = o;
  }
#endif
  // no tail barrier: waves retire independently
}

// ---------------------------------------------------------------------------
// K4: sequential inter-chunk state recurrence
// ---------------------------------------------------------------------------
__global__ __launch_bounds__(256)
void chunk_scan_kernel(const float* __restrict__ stloc, const float* __restrict__ csum_g,
                       float* __restrict__ stpre) {
  const int b  = blockIdx.x / NHEADS;
  const int h  = blockIdx.x % NHEADS;
  const int pn = threadIdx.x;
  float S = 0.0f;
  for (int c = 0; c < NCHUNKS; ++c) {
    const size_t idx = ((size_t)(b * NCHUNKS + c) * NHEADS + h) * 256 + pn;
    stpre[idx] = S;
    S = __expf(csum_g[(b * NHEADS + h) * NCHUNKS + c]) * S + stloc[idx];
  }
}

// ---------------------------------------------------------------------------
// K5 (fused, TT=8, 384 threads / 6 waves, 2048 blocks):
// Y_off, silu(z) gate, RMSNorm, out = yn @ W_out^T. Smaller tile -> 5
// blocks/CU (30 waves, 94% cap), half the per-block serial span.
// GEMM phase: each wave 2 col-tiles (M=8 used of 16; stores masked fr<8).
// ---------------------------------------------------------------------------
#define TT 8
#define LDY 392
__global__ __launch_bounds__(384)
void yoff_norm_gemm(const unsigned short* __restrict__ YdT,
                    const unsigned short* __restrict__ Co, const float* __restrict__ acum_g,
                    const float* __restrict__ stpre,
                    const unsigned short* __restrict__ zbuf, const float* __restrict__ norm_w,
                    const unsigned short* __restrict__ Wo,
                    float* __restrict__ out) {
  const int r0   = blockIdx.x * TT;
  const int b    = r0 / SEQLEN;
  const int t0   = r0 % SEQLEN;
  const int cidx = t0 / CHUNK;
  const int tid  = threadIdx.x;
  const int d    = tid;                  // channel 0..383
  const int h    = d >> 4, p = d & 15;
  const int wv   = tid >> 6;             // wave id 0..5

  __shared__ unsigned short Yt[NHEADS * TT * 16];   // [h][tt][p]
  __shared__ unsigned short ynL[TT * LDY];
  __shared__ float At[NHEADS * TT];                 // [h][tt]
  __shared__ float Ct[TT * 16];
  __shared__ float red[TT][6];

  {
    // stage Yt: 384 threads x 16B = 3072 shorts
    us8v* Yt8 = (us8v*)Yt;
    const int j  = tid;
    const int hh = j >> 4;
    const int tt = (j >> 1) & 7;
    const int pp = (j & 1) * 8;
    const size_t src = ((size_t)(b * NHEADS + hh) * SEQLEN + t0 + tt) * HEADDIM + pp;
    Yt8[j] = *(const us8v*)(YdT + src);
    if (tid < NHEADS * TT)
      At[tid] = acum_g[(size_t)(b * NHEADS + (tid >> 3)) * SEQLEN + t0 + (tid & 7)];
    if (tid < TT * 16) Ct[tid] = bf2f(Co[(size_t)r0 * D_STATE + tid]);
  }

  float S[16];
  {
    const float* Sp = stpre + ((size_t)(b * NCHUNKS + cidx) * NHEADS + h) * 256 + p * 16;
#pragma unroll
    for (int q = 0; q < 4; ++q) {
      float4 v4 = *(const float4*)(Sp + 4 * q);
      S[4 * q + 0] = v4.x; S[4 * q + 1] = v4.y; S[4 * q + 2] = v4.z; S[4 * q + 3] = v4.w;
    }
  }
  const float nw = norm_w[d];
  __syncthreads();

  float yg[TT];
#pragma unroll
  for (int tt = 0; tt < TT; ++tt) {
    float dot = 0.f;
#pragma unroll
    for (int n = 0; n < 16; ++n) dot += Ct[tt * 16 + n] * S[n];
    const float acl = At[h * TT + tt];
    float y = bf2f(Yt[h * (TT * 16) + tt * 16 + p]) + __expf(acl) * dot;
    const float z = bf2f(zbuf[(size_t)(r0 + tt) * 384 + d]);
    yg[tt] = y * silu_f(z);
    float s = yg[tt] * yg[tt];
#pragma unroll
    for (int off = 32; off > 0; off >>= 1) s += __shfl_down(s, off);
    if ((tid & 63) == 0) red[tt][wv] = s;
  }
  __syncthreads();

#pragma unroll
  for (int tt = 0; tt < TT; ++tt) {
    const float tot = red[tt][0] + red[tt][1] + red[tt][2] + red[tt][3] + red[tt][4] + red[tt][5];
    const float scale = rsqrtf(tot * (1.0f / D_INNER) + EPS);
    ynL[tt * LDY + d] = f2bf(yg[tt] * scale * nw);
  }
  __syncthreads();

  // ---- GEMM: out[8][192] = ynL @ Wo^T; wave wv -> cols wv*32..+31 ----
  const int lane = tid & 63;
  const int fr = lane & 15, fq = lane >> 4;
  const int n0 = wv * 32;
  f32x4 accg[2] = {};
#pragma unroll
  for (int kt = 0; kt < 12; ++kt) {
    const bf16x8 af = *(const bf16x8*)&ynL[(fr & 7) * LDY + kt * 32 + 8 * fq];
#pragma unroll
    for (int ct = 0; ct < 2; ++ct) {
      const int col = n0 + ct * 16 + fr;
      const bf16x8 bfr = *(const bf16x8*)(Wo + (size_t)col * D_INNER + kt * 32 + 8 * fq);
      accg[ct] = __builtin_amdgcn_mfma_f32_16x16x32_bf16(bfr, af, accg[ct], 0, 0, 0);
    }
  }
  if (fr < TT) {
#pragma unroll
    for (int ct = 0; ct < 2; ++ct) {
      float4 o = make_float4(accg[ct][0], accg[ct][1], accg[ct][2], accg[ct][3]);
      *(float4*)(out + (size_t)(r0 + fr) * D_MODEL + n0 + ct * 16 + fq * 4) = o;
    }
  }
}

// ---------------------------------------------------------------------------
extern "C" void kernel_launch(void* const* d_in, const int* in_sizes, int n_in,
                              void* d_out, int out_size, void* d_ws, size_t ws_size,
                              hipStream_t stream) {
  const float* u        = (const float*)d_in[0];
  const float* support  = (const float*)d_in[1];
  const float* W_in     = (const float*)d_in[2];
  const float* W_in_b   = (const float*)d_in[3];
  const float* conv_w   = (const float*)d_in[4];
  const float* conv_b   = (const float*)d_in[5];
  const float* conv_w_b = (const float*)d_in[6];
  const float* conv_b_b = (const float*)d_in[7];
  const float* dt_bias  = (const float*)d_in[8];
  const float* A_log    = (const float*)d_in[9];
  const float* Dvec     = (const float*)d_in[10];
  const float* norm_w   = (const float*)d_in[11];
  const float* W_out    = (const float*)d_in[12];
  float* out = (float*)d_out;
  char* wsb  = (char*)d_ws;

  unsigned short* Wi_b  = (unsigned short*)(wsb);
  unsigned short* Wo_b  = Wi_b + (size_t)D_IN_PROJ * D_MODEL;
  unsigned short* Wib_b = Wo_b + (size_t)D_MODEL * D_INNER;
  unsigned short* zbuf  = Wib_b + (size_t)D_STATE * D_MODEL;
  unsigned short* xT    = zbuf + (size_t)ROWS * D_INNER;
  unsigned short* Braw  = xT + (size_t)ROWS * D_INNER;
  unsigned short* draw  = Braw + (size_t)ROWS * D_STATE;
  unsigned short* craw  = draw + (size_t)ROWS * NHEADS;
  unsigned short* Bo    = craw + (size_t)ROWS * D_STATE;
  unsigned short* Co    = Bo + (size_t)ROWS * D_STATE;
  unsigned short* YdT   = Co + (size_t)ROWS * D_STATE;
  float* dtoT  = (float*)(YdT + (size_t)ROWS * D_INNER);
  float* acum  = dtoT  + (size_t)ROWS * NHEADS;
  float* csum  = acum  + (size_t)BATCH * NHEADS * SEQLEN;
  float* stloc = csum  + (size_t)BATCH * NHEADS * NCHUNKS;
  float* stpre = stloc + (size_t)BATCH * NCHUNKS * NHEADS * 256;

  cvt3_kernel<<<224, 256, 0, stream>>>(W_in, Wi_b, (long)D_IN_PROJ * D_MODEL,
                                       W_out, Wo_b, (long)D_MODEL * D_INNER,
                                       W_in_b, Wib_b, (long)D_STATE * D_MODEL);
  gemm_bf16<true, true, true><<<dim3(7, ROWS / 128), 256, 0, stream>>>(
      u, Wi_b, nullptr, ROWS, D_IN_PROJ, D_MODEL, zbuf, xT, Braw, draw);
  gemm_bf16<true, true, false><<<dim3(1, ROWS / 128), 256, 0, stream>>>(
      support, Wib_b, craw, ROWS, D_STATE, D_MODEL, nullptr, nullptr, nullptr, nullptr);
  conv_bcdt<<<CBC_NB + CDT_NB, 256, 0, stream>>>(
      Braw, craw, draw, conv_w, conv_b, conv_w_b, conv_b_b, dt_bias, Bo, Co, dtoT);
  ssd_mfma_kernel<<<dim3(NHEADS, NCHUNKS, BATCH), 512, 0, stream>>>(
      xT, Bo, Co, dtoT, A_log, conv_w, conv_b, Dvec, YdT, acum, csum, stloc);
  chunk_scan_kernel<<<BATCH * NHEADS, 256, 0, stream>>>(stloc, csum, stpre);
  yoff_norm_gemm<<<ROWS / TT, 384, 0, stream>>>(YdT, Co, acum, stpre, zbuf, norm_w,
                                                Wo_b, out);
}

// Round 24
// 121.873 us; speedup vs baseline: 1.1260x; 1.1260x over previous
//
#include <hip/hip_runtime.h>
#include <cmath>

#define ROWS      16384
#define SEQLEN    8192
#define BATCH     2
#define NHEADS    24
#define HEADDIM   16
#define D_STATE   16
#define D_INNER   384
#define D_MODEL   192
#define D_IN_PROJ 808
#define CONV_DIM  400
#define NCHUNKS   32
#define CHUNK     256
#define EPS       1e-5f
#define LOG2E     1.44269504088896f

typedef short bf16x8 __attribute__((ext_vector_type(8)));
typedef short bf16x4 __attribute__((ext_vector_type(4)));
typedef float f32x4  __attribute__((ext_vector_type(4)));
typedef unsigned short us4v __attribute__((ext_vector_type(4)));
typedef unsigned short us8v __attribute__((ext_vector_type(8)));
typedef unsigned int  u32x4 __attribute__((ext_vector_type(4)));

#if __has_builtin(__builtin_amdgcn_mfma_f32_16x16x16bf16_1k)
#define MFMA16(a, b, c) __builtin_amdgcn_mfma_f32_16x16x16bf16_1k((a), (b), (c), 0, 0, 0)
#define HAVE_MFMA16 1
#elif __has_builtin(__builtin_amdgcn_mfma_f32_16x16x16_bf16)
#define MFMA16(a, b, c) __builtin_amdgcn_mfma_f32_16x16x16_bf16((a), (b), (c), 0, 0, 0)
#define HAVE_MFMA16 1
#else
#define HAVE_MFMA16 0
#endif

__device__ __forceinline__ float silu_f(float x) { return x / (1.0f + expf(-x)); }
__device__ __forceinline__ float softplus_f(float x) { return (x > 20.0f) ? x : log1pf(expf(x)); }
__device__ __forceinline__ unsigned short f2bf(float x) {
  unsigned u = __builtin_bit_cast(unsigned, x);
  u += 0x7fff + ((u >> 16) & 1);
  return (unsigned short)(u >> 16);
}
__device__ __forceinline__ float bf2f(unsigned short s) {
  unsigned u = (unsigned)s << 16;
  return __builtin_bit_cast(float, u);
}
__device__ __forceinline__ unsigned pk_bf(float a, float b) {
  unsigned ua = __builtin_bit_cast(unsigned, a) + 0x7fffu;
  unsigned ub = __builtin_bit_cast(unsigned, b) + 0x7fffu;
  return __builtin_amdgcn_perm(ub, ua, 0x07060302u);
}

// ---------------------------------------------------------------------------
// K0: fp32 -> bf16 weights (W_in, W_out, W_in_b)
// ---------------------------------------------------------------------------
__global__ __launch_bounds__(256)
void cvt3_kernel(const float* __restrict__ a, unsigned short* __restrict__ ao, long na,
                 const float* __restrict__ b, unsigned short* __restrict__ bo, long nb,
                 const float* __restrict__ c, unsigned short* __restrict__ co, long nc) {
  const long t0 = na >> 2, t1 = t0 + (nb >> 2), t2 = t1 + (nc >> 2);
  const long stride = (long)gridDim.x * blockDim.x;
  for (long i = (long)blockIdx.x * blockDim.x + threadIdx.x; i < t2; i += stride) {
    const float4* s; us4v* d; long j;
    if (i < t0)      { s = (const float4*)a; d = (us4v*)ao; j = i; }
    else if (i < t1) { s = (const float4*)b; d = (us4v*)bo; j = i - t0; }
    else             { s = (const float4*)c; d = (us4v*)co; j = i - t1; }
    float4 v = s[j];
    us4v o = { f2bf(v.x), f2bf(v.y), f2bf(v.z), f2bf(v.w) };
    d[j] = o;
  }
}

// ---------------------------------------------------------------------------
// MFMA bf16 GEMM. ROUTE=true: in-proj output split into consumer-native dense
// buffers (z->zbuf, x->head-major xT, Braw, draw).
// ---------------------------------------------------------------------------
template<bool A_F32, bool OUT_BF16, bool ROUTE>
__launch_bounds__(256, 3)
__global__ void gemm_bf16(const void* __restrict__ Ap,
                          const unsigned short* __restrict__ W,
                          void* __restrict__ Cp, int M, int N, int K,
                          unsigned short* __restrict__ zbuf,
                          unsigned short* __restrict__ xT,
                          unsigned short* __restrict__ Braw,
                          unsigned short* __restrict__ draw) {
  constexpr int BM = 128, BN = 128, BK = 32, LDK = 40;
  __shared__ unsigned short As[2][BM * LDK];
  __shared__ unsigned short Ws[2][BN * LDK];
  const int tid  = threadIdx.x;
  const int wid  = tid >> 6, lane = tid & 63;
  const int wr   = wid >> 1, wc = wid & 1;
  const int fr   = lane & 15, fq = lane >> 4;
  const long m0  = (long)blockIdx.y * BM;
  const int  n0  = blockIdx.x * BN;

  f32x4 acc[4][4] = {};

  auto stage = [&](int k0, int buf) {
    if (A_F32) {
      const float* A = (const float*)Ap;
#pragma unroll
      for (int p = 0; p < 2; ++p) {
        int flat = p * 2048 + tid * 8;
        int r = flat >> 5, c = flat & 31;
        const float4* src = (const float4*)(A + (m0 + r) * (long)K + k0 + c);
        float4 v0 = src[0], v1 = src[1];
        us8v o = { f2bf(v0.x), f2bf(v0.y), f2bf(v0.z), f2bf(v0.w),
                   f2bf(v1.x), f2bf(v1.y), f2bf(v1.z), f2bf(v1.w) };
        *(us8v*)&As[buf][r * LDK + c] = o;
      }
    } else {
      const unsigned short* A = (const unsigned short*)Ap;
#pragma unroll
      for (int p = 0; p < 2; ++p) {
        int flat = p * 2048 + tid * 8;
        int r = flat >> 5, c = flat & 31;
        us8v v = *(const us8v*)(A + (m0 + r) * (long)K + k0 + c);
        *(us8v*)&As[buf][r * LDK + c] = v;
      }
    }
#pragma unroll
    for (int p = 0; p < 2; ++p) {
      int flat = p * 2048 + tid * 8;
      int r = flat >> 5, c = flat & 31;
      int gn = n0 + r;
      us8v v = { 0, 0, 0, 0, 0, 0, 0, 0 };
      if (gn < N) v = *(const us8v*)(W + (long)gn * K + k0 + c);
      *(us8v*)&Ws[buf][r * LDK + c] = v;
    }
  };

  const int nk = K / BK;
  stage(0, 0);
  __syncthreads();
  for (int kt = 0; kt < nk; ++kt) {
    const int cur = kt & 1;
    if (kt + 1 < nk) stage((kt + 1) * BK, cur ^ 1);
    bf16x8 af[4], bfr[4];
#pragma unroll
    for (int m = 0; m < 4; ++m)
      af[m] = *(const bf16x8*)&As[cur][(wr * 64 + m * 16 + fr) * LDK + fq * 8];
#pragma unroll
    for (int n = 0; n < 4; ++n)
      bfr[n] = *(const bf16x8*)&Ws[cur][(wc * 64 + n * 16 + fr) * LDK + fq * 8];
#pragma unroll
    for (int m = 0; m < 4; ++m)
#pragma unroll
      for (int n = 0; n < 4; ++n)
        acc[m][n] = __builtin_amdgcn_mfma_f32_16x16x32_bf16(bfr[n], af[m], acc[m][n], 0, 0, 0);
    __syncthreads();
  }

#pragma unroll
  for (int m = 0; m < 4; ++m) {
    const long gm = m0 + wr * 64 + m * 16 + fr;
#pragma unroll
    for (int n = 0; n < 4; ++n) {
      const int gn = n0 + wc * 64 + n * 16 + fq * 4;
      if (gn < N) {
        if (ROUTE) {
          us4v o = { f2bf(acc[m][n][0]), f2bf(acc[m][n][1]),
                     f2bf(acc[m][n][2]), f2bf(acc[m][n][3]) };
          const int bb = (int)(gm >> 13);
          const long t = gm & 8191;
          if (gn < 384) {
            *(us4v*)(zbuf + gm * 384 + gn) = o;
          } else if (gn < 768) {
            const int c = gn - 384, hh = c >> 4, ii = c & 15;
            *(us4v*)(xT + (((size_t)(bb * NHEADS + hh) * SEQLEN + t) << 4) + ii) = o;
          } else if (gn < 784) {
            *(us4v*)(Braw + gm * 16 + (gn - 768)) = o;
          } else {
            *(us4v*)(draw + gm * 24 + (gn - 784)) = o;
          }
        } else if (OUT_BF16) {
          us4v o = { f2bf(acc[m][n][0]), f2bf(acc[m][n][1]),
                     f2bf(acc[m][n][2]), f2bf(acc[m][n][3]) };
          *(us4v*)((unsigned short*)Cp + gm * N + gn) = o;
        } else {
          float4 o = make_float4(acc[m][n][0], acc[m][n][1], acc[m][n][2], acc[m][n][3]);
          *(float4*)((float*)Cp + gm * N + gn) = o;
        }
      }
    }
  }
}

// ---------------------------------------------------------------------------
// K2: B/C conv + dt softplus, dense raw buffers. 448 role-pure blocks.
// ---------------------------------------------------------------------------
#define CBC_NB  (ROWS * 4 / 256)    // 256
#define CDT_NB  (ROWS * 3 / 256)    // 192

__global__ __launch_bounds__(256)
void conv_bcdt(const unsigned short* __restrict__ Braw, const unsigned short* __restrict__ craw,
               const unsigned short* __restrict__ draw,
               const float* __restrict__ conv_w, const float* __restrict__ conv_b,
               const float* __restrict__ conv_w_b, const float* __restrict__ conv_b_b,
               const float* __restrict__ dt_bias,
               unsigned short* __restrict__ Bo, unsigned short* __restrict__ Co,
               float* __restrict__ dtoT) {
  const int blk = blockIdx.x;
  const us8v z8 = { 0, 0, 0, 0, 0, 0, 0, 0 };

  if (blk < CBC_NB) {
    const int idx = blk * 256 + threadIdx.x;
    const int row = idx / 4, q = idx % 4;
    const int b = row / SEQLEN, t = row % SEQLEN;

    const unsigned short* src = (q < 2) ? Braw : craw;
    const float* cw = (q < 2) ? conv_w + 384 * 4 : conv_w_b;
    const float* cb = (q < 2) ? conv_b + 384 : conv_b_b;
    const int c0 = (q & 1) * 8;
    const unsigned short* base = src + (size_t)row * D_STATE + c0;
    us8v x0 = (t >= 3) ? *(const us8v*)(base - 3 * D_STATE) : z8;
    us8v x1 = (t >= 2) ? *(const us8v*)(base - 2 * D_STATE) : z8;
    us8v x2 = (t >= 1) ? *(const us8v*)(base - 1 * D_STATE) : z8;
    us8v x3 = *(const us8v*)base;
    us8v o;
#pragma unroll
    for (int ch = 0; ch < 8; ++ch) {
      const float4 wv = *(const float4*)(cw + (c0 + ch) * 4);
      float acc = cb[c0 + ch] + wv.x * bf2f(x0[ch]) + wv.y * bf2f(x1[ch])
                + wv.z * bf2f(x2[ch]) + wv.w * bf2f(x3[ch]);
      o[ch] = f2bf(silu_f(acc));
    }
    if (q < 2) *(us8v*)(Bo + (size_t)row * D_STATE + c0) = o;
    else       *(us8v*)(Co + (size_t)row * D_STATE + c0) = o;
  } else {
    const int idx = (blk - CBC_NB) * 256 + threadIdx.x;
    const int row = idx / 3, q = idx % 3;
    const int b = row / SEQLEN, t = row % SEQLEN;
    const int h0 = q * 8;
    us8v dv = *(const us8v*)(draw + (size_t)row * 24 + h0);
#pragma unroll
    for (int j = 0; j < 8; ++j) {
      float v = bf2f(dv[j]) + dt_bias[h0 + j];
      dtoT[(size_t)(b * NHEADS + h0 + j) * SEQLEN + t] = softplus_f(v);
    }
  }
}

// ---------------------------------------------------------------------------
// K3 (MFMA, 8 waves, fused x-conv, factored decay, K16 PV): unchanged.
// ---------------------------------------------------------------------------
__global__ __launch_bounds__(512, 4)
void ssd_mfma_kernel(const unsigned short* __restrict__ xT, const unsigned short* __restrict__ Bo,
                     const unsigned short* __restrict__ Co, const float* __restrict__ dtoT,
                     const float* __restrict__ A_log, const float* __restrict__ conv_w,
                     const float* __restrict__ conv_b, const float* __restrict__ Dvec,
                     unsigned short* __restrict__ YdT, float* __restrict__ acum_g,
                     float* __restrict__ csum_g, float* __restrict__ stloc) {
  const int h    = blockIdx.x;
  const int cidx = blockIdx.y;
  const int b    = blockIdx.z;
  const int tid  = threadIdx.x;
  const int wid  = tid >> 6, lane = tid & 63;
  const int fr   = lane & 15, g = lane >> 4;

  __shared__ unsigned short Bs[256 * 24 + 32];
  __shared__ unsigned short xsT[16 * 264];
  __shared__ unsigned short BwT[16 * 264];
  __shared__ unsigned short xraw[259 * 16 + 8];
  __shared__ float sc2[CHUNK];
  __shared__ float scE[16];
  __shared__ float wsum[4];

  const float Ah = -expf(A_log[h]);
  const us8v z8 = { 0, 0, 0, 0, 0, 0, 0, 0 };

  float v = 0.f;
  if (tid < CHUNK) {
    v = dtoT[(size_t)(b * NHEADS + h) * SEQLEN + (size_t)cidx * CHUNK + tid] * Ah;
#pragma unroll
    for (int off = 1; off < 64; off <<= 1) {
      float u = __shfl_up(v, off, 64);
      if (lane >= off) v += u;
    }
    if (lane == 63) wsum[wid] = v;
  }

  const int r  = tid >> 1;
  const int hf = tid & 1;
  const size_t rowbase = (size_t)b * SEQLEN + (size_t)cidx * CHUNK;
  const size_t rhrow = (size_t)(b * NHEADS + h) * SEQLEN + (size_t)cidx * CHUNK + r;
  const float rdtv = dtoT[rhrow];
  us8v bh = ((const us8v*)(Bo + (rowbase + r) * D_STATE))[hf];
  if (hf == 0) *(us8v*)&Bs[r * 24 + 16] = z8;
  if (tid < 32) Bs[256 * 24 + tid] = 0;
  {
    const int tg = cidx * CHUNK + r - 3;
    us8v xv = z8;
    if (tg >= 0)
      xv = *(const us8v*)(xT + (((size_t)(b * NHEADS + h) * SEQLEN + tg) << 4) + 8 * hf);
    *(us8v*)&xraw[r * 16 + 8 * hf] = xv;
    if (tid < 6) {
      const int rr2 = 256 + (tid >> 1);
      const int hf2 = tid & 1;
      const int tg2 = cidx * CHUNK + rr2 - 3;
      us8v xv2 = *(const us8v*)(xT + (((size_t)(b * NHEADS + h) * SEQLEN + tg2) << 4) + 8 * hf2);
      *(us8v*)&xraw[rr2 * 16 + 8 * hf2] = xv2;
    }
  }
  __syncthreads();   // #1

  us8v xsil, xdt8;
  {
    us8v tA = *(const us8v*)&xraw[(r + 0) * 16 + 8 * hf];
    us8v tB = *(const us8v*)&xraw[(r + 1) * 16 + 8 * hf];
    us8v tC = *(const us8v*)&xraw[(r + 2) * 16 + 8 * hf];
    us8v tD = *(const us8v*)&xraw[(r + 3) * 16 + 8 * hf];
    const int cbase = h * HEADDIM + 8 * hf;
#pragma unroll
    for (int ch = 0; ch < 8; ++ch) {
      const float4 wv = *(const float4*)(conv_w + (cbase + ch) * 4);
      float acc = conv_b[cbase + ch] + wv.x * bf2f(tA[ch]) + wv.y * bf2f(tB[ch])
                + wv.z * bf2f(tC[ch]) + wv.w * bf2f(tD[ch]);
      float sv = silu_f(acc);
      xsil[ch] = f2bf(sv);
      xdt8[ch] = f2bf(sv * rdtv);
    }
  }
  const float ctot  = wsum[0] + wsum[1] + wsum[2] + wsum[3];
  const float ctot2 = ctot * LOG2E;
  if (tid < CHUNK) {
    float pre = 0.f;
#pragma unroll
    for (int w = 0; w < 4; ++w) if (w < wid) pre += wsum[w];
    v += pre;
    sc2[tid] = v * LOG2E;
    acum_g[(size_t)(b * NHEADS + h) * SEQLEN + (size_t)cidx * CHUNK + tid] = v;
    if (tid == CHUNK - 1) csum_g[(b * NHEADS + h) * NCHUNKS + cidx] = v;
  }
  __syncthreads();   // #2

  *(us8v*)&xraw[(r + 3) * 16 + 8 * hf] = xsil;
#pragma unroll
  for (int q = 0; q < 8; ++q)
    xsT[(q + 8 * hf) * 264 + r] = xdt8[q];
  {
    const float wdv = exp2f(ctot2 - sc2[r]);
    const float ed  = exp2f(sc2[r | 15] - sc2[r]);   // <= 1
    us8v bscaled;
#pragma unroll
    for (int q = 0; q < 8; ++q) {
      BwT[(q + 8 * hf) * 264 + r] = f2bf(bf2f(bh[q]) * wdv);
      bscaled[q] = f2bf(bf2f(bh[q]) * ed);
    }
    *(us8v*)&Bs[r * 24 + 8 * hf] = bscaled;
  }
  if (tid < 16) scE[tid] = sc2[tid * 16 + 15];
  __syncthreads();   // #3 (last barrier)

  if (wid == 0) {
    f32x4 accS = {};
#pragma unroll
    for (int k2 = 0; k2 < 8; ++k2) {
      bf16x8 af = *(const bf16x8*)&BwT[fr * 264 + 32 * k2 + 8 * g];
      bf16x8 bb = *(const bf16x8*)&xsT[fr * 264 + 32 * k2 + 8 * g];
      accS = __builtin_amdgcn_mfma_f32_16x16x32_bf16(af, bb, accS, 0, 0, 0);
    }
    *(f32x4*)&stloc[((size_t)(b * NCHUNKS + cidx) * NHEADS + h) * 256 + fr * 16 + 4 * g] = accS;
  }

  const f32x4 zf = { 0.f, 0.f, 0.f, 0.f };
  const unsigned short* Cbase = Co + rowbase * D_STATE;
  const float Dh = Dvec[h];
  const int strips[2] = { wid, 15 - wid };

  bf16x8 brawq[2];
#pragma unroll
  for (int q = 0; q < 2; ++q) {
    us8v bv = z8;
    if (g < 2)
      bv = *(const us8v*)(Bo + (rowbase + strips[q] * 16 + fr) * D_STATE + 8 * g);
    brawq[q] = __builtin_bit_cast(bf16x8, bv);
  }

#if HAVE_MFMA16
#pragma unroll
  for (int q = 0; q < 2; ++q) {
    const int lt = strips[q];
    f32x4 acc = zf;
    bf16x8 cf = { 0, 0, 0, 0, 0, 0, 0, 0 };
    if (g < 2) cf = *(const bf16x8*)(Cbase + (size_t)(lt * 16 + fr) * D_STATE + 8 * g);
    const float acl2 = sc2[lt * 16 + fr];
    const int   lg   = lt * 16 + fr;
    for (int st = 0; st <= lt; ++st) {
      uint2 pp;
      if (st < lt) {
        bf16x8 bfg = *(const bf16x8*)&Bs[(st * 16 + fr) * 24 + 8 * g];
        f32x4 G = __builtin_amdgcn_mfma_f32_16x16x32_bf16(bfg, cf, zf, 0, 0, 0);
        const float wl = exp2f(acl2 - scE[st]);
        pp.x = pk_bf(G[0] * wl, G[1] * wl);
        pp.y = pk_bf(G[2] * wl, G[3] * wl);
      } else {
        f32x4 G = __builtin_amdgcn_mfma_f32_16x16x32_bf16(brawq[q], cf, zf, 0, 0, 0);
        f32x4 se2 = *(const f32x4*)&sc2[st * 16 + 4 * g];
        const int sbase = st * 16 + 4 * g;
        float w0 = (sbase + 0 <= lg) ? exp2f(acl2 - se2[0]) : 0.f;
        float w1 = (sbase + 1 <= lg) ? exp2f(acl2 - se2[1]) : 0.f;
        float w2 = (sbase + 2 <= lg) ? exp2f(acl2 - se2[2]) : 0.f;
        float w3 = (sbase + 3 <= lg) ? exp2f(acl2 - se2[3]) : 0.f;
        pp.x = pk_bf(G[0] * w0, G[1] * w1);
        pp.y = pk_bf(G[2] * w2, G[3] * w3);
      }
      const bf16x4 p4 = __builtin_bit_cast(bf16x4, pp);
      const bf16x4 x4 = *(const bf16x4*)&xsT[fr * 264 + st * 16 + 4 * g];
      acc = MFMA16(x4, p4, acc);
    }
    us4v xs4 = *(const us4v*)&xraw[(lt * 16 + fr + 3) * 16 + 4 * g];
    us4v o = { f2bf(acc[0] + Dh * bf2f(xs4[0])),
               f2bf(acc[1] + Dh * bf2f(xs4[1])),
               f2bf(acc[2] + Dh * bf2f(xs4[2])),
               f2bf(acc[3] + Dh * bf2f(xs4[3])) };
    *(us4v*)(YdT + (rhrow - r + (size_t)lt * 16 + fr) * HEADDIM + 4 * g) = o;
  }
#else
  const int Ls0 = fr + ((g & 1) << 5);
  const int Ls1 = Ls0 + 16;
  const bool hiq = (g >= 2);
#pragma unroll
  for (int q = 0; q < 2; ++q) {
    const int lt = strips[q];
    f32x4 acc = zf;
    bf16x8 cf = { 0, 0, 0, 0, 0, 0, 0, 0 };
    if (g < 2) cf = *(const bf16x8*)(Cbase + (size_t)(lt * 16 + fr) * D_STATE + 8 * g);
    const float acl2 = sc2[lt * 16 + fr];
    const int   lg   = lt * 16 + fr;
    const int npair = (lt + 2) >> 1;
    for (int sp = 0; sp < npair; ++sp) {
      uint2 pk[2];
#pragma unroll
      for (int ti = 0; ti < 2; ++ti) {
        const int st = 2 * sp + ti;
        if (st < lt) {
          bf16x8 bfg = *(const bf16x8*)&Bs[(st * 16 + fr) * 24 + 8 * g];
          f32x4 G = __builtin_amdgcn_mfma_f32_16x16x32_bf16(bfg, cf, zf, 0, 0, 0);
          const float wl = exp2f(acl2 - scE[st]);
          pk[ti].x = pk_bf(G[0] * wl, G[1] * wl);
          pk[ti].y = pk_bf(G[2] * wl, G[3] * wl);
        } else if (st == lt) {
          f32x4 G = __builtin_amdgcn_mfma_f32_16x16x32_bf16(brawq[q], cf, zf, 0, 0, 0);
          f32x4 se2 = *(const f32x4*)&sc2[st * 16 + 4 * g];
          const int sbase = st * 16 + 4 * g;
          float w0 = (sbase + 0 <= lg) ? exp2f(acl2 - se2[0]) : 0.f;
          float w1 = (sbase + 1 <= lg) ? exp2f(acl2 - se2[1]) : 0.f;
          float w2 = (sbase + 2 <= lg) ? exp2f(acl2 - se2[2]) : 0.f;
          float w3 = (sbase + 3 <= lg) ? exp2f(acl2 - se2[3]) : 0.f;
          pk[ti].x = pk_bf(G[0] * w0, G[1] * w1);
          pk[ti].y = pk_bf(G[2] * w2, G[3] * w3);
        } else {
          pk[ti].x = 0u; pk[ti].y = 0u;
        }
      }
      const int a00 = __shfl((int)pk[0].x, Ls0, 64);
      const int a10 = __shfl((int)pk[0].y, Ls0, 64);
      const int a01 = __shfl((int)pk[0].x, Ls1, 64);
      const int a11 = __shfl((int)pk[0].y, Ls1, 64);
      const int b00 = __shfl((int)pk[1].x, Ls0, 64);
      const int b10 = __shfl((int)pk[1].y, Ls0, 64);
      const int b01 = __shfl((int)pk[1].x, Ls1, 64);
      const int b11 = __shfl((int)pk[1].y, Ls1, 64);
      u32x4 pw;
      pw[0] = (unsigned)(hiq ? b00 : a00);
      pw[1] = (unsigned)(hiq ? b10 : a10);
      pw[2] = (unsigned)(hiq ? b01 : a01);
      pw[3] = (unsigned)(hiq ? b11 : a11);
      const bf16x8 pf = __builtin_bit_cast(bf16x8, pw);
      const bf16x8 xf = *(const bf16x8*)&xsT[fr * 264 + sp * 32 + 8 * g];
      acc = __builtin_amdgcn_mfma_f32_16x16x32_bf16(xf, pf, acc, 0, 0, 0);
    }
    us4v xs4 = *(const us4v*)&xraw[(lt * 16 + fr + 3) * 16 + 4 * g];
    us4v o = { f2bf(acc[0] + Dh * bf2f(xs4[0])),
               f2bf(acc[1] + Dh * bf2f(xs4[1])),
               f2bf(acc[2] + Dh * bf2f(xs4[2])),
               f2bf(acc[3] + Dh * bf2f(xs4[3])) };
    *(us4v*)(YdT + (rhrow - r + (size_t)lt * 16 + fr) * HEADDIM + 4 * g) = o;
  }
#endif
  // no tail barrier: waves retire independently
}

// ---------------------------------------------------------------------------
// K4: sequential inter-chunk state recurrence
// ---------------------------------------------------------------------------
__global__ __launch_bounds__(256)
void chunk_scan_kernel(const float* __restrict__ stloc, const float* __restrict__ csum_g,
                       float* __restrict__ stpre) {
  const int b  = blockIdx.x / NHEADS;
  const int h  = blockIdx.x % NHEADS;
  const int pn = threadIdx.x;
  float S = 0.0f;
  for (int c = 0; c < NCHUNKS; ++c) {
    const size_t idx = ((size_t)(b * NCHUNKS + c) * NHEADS + h) * 256 + pn;
    stpre[idx] = S;
    S = __expf(csum_g[(b * NHEADS + h) * NCHUNKS + c]) * S + stloc[idx];
  }
}

// ---------------------------------------------------------------------------
// K5 (fused, 12 waves, r22 config): Y_off, silu(z) gate, RMSNorm,
// out = yn @ W_out^T. 768 threads; setprio(1) around the GEMM MFMA loop
// (independent blocks at different phases -> scheduler can favor MFMA waves).
// ---------------------------------------------------------------------------
#define TT 16
#define LDY 392
__global__ __launch_bounds__(768)
void yoff_norm_gemm(const unsigned short* __restrict__ YdT,
                    const unsigned short* __restrict__ Co, const float* __restrict__ acum_g,
                    const float* __restrict__ stpre,
                    const unsigned short* __restrict__ zbuf, const float* __restrict__ norm_w,
                    const unsigned short* __restrict__ Wo,
                    float* __restrict__ out) {
  const int r0   = blockIdx.x * TT;
  const int b    = r0 / SEQLEN;
  const int t0   = r0 % SEQLEN;
  const int cidx = t0 / CHUNK;
  const int tid  = threadIdx.x;
  const int d    = tid % 384;            // channel
  const int half = tid / 384;            // row half: 0 -> rows 0-7, 1 -> rows 8-15
  const int h    = d >> 4, p = d & 15;
  const int wv   = tid >> 6;             // wave id 0..11

  __shared__ unsigned short Yt[NHEADS * TT * 16];
  __shared__ unsigned short ynL[TT * LDY];
  __shared__ float At[NHEADS * TT];
  __shared__ float Ct[TT * 16];
  __shared__ float red[TT][6];

  {
    us8v* Yt8 = (us8v*)Yt;
    int hh = tid >> 5, q = tid & 31;
    const size_t src = ((size_t)(b * NHEADS + hh) * SEQLEN + t0) * HEADDIM + q * 8;
    Yt8[tid] = *(const us8v*)(YdT + src);
    if (tid < NHEADS * TT)
      At[tid] = acum_g[(size_t)(b * NHEADS + (tid >> 4)) * SEQLEN + t0 + (tid & 15)];
    if (tid < TT * 16) Ct[tid] = bf2f(Co[(size_t)r0 * D_STATE + tid]);
  }

  float S[16];
  {
    const float* Sp = stpre + ((size_t)(b * NCHUNKS + cidx) * NHEADS + h) * 256 + p * 16;
#pragma unroll
    for (int q = 0; q < 4; ++q) {
      float4 v4 = *(const float4*)(Sp + 4 * q);
      S[4 * q + 0] = v4.x; S[4 * q + 1] = v4.y; S[4 * q + 2] = v4.z; S[4 * q + 3] = v4.w;
    }
  }
  const float nw = norm_w[d];
  __syncthreads();

  const int tb = half * 8;
  float yg[8];
#pragma unroll
  for (int ti = 0; ti < 8; ++ti) {
    const int tt = tb + ti;
    float dot = 0.f;
#pragma unroll
    for (int n = 0; n < 16; ++n) dot += Ct[tt * 16 + n] * S[n];
    const float acl = At[h * TT + tt];
    float y = bf2f(Yt[h * 256 + tt * 16 + p]) + __expf(acl) * dot;
    const float z = bf2f(zbuf[(size_t)(r0 + tt) * 384 + d]);
    yg[ti] = y * silu_f(z);
    float s = yg[ti] * yg[ti];
#pragma unroll
    for (int off = 32; off > 0; off >>= 1) s += __shfl_down(s, off);
    if ((tid & 63) == 0) red[tt][wv - half * 6] = s;
  }
  __syncthreads();

#pragma unroll
  for (int ti = 0; ti < 8; ++ti) {
    const int tt = tb + ti;
    const float tot = red[tt][0] + red[tt][1] + red[tt][2] + red[tt][3] + red[tt][4] + red[tt][5];
    const float scale = rsqrtf(tot * (1.0f / D_INNER) + EPS);
    ynL[tt * LDY + d] = f2bf(yg[ti] * scale * nw);
  }
  __syncthreads();

  // ---- GEMM phase: out[16][192] = ynL @ Wo^T; wave wv -> cols wv*16..+15 ----
  const int lane = tid & 63;
  const int fr = lane & 15, fq = lane >> 4;
  const int n0 = wv * 16;
  f32x4 accg = {};
  __builtin_amdgcn_s_setprio(1);
#pragma unroll
  for (int kt = 0; kt < 12; ++kt) {
    const bf16x8 af = *(const bf16x8*)&ynL[fr * LDY + kt * 32 + 8 * fq];
    const int col = n0 + fr;
    const bf16x8 bfr = *(const bf16x8*)(Wo + (size_t)col * D_INNER + kt * 32 + 8 * fq);
    accg = __builtin_amdgcn_mfma_f32_16x16x32_bf16(bfr, af, accg, 0, 0, 0);
  }
  __builtin_amdgcn_s_setprio(0);
  float4 o = make_float4(accg[0], accg[1], accg[2], accg[3]);
  *(float4*)(out + (size_t)(r0 + fr) * D_MODEL + n0 + fq * 4) = o;
}

// ---------------------------------------------------------------------------
extern "C" void kernel_launch(void* const* d_in, const int* in_sizes, int n_in,
                              void* d_out, int out_size, void* d_ws, size_t ws_size,
                              hipStream_t stream) {
  const float* u        = (const float*)d_in[0];
  const float* support  = (const float*)d_in[1];
  const float* W_in     = (const float*)d_in[2];
  const float* W_in_b   = (const float*)d_in[3];
  const float* conv_w   = (const float*)d_in[4];
  const float* conv_b   = (const float*)d_in[5];
  const float* conv_w_b = (const float*)d_in[6];
  const float* conv_b_b = (const float*)d_in[7];
  const float* dt_bias  = (const float*)d_in[8];
  const float* A_log    = (const float*)d_in[9];
  const float* Dvec     = (const float*)d_in[10];
  const float* norm_w   = (const float*)d_in[11];
  const float* W_out    = (const float*)d_in[12];
  float* out = (float*)d_out;
  char* wsb  = (char*)d_ws;

  unsigned short* Wi_b  = (unsigned short*)(wsb);
  unsigned short* Wo_b  = Wi_b + (size_t)D_IN_PROJ * D_MODEL;
  unsigned short* Wib_b = Wo_b + (size_t)D_MODEL * D_INNER;
  unsigned short* zbuf  = Wib_b + (size_t)D_STATE * D_MODEL;
  unsigned short* xT    = zbuf + (size_t)ROWS * D_INNER;
  unsigned short* Braw  = xT + (size_t)ROWS * D_INNER;
  unsigned short* draw  = Braw + (size_t)ROWS * D_STATE;
  unsigned short* craw  = draw + (size_t)ROWS * NHEADS;
  unsigned short* Bo    = craw + (size_t)ROWS * D_STATE;
  unsigned short* Co    = Bo + (size_t)ROWS * D_STATE;
  unsigned short* YdT   = Co + (size_t)ROWS * D_STATE;
  float* dtoT  = (float*)(YdT + (size_t)ROWS * D_INNER);
  float* acum  = dtoT  + (size_t)ROWS * NHEADS;
  float* csum  = acum  + (size_t)BATCH * NHEADS * SEQLEN;
  float* stloc = csum  + (size_t)BATCH * NHEADS * NCHUNKS;
  float* stpre = stloc + (size_t)BATCH * NCHUNKS * NHEADS * 256;

  cvt3_kernel<<<224, 256, 0, stream>>>(W_in, Wi_b, (long)D_IN_PROJ * D_MODEL,
                                       W_out, Wo_b, (long)D_MODEL * D_INNER,
                                       W_in_b, Wib_b, (long)D_STATE * D_MODEL);
  gemm_bf16<true, true, true><<<dim3(7, ROWS / 128), 256, 0, stream>>>(
      u, Wi_b, nullptr, ROWS, D_IN_PROJ, D_MODEL, zbuf, xT, Braw, draw);
  gemm_bf16<true, true, false><<<dim3(1, ROWS / 128), 256, 0, stream>>>(
      support, Wib_b, craw, ROWS, D_STATE, D_MODEL, nullptr, nullptr, nullptr, nullptr);
  conv_bcdt<<<CBC_NB + CDT_NB, 256, 0, stream>>>(
      Braw, craw, draw, conv_w, conv_b, conv_w_b, conv_b_b, dt_bias, Bo, Co, dtoT);
  ssd_mfma_kernel<<<dim3(NHEADS, NCHUNKS, BATCH), 512, 0, stream>>>(
      xT, Bo, Co, dtoT, A_log, conv_w, conv_b, Dvec, YdT, acum, csum, stloc);
  chunk_scan_kernel<<<BATCH * NHEADS, 256, 0, stream>>>(stloc, csum, stpre);
  yoff_norm_gemm<<<ROWS / TT, 768, 0, stream>>>(YdT, Co, acum, stpre, zbuf, norm_w,
                                                Wo_b, out);
}

// Round 25
// 121.335 us; speedup vs baseline: 1.1310x; 1.0044x over previous
//
#include <hip/hip_runtime.h>
#include <cmath>

#define ROWS      16384
#define SEQLEN    8192
#define BATCH     2
#define NHEADS    24
#define HEADDIM   16
#define D_STATE   16
#define D_INNER   384
#define D_MODEL   192
#define D_IN_PROJ 808
#define CONV_DIM  400
#define NCHUNKS   32
#define CHUNK     256
#define EPS       1e-5f
#define LOG2E     1.44269504088896f

typedef short bf16x8 __attribute__((ext_vector_type(8)));
typedef short bf16x4 __attribute__((ext_vector_type(4)));
typedef float f32x4  __attribute__((ext_vector_type(4)));
typedef unsigned short us4v __attribute__((ext_vector_type(4)));
typedef unsigned short us8v __attribute__((ext_vector_type(8)));
typedef unsigned int  u32x4 __attribute__((ext_vector_type(4)));

#if __has_builtin(__builtin_amdgcn_mfma_f32_16x16x16bf16_1k)
#define MFMA16(a, b, c) __builtin_amdgcn_mfma_f32_16x16x16bf16_1k((a), (b), (c), 0, 0, 0)
#define HAVE_MFMA16 1
#elif __has_builtin(__builtin_amdgcn_mfma_f32_16x16x16_bf16)
#define MFMA16(a, b, c) __builtin_amdgcn_mfma_f32_16x16x16_bf16((a), (b), (c), 0, 0, 0)
#define HAVE_MFMA16 1
#else
#define HAVE_MFMA16 0
#endif

__device__ __forceinline__ float silu_f(float x) { return x / (1.0f + expf(-x)); }
__device__ __forceinline__ float softplus_f(float x) { return (x > 20.0f) ? x : log1pf(expf(x)); }
__device__ __forceinline__ unsigned short f2bf(float x) {
  unsigned u = __builtin_bit_cast(unsigned, x);
  u += 0x7fff + ((u >> 16) & 1);
  return (unsigned short)(u >> 16);
}
__device__ __forceinline__ float bf2f(unsigned short s) {
  unsigned u = (unsigned)s << 16;
  return __builtin_bit_cast(float, u);
}
__device__ __forceinline__ unsigned pk_bf(float a, float b) {
  unsigned ua = __builtin_bit_cast(unsigned, a) + 0x7fffu;
  unsigned ub = __builtin_bit_cast(unsigned, b) + 0x7fffu;
  return __builtin_amdgcn_perm(ub, ua, 0x07060302u);
}

// ---------------------------------------------------------------------------
// K0: fp32 -> bf16 weights (W_in, W_out, W_in_b)
// ---------------------------------------------------------------------------
__global__ __launch_bounds__(256)
void cvt3_kernel(const float* __restrict__ a, unsigned short* __restrict__ ao, long na,
                 const float* __restrict__ b, unsigned short* __restrict__ bo, long nb,
                 const float* __restrict__ c, unsigned short* __restrict__ co, long nc) {
  const long t0 = na >> 2, t1 = t0 + (nb >> 2), t2 = t1 + (nc >> 2);
  const long stride = (long)gridDim.x * blockDim.x;
  for (long i = (long)blockIdx.x * blockDim.x + threadIdx.x; i < t2; i += stride) {
    const float4* s; us4v* d; long j;
    if (i < t0)      { s = (const float4*)a; d = (us4v*)ao; j = i; }
    else if (i < t1) { s = (const float4*)b; d = (us4v*)bo; j = i - t0; }
    else             { s = (const float4*)c; d = (us4v*)co; j = i - t1; }
    float4 v = s[j];
    us4v o = { f2bf(v.x), f2bf(v.y), f2bf(v.z), f2bf(v.w) };
    d[j] = o;
  }
}

// ---------------------------------------------------------------------------
// MFMA bf16 GEMM. ROUTE=true: in-proj output split into consumer-native dense
// buffers (z->zbuf, x->head-major xT, Braw, draw).
// ---------------------------------------------------------------------------
template<bool A_F32, bool OUT_BF16, bool ROUTE>
__launch_bounds__(256, 3)
__global__ void gemm_bf16(const void* __restrict__ Ap,
                          const unsigned short* __restrict__ W,
                          void* __restrict__ Cp, int M, int N, int K,
                          unsigned short* __restrict__ zbuf,
                          unsigned short* __restrict__ xT,
                          unsigned short* __restrict__ Braw,
                          unsigned short* __restrict__ draw) {
  constexpr int BM = 128, BN = 128, BK = 32, LDK = 40;
  __shared__ unsigned short As[2][BM * LDK];
  __shared__ unsigned short Ws[2][BN * LDK];
  const int tid  = threadIdx.x;
  const int wid  = tid >> 6, lane = tid & 63;
  const int wr   = wid >> 1, wc = wid & 1;
  const int fr   = lane & 15, fq = lane >> 4;
  const long m0  = (long)blockIdx.y * BM;
  const int  n0  = blockIdx.x * BN;

  f32x4 acc[4][4] = {};

  auto stage = [&](int k0, int buf) {
    if (A_F32) {
      const float* A = (const float*)Ap;
#pragma unroll
      for (int p = 0; p < 2; ++p) {
        int flat = p * 2048 + tid * 8;
        int r = flat >> 5, c = flat & 31;
        const float4* src = (const float4*)(A + (m0 + r) * (long)K + k0 + c);
        float4 v0 = src[0], v1 = src[1];
        us8v o = { f2bf(v0.x), f2bf(v0.y), f2bf(v0.z), f2bf(v0.w),
                   f2bf(v1.x), f2bf(v1.y), f2bf(v1.z), f2bf(v1.w) };
        *(us8v*)&As[buf][r * LDK + c] = o;
      }
    } else {
      const unsigned short* A = (const unsigned short*)Ap;
#pragma unroll
      for (int p = 0; p < 2; ++p) {
        int flat = p * 2048 + tid * 8;
        int r = flat >> 5, c = flat & 31;
        us8v v = *(const us8v*)(A + (m0 + r) * (long)K + k0 + c);
        *(us8v*)&As[buf][r * LDK + c] = v;
      }
    }
#pragma unroll
    for (int p = 0; p < 2; ++p) {
      int flat = p * 2048 + tid * 8;
      int r = flat >> 5, c = flat & 31;
      int gn = n0 + r;
      us8v v = { 0, 0, 0, 0, 0, 0, 0, 0 };
      if (gn < N) v = *(const us8v*)(W + (long)gn * K + k0 + c);
      *(us8v*)&Ws[buf][r * LDK + c] = v;
    }
  };

  const int nk = K / BK;
  stage(0, 0);
  __syncthreads();
  for (int kt = 0; kt < nk; ++kt) {
    const int cur = kt & 1;
    if (kt + 1 < nk) stage((kt + 1) * BK, cur ^ 1);
    bf16x8 af[4], bfr[4];
#pragma unroll
    for (int m = 0; m < 4; ++m)
      af[m] = *(const bf16x8*)&As[cur][(wr * 64 + m * 16 + fr) * LDK + fq * 8];
#pragma unroll
    for (int n = 0; n < 4; ++n)
      bfr[n] = *(const bf16x8*)&Ws[cur][(wc * 64 + n * 16 + fr) * LDK + fq * 8];
#pragma unroll
    for (int m = 0; m < 4; ++m)
#pragma unroll
      for (int n = 0; n < 4; ++n)
        acc[m][n] = __builtin_amdgcn_mfma_f32_16x16x32_bf16(bfr[n], af[m], acc[m][n], 0, 0, 0);
    __syncthreads();
  }

#pragma unroll
  for (int m = 0; m < 4; ++m) {
    const long gm = m0 + wr * 64 + m * 16 + fr;
#pragma unroll
    for (int n = 0; n < 4; ++n) {
      const int gn = n0 + wc * 64 + n * 16 + fq * 4;
      if (gn < N) {
        if (ROUTE) {
          us4v o = { f2bf(acc[m][n][0]), f2bf(acc[m][n][1]),
                     f2bf(acc[m][n][2]), f2bf(acc[m][n][3]) };
          const int bb = (int)(gm >> 13);
          const long t = gm & 8191;
          if (gn < 384) {
            *(us4v*)(zbuf + gm * 384 + gn) = o;
          } else if (gn < 768) {
            const int c = gn - 384, hh = c >> 4, ii = c & 15;
            *(us4v*)(xT + (((size_t)(bb * NHEADS + hh) * SEQLEN + t) << 4) + ii) = o;
          } else if (gn < 784) {
            *(us4v*)(Braw + gm * 16 + (gn - 768)) = o;
          } else {
            *(us4v*)(draw + gm * 24 + (gn - 784)) = o;
          }
        } else if (OUT_BF16) {
          us4v o = { f2bf(acc[m][n][0]), f2bf(acc[m][n][1]),
                     f2bf(acc[m][n][2]), f2bf(acc[m][n][3]) };
          *(us4v*)((unsigned short*)Cp + gm * N + gn) = o;
        } else {
          float4 o = make_float4(acc[m][n][0], acc[m][n][1], acc[m][n][2], acc[m][n][3]);
          *(float4*)((float*)Cp + gm * N + gn) = o;
        }
      }
    }
  }
}

// ---------------------------------------------------------------------------
// K2: B/C conv + dt softplus, dense raw buffers. 448 role-pure blocks.
// ---------------------------------------------------------------------------
#define CBC_NB  (ROWS * 4 / 256)    // 256
#define CDT_NB  (ROWS * 3 / 256)    // 192

__global__ __launch_bounds__(256)
void conv_bcdt(const unsigned short* __restrict__ Braw, const unsigned short* __restrict__ craw,
               const unsigned short* __restrict__ draw,
               const float* __restrict__ conv_w, const float* __restrict__ conv_b,
               const float* __restrict__ conv_w_b, const float* __restrict__ conv_b_b,
               const float* __restrict__ dt_bias,
               unsigned short* __restrict__ Bo, unsigned short* __restrict__ Co,
               float* __restrict__ dtoT) {
  const int blk = blockIdx.x;
  const us8v z8 = { 0, 0, 0, 0, 0, 0, 0, 0 };

  if (blk < CBC_NB) {
    const int idx = blk * 256 + threadIdx.x;
    const int row = idx / 4, q = idx % 4;
    const int b = row / SEQLEN, t = row % SEQLEN;

    const unsigned short* src = (q < 2) ? Braw : craw;
    const float* cw = (q < 2) ? conv_w + 384 * 4 : conv_w_b;
    const float* cb = (q < 2) ? conv_b + 384 : conv_b_b;
    const int c0 = (q & 1) * 8;
    const unsigned short* base = src + (size_t)row * D_STATE + c0;
    us8v x0 = (t >= 3) ? *(const us8v*)(base - 3 * D_STATE) : z8;
    us8v x1 = (t >= 2) ? *(const us8v*)(base - 2 * D_STATE) : z8;
    us8v x2 = (t >= 1) ? *(const us8v*)(base - 1 * D_STATE) : z8;
    us8v x3 = *(const us8v*)base;
    us8v o;
#pragma unroll
    for (int ch = 0; ch < 8; ++ch) {
      const float4 wv = *(const float4*)(cw + (c0 + ch) * 4);
      float acc = cb[c0 + ch] + wv.x * bf2f(x0[ch]) + wv.y * bf2f(x1[ch])
                + wv.z * bf2f(x2[ch]) + wv.w * bf2f(x3[ch]);
      o[ch] = f2bf(silu_f(acc));
    }
    if (q < 2) *(us8v*)(Bo + (size_t)row * D_STATE + c0) = o;
    else       *(us8v*)(Co + (size_t)row * D_STATE + c0) = o;
  } else {
    const int idx = (blk - CBC_NB) * 256 + threadIdx.x;
    const int row = idx / 3, q = idx % 3;
    const int b = row / SEQLEN, t = row % SEQLEN;
    const int h0 = q * 8;
    us8v dv = *(const us8v*)(draw + (size_t)row * 24 + h0);
#pragma unroll
    for (int j = 0; j < 8; ++j) {
      float v = bf2f(dv[j]) + dt_bias[h0 + j];
      dtoT[(size_t)(b * NHEADS + h0 + j) * SEQLEN + t] = softplus_f(v);
    }
  }
}

// ---------------------------------------------------------------------------
// K3 (MFMA, 8 waves, fused x-conv, factored decay, K16 PV): unchanged.
// ---------------------------------------------------------------------------
__global__ __launch_bounds__(512, 4)
void ssd_mfma_kernel(const unsigned short* __restrict__ xT, const unsigned short* __restrict__ Bo,
                     const unsigned short* __restrict__ Co, const float* __restrict__ dtoT,
                     const float* __restrict__ A_log, const float* __restrict__ conv_w,
                     const float* __restrict__ conv_b, const float* __restrict__ Dvec,
                     unsigned short* __restrict__ YdT, float* __restrict__ acum_g,
                     float* __restrict__ csum_g, float* __restrict__ stloc) {
  const int h    = blockIdx.x;
  const int cidx = blockIdx.y;
  const int b    = blockIdx.z;
  const int tid  = threadIdx.x;
  const int wid  = tid >> 6, lane = tid & 63;
  const int fr   = lane & 15, g = lane >> 4;

  __shared__ unsigned short Bs[256 * 24 + 32];
  __shared__ unsigned short xsT[16 * 264];
  __shared__ unsigned short BwT[16 * 264];
  __shared__ unsigned short xraw[259 * 16 + 8];
  __shared__ float sc2[CHUNK];
  __shared__ float scE[16];
  __shared__ float wsum[4];

  const float Ah = -expf(A_log[h]);
  const us8v z8 = { 0, 0, 0, 0, 0, 0, 0, 0 };

  float v = 0.f;
  if (tid < CHUNK) {
    v = dtoT[(size_t)(b * NHEADS + h) * SEQLEN + (size_t)cidx * CHUNK + tid] * Ah;
#pragma unroll
    for (int off = 1; off < 64; off <<= 1) {
      float u = __shfl_up(v, off, 64);
      if (lane >= off) v += u;
    }
    if (lane == 63) wsum[wid] = v;
  }

  const int r  = tid >> 1;
  const int hf = tid & 1;
  const size_t rowbase = (size_t)b * SEQLEN + (size_t)cidx * CHUNK;
  const size_t rhrow = (size_t)(b * NHEADS + h) * SEQLEN + (size_t)cidx * CHUNK + r;
  const float rdtv = dtoT[rhrow];
  us8v bh = ((const us8v*)(Bo + (rowbase + r) * D_STATE))[hf];
  if (hf == 0) *(us8v*)&Bs[r * 24 + 16] = z8;
  if (tid < 32) Bs[256 * 24 + tid] = 0;
  {
    const int tg = cidx * CHUNK + r - 3;
    us8v xv = z8;
    if (tg >= 0)
      xv = *(const us8v*)(xT + (((size_t)(b * NHEADS + h) * SEQLEN + tg) << 4) + 8 * hf);
    *(us8v*)&xraw[r * 16 + 8 * hf] = xv;
    if (tid < 6) {
      const int rr2 = 256 + (tid >> 1);
      const int hf2 = tid & 1;
      const int tg2 = cidx * CHUNK + rr2 - 3;
      us8v xv2 = *(const us8v*)(xT + (((size_t)(b * NHEADS + h) * SEQLEN + tg2) << 4) + 8 * hf2);
      *(us8v*)&xraw[rr2 * 16 + 8 * hf2] = xv2;
    }
  }
  __syncthreads();   // #1

  us8v xsil, xdt8;
  {
    us8v tA = *(const us8v*)&xraw[(r + 0) * 16 + 8 * hf];
    us8v tB = *(const us8v*)&xraw[(r + 1) * 16 + 8 * hf];
    us8v tC = *(const us8v*)&xraw[(r + 2) * 16 + 8 * hf];
    us8v tD = *(const us8v*)&xraw[(r + 3) * 16 + 8 * hf];
    const int cbase = h * HEADDIM + 8 * hf;
#pragma unroll
    for (int ch = 0; ch < 8; ++ch) {
      const float4 wv = *(const float4*)(conv_w + (cbase + ch) * 4);
      float acc = conv_b[cbase + ch] + wv.x * bf2f(tA[ch]) + wv.y * bf2f(tB[ch])
                + wv.z * bf2f(tC[ch]) + wv.w * bf2f(tD[ch]);
      float sv = silu_f(acc);
      xsil[ch] = f2bf(sv);
      xdt8[ch] = f2bf(sv * rdtv);
    }
  }
  const float ctot  = wsum[0] + wsum[1] + wsum[2] + wsum[3];
  const float ctot2 = ctot * LOG2E;
  if (tid < CHUNK) {
    float pre = 0.f;
#pragma unroll
    for (int w = 0; w < 4; ++w) if (w < wid) pre += wsum[w];
    v += pre;
    sc2[tid] = v * LOG2E;
    acum_g[(size_t)(b * NHEADS + h) * SEQLEN + (size_t)cidx * CHUNK + tid] = v;
    if (tid == CHUNK - 1) csum_g[(b * NHEADS + h) * NCHUNKS + cidx] = v;
  }
  __syncthreads();   // #2

  *(us8v*)&xraw[(r + 3) * 16 + 8 * hf] = xsil;
#pragma unroll
  for (int q = 0; q < 8; ++q)
    xsT[(q + 8 * hf) * 264 + r] = xdt8[q];
  {
    const float wdv = exp2f(ctot2 - sc2[r]);
    const float ed  = exp2f(sc2[r | 15] - sc2[r]);   // <= 1
    us8v bscaled;
#pragma unroll
    for (int q = 0; q < 8; ++q) {
      BwT[(q + 8 * hf) * 264 + r] = f2bf(bf2f(bh[q]) * wdv);
      bscaled[q] = f2bf(bf2f(bh[q]) * ed);
    }
    *(us8v*)&Bs[r * 24 + 8 * hf] = bscaled;
  }
  if (tid < 16) scE[tid] = sc2[tid * 16 + 15];
  __syncthreads();   // #3 (last barrier)

  if (wid == 0) {
    f32x4 accS = {};
#pragma unroll
    for (int k2 = 0; k2 < 8; ++k2) {
      bf16x8 af = *(const bf16x8*)&BwT[fr * 264 + 32 * k2 + 8 * g];
      bf16x8 bb = *(const bf16x8*)&xsT[fr * 264 + 32 * k2 + 8 * g];
      accS = __builtin_amdgcn_mfma_f32_16x16x32_bf16(af, bb, accS, 0, 0, 0);
    }
    *(f32x4*)&stloc[((size_t)(b * NCHUNKS + cidx) * NHEADS + h) * 256 + fr * 16 + 4 * g] = accS;
  }

  const f32x4 zf = { 0.f, 0.f, 0.f, 0.f };
  const unsigned short* Cbase = Co + rowbase * D_STATE;
  const float Dh = Dvec[h];
  const int strips[2] = { wid, 15 - wid };

  bf16x8 brawq[2];
#pragma unroll
  for (int q = 0; q < 2; ++q) {
    us8v bv = z8;
    if (g < 2)
      bv = *(const us8v*)(Bo + (rowbase + strips[q] * 16 + fr) * D_STATE + 8 * g);
    brawq[q] = __builtin_bit_cast(bf16x8, bv);
  }

#if HAVE_MFMA16
#pragma unroll
  for (int q = 0; q < 2; ++q) {
    const int lt = strips[q];
    f32x4 acc = zf;
    bf16x8 cf = { 0, 0, 0, 0, 0, 0, 0, 0 };
    if (g < 2) cf = *(const bf16x8*)(Cbase + (size_t)(lt * 16 + fr) * D_STATE + 8 * g);
    const float acl2 = sc2[lt * 16 + fr];
    const int   lg   = lt * 16 + fr;
    for (int st = 0; st <= lt; ++st) {
      uint2 pp;
      if (st < lt) {
        bf16x8 bfg = *(const bf16x8*)&Bs[(st * 16 + fr) * 24 + 8 * g];
        f32x4 G = __builtin_amdgcn_mfma_f32_16x16x32_bf16(bfg, cf, zf, 0, 0, 0);
        const float wl = exp2f(acl2 - scE[st]);
        pp.x = pk_bf(G[0] * wl, G[1] * wl);
        pp.y = pk_bf(G[2] * wl, G[3] * wl);
      } else {
        f32x4 G = __builtin_amdgcn_mfma_f32_16x16x32_bf16(brawq[q], cf, zf, 0, 0, 0);
        f32x4 se2 = *(const f32x4*)&sc2[st * 16 + 4 * g];
        const int sbase = st * 16 + 4 * g;
        float w0 = (sbase + 0 <= lg) ? exp2f(acl2 - se2[0]) : 0.f;
        float w1 = (sbase + 1 <= lg) ? exp2f(acl2 - se2[1]) : 0.f;
        float w2 = (sbase + 2 <= lg) ? exp2f(acl2 - se2[2]) : 0.f;
        float w3 = (sbase + 3 <= lg) ? exp2f(acl2 - se2[3]) : 0.f;
        pp.x = pk_bf(G[0] * w0, G[1] * w1);
        pp.y = pk_bf(G[2] * w2, G[3] * w3);
      }
      const bf16x4 p4 = __builtin_bit_cast(bf16x4, pp);
      const bf16x4 x4 = *(const bf16x4*)&xsT[fr * 264 + st * 16 + 4 * g];
      acc = MFMA16(x4, p4, acc);
    }
    us4v xs4 = *(const us4v*)&xraw[(lt * 16 + fr + 3) * 16 + 4 * g];
    us4v o = { f2bf(acc[0] + Dh * bf2f(xs4[0])),
               f2bf(acc[1] + Dh * bf2f(xs4[1])),
               f2bf(acc[2] + Dh * bf2f(xs4[2])),
               f2bf(acc[3] + Dh * bf2f(xs4[3])) };
    *(us4v*)(YdT + (rhrow - r + (size_t)lt * 16 + fr) * HEADDIM + 4 * g) = o;
  }
#else
  const int Ls0 = fr + ((g & 1) << 5);
  const int Ls1 = Ls0 + 16;
  const bool hiq = (g >= 2);
#pragma unroll
  for (int q = 0; q < 2; ++q) {
    const int lt = strips[q];
    f32x4 acc = zf;
    bf16x8 cf = { 0, 0, 0, 0, 0, 0, 0, 0 };
    if (g < 2) cf = *(const bf16x8*)(Cbase + (size_t)(lt * 16 + fr) * D_STATE + 8 * g);
    const float acl2 = sc2[lt * 16 + fr];
    const int   lg   = lt * 16 + fr;
    const int npair = (lt + 2) >> 1;
    for (int sp = 0; sp < npair; ++sp) {
      uint2 pk[2];
#pragma unroll
      for (int ti = 0; ti < 2; ++ti) {
        const int st = 2 * sp + ti;
        if (st < lt) {
          bf16x8 bfg = *(const bf16x8*)&Bs[(st * 16 + fr) * 24 + 8 * g];
          f32x4 G = __builtin_amdgcn_mfma_f32_16x16x32_bf16(bfg, cf, zf, 0, 0, 0);
          const float wl = exp2f(acl2 - scE[st]);
          pk[ti].x = pk_bf(G[0] * wl, G[1] * wl);
          pk[ti].y = pk_bf(G[2] * wl, G[3] * wl);
        } else if (st == lt) {
          f32x4 G = __builtin_amdgcn_mfma_f32_16x16x32_bf16(brawq[q], cf, zf, 0, 0, 0);
          f32x4 se2 = *(const f32x4*)&sc2[st * 16 + 4 * g];
          const int sbase = st * 16 + 4 * g;
          float w0 = (sbase + 0 <= lg) ? exp2f(acl2 - se2[0]) : 0.f;
          float w1 = (sbase + 1 <= lg) ? exp2f(acl2 - se2[1]) : 0.f;
          float w2 = (sbase + 2 <= lg) ? exp2f(acl2 - se2[2]) : 0.f;
          float w3 = (sbase + 3 <= lg) ? exp2f(acl2 - se2[3]) : 0.f;
          pk[ti].x = pk_bf(G[0] * w0, G[1] * w1);
          pk[ti].y = pk_bf(G[2] * w2, G[3] * w3);
        } else {
          pk[ti].x = 0u; pk[ti].y = 0u;
        }
      }
      const int a00 = __shfl((int)pk[0].x, Ls0, 64);
      const int a10 = __shfl((int)pk[0].y, Ls0, 64);
      const int a01 = __shfl((int)pk[0].x, Ls1, 64);
      const int a11 = __shfl((int)pk[0].y, Ls1, 64);
      const int b00 = __shfl((int)pk[1].x, Ls0, 64);
      const int b10 = __shfl((int)pk[1].y, Ls0, 64);
      const int b01 = __shfl((int)pk[1].x, Ls1, 64);
      const int b11 = __shfl((int)pk[1].y, Ls1, 64);
      u32x4 pw;
      pw[0] = (unsigned)(hiq ? b00 : a00);
      pw[1] = (unsigned)(hiq ? b10 : a10);
      pw[2] = (unsigned)(hiq ? b01 : a01);
      pw[3] = (unsigned)(hiq ? b11 : a11);
      const bf16x8 pf = __builtin_bit_cast(bf16x8, pw);
      const bf16x8 xf = *(const bf16x8*)&xsT[fr * 264 + sp * 32 + 8 * g];
      acc = __builtin_amdgcn_mfma_f32_16x16x32_bf16(xf, pf, acc, 0, 0, 0);
    }
    us4v xs4 = *(const us4v*)&xraw[(lt * 16 + fr + 3) * 16 + 4 * g];
    us4v o = { f2bf(acc[0] + Dh * bf2f(xs4[0])),
               f2bf(acc[1] + Dh * bf2f(xs4[1])),
               f2bf(acc[2] + Dh * bf2f(xs4[2])),
               f2bf(acc[3] + Dh * bf2f(xs4[3])) };
    *(us4v*)(YdT + (rhrow - r + (size_t)lt * 16 + fr) * HEADDIM + 4 * g) = o;
  }
#endif
  // no tail barrier: waves retire independently
}

// ---------------------------------------------------------------------------
// K4: sequential inter-chunk state recurrence
// ---------------------------------------------------------------------------
__global__ __launch_bounds__(256)
void chunk_scan_kernel(const float* __restrict__ stloc, const float* __restrict__ csum_g,
                       float* __restrict__ stpre) {
  const int b  = blockIdx.x / NHEADS;
  const int h  = blockIdx.x % NHEADS;
  const int pn = threadIdx.x;
  float S = 0.0f;
  for (int c = 0; c < NCHUNKS; ++c) {
    const size_t idx = ((size_t)(b * NCHUNKS + c) * NHEADS + h) * 256 + pn;
    stpre[idx] = S;
    S = __expf(csum_g[(b * NHEADS + h) * NCHUNKS + c]) * S + stloc[idx];
  }
}

// ---------------------------------------------------------------------------
// K5 (fused, 12 waves): Y_off, silu(z) gate, RMSNorm, out = yn @ W_out^T.
// r25: z staged into LDS with one 16B load/thread (was 8 scalar 2B loads);
// exp(acum) precomputed once per (h,t) at staging (was 8x redundant/thread).
// ---------------------------------------------------------------------------
#define TT 16
#define LDY 392
__global__ __launch_bounds__(768)
void yoff_norm_gemm(const unsigned short* __restrict__ YdT,
                    const unsigned short* __restrict__ Co, const float* __restrict__ acum_g,
                    const float* __restrict__ stpre,
                    const unsigned short* __restrict__ zbuf, const float* __restrict__ norm_w,
                    const unsigned short* __restrict__ Wo,
                    float* __restrict__ out) {
  const int r0   = blockIdx.x * TT;
  const int b    = r0 / SEQLEN;
  const int t0   = r0 % SEQLEN;
  const int cidx = t0 / CHUNK;
  const int tid  = threadIdx.x;
  const int d    = tid % 384;            // channel
  const int half = tid / 384;            // row half
  const int h    = d >> 4, p = d & 15;
  const int wv   = tid >> 6;             // wave id 0..11

  __shared__ unsigned short Yt[NHEADS * TT * 16];
  __shared__ unsigned short zL[TT * 384];           // z tile (16B-vector staged)
  __shared__ unsigned short ynL[TT * LDY];
  __shared__ float At[NHEADS * TT];                 // exp(acum)
  __shared__ float Ct[TT * 16];
  __shared__ float red[TT][6];

  {
    us8v* Yt8 = (us8v*)Yt;
    int hh = tid >> 5, q = tid & 31;
    const size_t src = ((size_t)(b * NHEADS + hh) * SEQLEN + t0) * HEADDIM + q * 8;
    Yt8[tid] = *(const us8v*)(YdT + src);
    // z tile: 768 threads x one us8v = 16 rows x 384 ch
    const int zr = tid / 48, zc = (tid % 48) * 8;
    *(us8v*)&zL[zr * 384 + zc] = *(const us8v*)(zbuf + (size_t)(r0 + zr) * 384 + zc);
    if (tid < NHEADS * TT)
      At[tid] = __expf(acum_g[(size_t)(b * NHEADS + (tid >> 4)) * SEQLEN + t0 + (tid & 15)]);
    if (tid < TT * 16) Ct[tid] = bf2f(Co[(size_t)r0 * D_STATE + tid]);
  }

  float S[16];
  {
    const float* Sp = stpre + ((size_t)(b * NCHUNKS + cidx) * NHEADS + h) * 256 + p * 16;
#pragma unroll
    for (int q = 0; q < 4; ++q) {
      float4 v4 = *(const float4*)(Sp + 4 * q);
      S[4 * q + 0] = v4.x; S[4 * q + 1] = v4.y; S[4 * q + 2] = v4.z; S[4 * q + 3] = v4.w;
    }
  }
  const float nw = norm_w[d];
  __syncthreads();

  const int tb = half * 8;
  float yg[8];
#pragma unroll
  for (int ti = 0; ti < 8; ++ti) {
    const int tt = tb + ti;
    float dot = 0.f;
#pragma unroll
    for (int n = 0; n < 16; ++n) dot += Ct[tt * 16 + n] * S[n];
    const float eA = At[h * TT + tt];
    float y = bf2f(Yt[h * 256 + tt * 16 + p]) + eA * dot;
    const float z = bf2f(zL[tt * 384 + d]);
    yg[ti] = y * silu_f(z);
    float s = yg[ti] * yg[ti];
#pragma unroll
    for (int off = 32; off > 0; off >>= 1) s += __shfl_down(s, off);
    if ((tid & 63) == 0) red[tt][wv - half * 6] = s;
  }
  __syncthreads();

#pragma unroll
  for (int ti = 0; ti < 8; ++ti) {
    const int tt = tb + ti;
    const float tot = red[tt][0] + red[tt][1] + red[tt][2] + red[tt][3] + red[tt][4] + red[tt][5];
    const float scale = rsqrtf(tot * (1.0f / D_INNER) + EPS);
    ynL[tt * LDY + d] = f2bf(yg[ti] * scale * nw);
  }
  __syncthreads();

  // ---- GEMM phase: out[16][192] = ynL @ Wo^T; wave wv -> cols wv*16..+15 ----
  const int lane = tid & 63;
  const int fr = lane & 15, fq = lane >> 4;
  const int n0 = wv * 16;
  f32x4 accg = {};
  __builtin_amdgcn_s_setprio(1);
#pragma unroll
  for (int kt = 0; kt < 12; ++kt) {
    const bf16x8 af = *(const bf16x8*)&ynL[fr * LDY + kt * 32 + 8 * fq];
    const int col = n0 + fr;
    const bf16x8 bfr = *(const bf16x8*)(Wo + (size_t)col * D_INNER + kt * 32 + 8 * fq);
    accg = __builtin_amdgcn_mfma_f32_16x16x32_bf16(bfr, af, accg, 0, 0, 0);
  }
  __builtin_amdgcn_s_setprio(0);
  float4 o = make_float4(accg[0], accg[1], accg[2], accg[3]);
  *(float4*)(out + (size_t)(r0 + fr) * D_MODEL + n0 + fq * 4) = o;
}

// ---------------------------------------------------------------------------
extern "C" void kernel_launch(void* const* d_in, const int* in_sizes, int n_in,
                              void* d_out, int out_size, void* d_ws, size_t ws_size,
                              hipStream_t stream) {
  const float* u        = (const float*)d_in[0];
  const float* support  = (const float*)d_in[1];
  const float* W_in     = (const float*)d_in[2];
  const float* W_in_b   = (const float*)d_in[3];
  const float* conv_w   = (const float*)d_in[4];
  const float* conv_b   = (const float*)d_in[5];
  const float* conv_w_b = (const float*)d_in[6];
  const float* conv_b_b = (const float*)d_in[7];
  const float* dt_bias  = (const float*)d_in[8];
  const float* A_log    = (const float*)d_in[9];
  const float* Dvec     = (const float*)d_in[10];
  const float* norm_w   = (const float*)d_in[11];
  const float* W_out    = (const float*)d_in[12];
  float* out = (float*)d_out;
  char* wsb  = (char*)d_ws;

  unsigned short* Wi_b  = (unsigned short*)(wsb);
  unsigned short* Wo_b  = Wi_b + (size_t)D_IN_PROJ * D_MODEL;
  unsigned short* Wib_b = Wo_b + (size_t)D_MODEL * D_INNER;
  unsigned short* zbuf  = Wib_b + (size_t)D_STATE * D_MODEL;
  unsigned short* xT    = zbuf + (size_t)ROWS * D_INNER;
  unsigned short* Braw  = xT + (size_t)ROWS * D_INNER;
  unsigned short* draw  = Braw + (size_t)ROWS * D_STATE;
  unsigned short* craw  = draw + (size_t)ROWS * NHEADS;
  unsigned short* Bo    = craw + (size_t)ROWS * D_STATE;
  unsigned short* Co    = Bo + (size_t)ROWS * D_STATE;
  unsigned short* YdT   = Co + (size_t)ROWS * D_STATE;
  float* dtoT  = (float*)(YdT + (size_t)ROWS * D_INNER);
  float* acum  = dtoT  + (size_t)ROWS * NHEADS;
  float* csum  = acum  + (size_t)BATCH * NHEADS * SEQLEN;
  float* stloc = csum  + (size_t)BATCH * NHEADS * NCHUNKS;
  float* stpre = stloc + (size_t)BATCH * NCHUNKS * NHEADS * 256;

  cvt3_kernel<<<224, 256, 0, stream>>>(W_in, Wi_b, (long)D_IN_PROJ * D_MODEL,
                                       W_out, Wo_b, (long)D_MODEL * D_INNER,
                                       W_in_b, Wib_b, (long)D_STATE * D_MODEL);
  gemm_bf16<true, true, true><<<dim3(7, ROWS / 128), 256, 0, stream>>>(
      u, Wi_b, nullptr, ROWS, D_IN_PROJ, D_MODEL, zbuf, xT, Braw, draw);
  gemm_bf16<true, true, false><<<dim3(1, ROWS / 128), 256, 0, stream>>>(
      support, Wib_b, craw, ROWS, D_STATE, D_MODEL, nullptr, nullptr, nullptr, nullptr);
  conv_bcdt<<<CBC_NB + CDT_NB, 256, 0, stream>>>(
      Braw, craw, draw, conv_w, conv_b, conv_w_b, conv_b_b, dt_bias, Bo, Co, dtoT);
  ssd_mfma_kernel<<<dim3(NHEADS, NCHUNKS, BATCH), 512, 0, stream>>>(
      xT, Bo, Co, dtoT, A_log, conv_w, conv_b, Dvec, YdT, acum, csum, stloc);
  chunk_scan_kernel<<<BATCH * NHEADS, 256, 0, stream>>>(stloc, csum, stpre);
  yoff_norm_gemm<<<ROWS / TT, 768, 0, stream>>>(YdT, Co, acum, stpre, zbuf, norm_w,
                                                Wo_b, out);
}

// Round 26
// 115.156 us; speedup vs baseline: 1.1917x; 1.0537x over previous
//
#include <hip/hip_runtime.h>
#include <cmath>

#define ROWS      16384
#define SEQLEN    8192
#define BATCH     2
#define NHEADS    24
#define HEADDIM   16
#define D_STATE   16
#define D_INNER   384
#define D_MODEL   192
#define D_IN_PROJ 808
#define CONV_DIM  400
#define NCHUNKS   32
#define CHUNK     256
#define EPS       1e-5f
#define LOG2E     1.44269504088896f

typedef short bf16x8 __attribute__((ext_vector_type(8)));
typedef short bf16x4 __attribute__((ext_vector_type(4)));
typedef float f32x4  __attribute__((ext_vector_type(4)));
typedef unsigned short us4v __attribute__((ext_vector_type(4)));
typedef unsigned short us8v __attribute__((ext_vector_type(8)));
typedef unsigned int  u32x4 __attribute__((ext_vector_type(4)));

#if __has_builtin(__builtin_amdgcn_mfma_f32_16x16x16bf16_1k)
#define MFMA16(a, b, c) __builtin_amdgcn_mfma_f32_16x16x16bf16_1k((a), (b), (c), 0, 0, 0)
#define HAVE_MFMA16 1
#elif __has_builtin(__builtin_amdgcn_mfma_f32_16x16x16_bf16)
#define MFMA16(a, b, c) __builtin_amdgcn_mfma_f32_16x16x16_bf16((a), (b), (c), 0, 0, 0)
#define HAVE_MFMA16 1
#else
#define HAVE_MFMA16 0
#endif

__device__ __forceinline__ float silu_f(float x) { return x / (1.0f + expf(-x)); }
__device__ __forceinline__ float softplus_f(float x) { return (x > 20.0f) ? x : log1pf(expf(x)); }
__device__ __forceinline__ unsigned short f2bf(float x) {
  unsigned u = __builtin_bit_cast(unsigned, x);
  u += 0x7fff + ((u >> 16) & 1);
  return (unsigned short)(u >> 16);
}
__device__ __forceinline__ float bf2f(unsigned short s) {
  unsigned u = (unsigned)s << 16;
  return __builtin_bit_cast(float, u);
}
__device__ __forceinline__ unsigned pk_bf(float a, float b) {
  unsigned ua = __builtin_bit_cast(unsigned, a) + 0x7fffu;
  unsigned ub = __builtin_bit_cast(unsigned, b) + 0x7fffu;
  return __builtin_amdgcn_perm(ub, ua, 0x07060302u);
}

// ---------------------------------------------------------------------------
// K0: fp32 -> bf16 weights (W_in, W_out, W_in_b)
// ---------------------------------------------------------------------------
__global__ __launch_bounds__(256)
void cvt3_kernel(const float* __restrict__ a, unsigned short* __restrict__ ao, long na,
                 const float* __restrict__ b, unsigned short* __restrict__ bo, long nb,
                 const float* __restrict__ c, unsigned short* __restrict__ co, long nc) {
  const long t0 = na >> 2, t1 = t0 + (nb >> 2), t2 = t1 + (nc >> 2);
  const long stride = (long)gridDim.x * blockDim.x;
  for (long i = (long)blockIdx.x * blockDim.x + threadIdx.x; i < t2; i += stride) {
    const float4* s; us4v* d; long j;
    if (i < t0)      { s = (const float4*)a; d = (us4v*)ao; j = i; }
    else if (i < t1) { s = (const float4*)b; d = (us4v*)bo; j = i - t0; }
    else             { s = (const float4*)c; d = (us4v*)co; j = i - t1; }
    float4 v = s[j];
    us4v o = { f2bf(v.x), f2bf(v.y), f2bf(v.z), f2bf(v.w) };
    d[j] = o;
  }
}

// ---------------------------------------------------------------------------
// GEMM body (device fn; LDS passed in). ROUTE routes in-proj columns to
// consumer-native buffers; else bf16 plain store.
// ---------------------------------------------------------------------------
template<bool OUT_BF16, bool ROUTE>
__device__ __forceinline__
void gemm_body(unsigned short* __restrict__ As, unsigned short* __restrict__ Ws,
               const float* __restrict__ A, const unsigned short* __restrict__ W,
               void* __restrict__ Cp, int M, int N, int K, int bx, int by,
               unsigned short* __restrict__ zbuf, unsigned short* __restrict__ xT,
               unsigned short* __restrict__ Braw, unsigned short* __restrict__ draw) {
  constexpr int BM = 128, BN = 128, BK = 32, LDK = 40;
  const int tid  = threadIdx.x;
  const int wid  = tid >> 6, lane = tid & 63;
  const int wr   = wid >> 1, wc = wid & 1;
  const int fr   = lane & 15, fq = lane >> 4;
  const long m0  = (long)by * BM;
  const int  n0  = bx * BN;

  f32x4 acc[4][4] = {};

  auto stage = [&](int k0, int buf) {
#pragma unroll
    for (int p = 0; p < 2; ++p) {
      int flat = p * 2048 + tid * 8;
      int r = flat >> 5, c = flat & 31;
      const float4* src = (const float4*)(A + (m0 + r) * (long)K + k0 + c);
      float4 v0 = src[0], v1 = src[1];
      us8v o = { f2bf(v0.x), f2bf(v0.y), f2bf(v0.z), f2bf(v0.w),
                 f2bf(v1.x), f2bf(v1.y), f2bf(v1.z), f2bf(v1.w) };
      *(us8v*)&As[buf * BM * LDK + r * LDK + c] = o;
    }
#pragma unroll
    for (int p = 0; p < 2; ++p) {
      int flat = p * 2048 + tid * 8;
      int r = flat >> 5, c = flat & 31;
      int gn = n0 + r;
      us8v v = { 0, 0, 0, 0, 0, 0, 0, 0 };
      if (gn < N) v = *(const us8v*)(W + (long)gn * K + k0 + c);
      *(us8v*)&Ws[buf * BN * LDK + r * LDK + c] = v;
    }
  };

  const int nk = K / BK;
  stage(0, 0);
  __syncthreads();
  for (int kt = 0; kt < nk; ++kt) {
    const int cur = kt & 1;
    if (kt + 1 < nk) stage((kt + 1) * BK, cur ^ 1);
    bf16x8 af[4], bfr[4];
#pragma unroll
    for (int m = 0; m < 4; ++m)
      af[m] = *(const bf16x8*)&As[cur * BM * LDK + (wr * 64 + m * 16 + fr) * LDK + fq * 8];
#pragma unroll
    for (int n = 0; n < 4; ++n)
      bfr[n] = *(const bf16x8*)&Ws[cur * BN * LDK + (wc * 64 + n * 16 + fr) * LDK + fq * 8];
#pragma unroll
    for (int m = 0; m < 4; ++m)
#pragma unroll
      for (int n = 0; n < 4; ++n)
        acc[m][n] = __builtin_amdgcn_mfma_f32_16x16x32_bf16(bfr[n], af[m], acc[m][n], 0, 0, 0);
    __syncthreads();
  }

#pragma unroll
  for (int m = 0; m < 4; ++m) {
    const long gm = m0 + wr * 64 + m * 16 + fr;
#pragma unroll
    for (int n = 0; n < 4; ++n) {
      const int gn = n0 + wc * 64 + n * 16 + fq * 4;
      if (gn < N) {
        if (ROUTE) {
          us4v o = { f2bf(acc[m][n][0]), f2bf(acc[m][n][1]),
                     f2bf(acc[m][n][2]), f2bf(acc[m][n][3]) };
          const int bb = (int)(gm >> 13);
          const long t = gm & 8191;
          if (gn < 384) {
            *(us4v*)(zbuf + gm * 384 + gn) = o;
          } else if (gn < 768) {
            const int c = gn - 384, hh = c >> 4, ii = c & 15;
            *(us4v*)(xT + (((size_t)(bb * NHEADS + hh) * SEQLEN + t) << 4) + ii) = o;
          } else if (gn < 784) {
            *(us4v*)(Braw + gm * 16 + (gn - 768)) = o;
          } else {
            *(us4v*)(draw + gm * 24 + (gn - 784)) = o;
          }
        } else if (OUT_BF16) {
          us4v o = { f2bf(acc[m][n][0]), f2bf(acc[m][n][1]),
                     f2bf(acc[m][n][2]), f2bf(acc[m][n][3]) };
          *(us4v*)((unsigned short*)Cp + gm * N + gn) = o;
        } else {
          float4 o = make_float4(acc[m][n][0], acc[m][n][1], acc[m][n][2], acc[m][n][3]);
          *(float4*)((float*)Cp + gm * N + gn) = o;
        }
      }
    }
  }
}

// ---------------------------------------------------------------------------
// K1 (merged): bx<7 -> routed in-proj (u @ W_in^T); bx==7 -> support @ W_in_b^T
// into craw. K1b's 128 blocks fill K1a's tail; one launch boundary removed.
// ---------------------------------------------------------------------------
__global__ __launch_bounds__(256, 3)
void gemm_in_merged(const float* __restrict__ u, const unsigned short* __restrict__ Wi,
                    const float* __restrict__ support, const unsigned short* __restrict__ Wib,
                    unsigned short* __restrict__ craw,
                    unsigned short* __restrict__ zbuf, unsigned short* __restrict__ xT,
                    unsigned short* __restrict__ Braw, unsigned short* __restrict__ draw) {
  __shared__ unsigned short As[2 * 128 * 40];
  __shared__ unsigned short Ws[2 * 128 * 40];
  if (blockIdx.x < 7)
    gemm_body<true, true>(As, Ws, u, Wi, nullptr, ROWS, D_IN_PROJ, D_MODEL,
                          blockIdx.x, blockIdx.y, zbuf, xT, Braw, draw);
  else
    gemm_body<true, false>(As, Ws, support, Wib, craw, ROWS, D_STATE, D_MODEL,
                           0, blockIdx.y, nullptr, nullptr, nullptr, nullptr);
}

// ---------------------------------------------------------------------------
// K2: B/C conv + dt softplus, dense raw buffers. 448 role-pure blocks.
// ---------------------------------------------------------------------------
#define CBC_NB  (ROWS * 4 / 256)    // 256
#define CDT_NB  (ROWS * 3 / 256)    // 192

__global__ __launch_bounds__(256)
void conv_bcdt(const unsigned short* __restrict__ Braw, const unsigned short* __restrict__ craw,
               const unsigned short* __restrict__ draw,
               const float* __restrict__ conv_w, const float* __restrict__ conv_b,
               const float* __restrict__ conv_w_b, const float* __restrict__ conv_b_b,
               const float* __restrict__ dt_bias,
               unsigned short* __restrict__ Bo, unsigned short* __restrict__ Co,
               float* __restrict__ dtoT) {
  const int blk = blockIdx.x;
  const us8v z8 = { 0, 0, 0, 0, 0, 0, 0, 0 };

  if (blk < CBC_NB) {
    const int idx = blk * 256 + threadIdx.x;
    const int row = idx / 4, q = idx % 4;
    const int b = row / SEQLEN, t = row % SEQLEN;

    const unsigned short* src = (q < 2) ? Braw : craw;
    const float* cw = (q < 2) ? conv_w + 384 * 4 : conv_w_b;
    const float* cb = (q < 2) ? conv_b + 384 : conv_b_b;
    const int c0 = (q & 1) * 8;
    const unsigned short* base = src + (size_t)row * D_STATE + c0;
    us8v x0 = (t >= 3) ? *(const us8v*)(base - 3 * D_STATE) : z8;
    us8v x1 = (t >= 2) ? *(const us8v*)(base - 2 * D_STATE) : z8;
    us8v x2 = (t >= 1) ? *(const us8v*)(base - 1 * D_STATE) : z8;
    us8v x3 = *(const us8v*)base;
    us8v o;
#pragma unroll
    for (int ch = 0; ch < 8; ++ch) {
      const float4 wv = *(const float4*)(cw + (c0 + ch) * 4);
      float acc = cb[c0 + ch] + wv.x * bf2f(x0[ch]) + wv.y * bf2f(x1[ch])
                + wv.z * bf2f(x2[ch]) + wv.w * bf2f(x3[ch]);
      o[ch] = f2bf(silu_f(acc));
    }
    if (q < 2) *(us8v*)(Bo + (size_t)row * D_STATE + c0) = o;
    else       *(us8v*)(Co + (size_t)row * D_STATE + c0) = o;
  } else {
    const int idx = (blk - CBC_NB) * 256 + threadIdx.x;
    const int row = idx / 3, q = idx % 3;
    const int b = row / SEQLEN, t = row % SEQLEN;
    const int h0 = q * 8;
    us8v dv = *(const us8v*)(draw + (size_t)row * 24 + h0);
#pragma unroll
    for (int j = 0; j < 8; ++j) {
      float v = bf2f(dv[j]) + dt_bias[h0 + j];
      dtoT[(size_t)(b * NHEADS + h0 + j) * SEQLEN + t] = softplus_f(v);
    }
  }
}

// ---------------------------------------------------------------------------
// K3 (MFMA, 8 waves, fused x-conv, factored decay, K16 PV): unchanged.
// ---------------------------------------------------------------------------
__global__ __launch_bounds__(512, 4)
void ssd_mfma_kernel(const unsigned short* __restrict__ xT, const unsigned short* __restrict__ Bo,
                     const unsigned short* __restrict__ Co, const float* __restrict__ dtoT,
                     const float* __restrict__ A_log, const float* __restrict__ conv_w,
                     const float* __restrict__ conv_b, const float* __restrict__ Dvec,
                     unsigned short* __restrict__ YdT, float* __restrict__ acum_g,
                     float* __restrict__ csum_g, float* __restrict__ stloc) {
  const int h    = blockIdx.x;
  const int cidx = blockIdx.y;
  const int b    = blockIdx.z;
  const int tid  = threadIdx.x;
  const int wid  = tid >> 6, lane = tid & 63;
  const int fr   = lane & 15, g = lane >> 4;

  __shared__ unsigned short Bs[256 * 24 + 32];
  __shared__ unsigned short xsT[16 * 264];
  __shared__ unsigned short BwT[16 * 264];
  __shared__ unsigned short xraw[259 * 16 + 8];
  __shared__ float sc2[CHUNK];
  __shared__ float scE[16];
  __shared__ float wsum[4];

  const float Ah = -expf(A_log[h]);
  const us8v z8 = { 0, 0, 0, 0, 0, 0, 0, 0 };

  float v = 0.f;
  if (tid < CHUNK) {
    v = dtoT[(size_t)(b * NHEADS + h) * SEQLEN + (size_t)cidx * CHUNK + tid] * Ah;
#pragma unroll
    for (int off = 1; off < 64; off <<= 1) {
      float u = __shfl_up(v, off, 64);
      if (lane >= off) v += u;
    }
    if (lane == 63) wsum[wid] = v;
  }

  const int r  = tid >> 1;
  const int hf = tid & 1;
  const size_t rowbase = (size_t)b * SEQLEN + (size_t)cidx * CHUNK;
  const size_t rhrow = (size_t)(b * NHEADS + h) * SEQLEN + (size_t)cidx * CHUNK + r;
  const float rdtv = dtoT[rhrow];
  us8v bh = ((const us8v*)(Bo + (rowbase + r) * D_STATE))[hf];
  if (hf == 0) *(us8v*)&Bs[r * 24 + 16] = z8;
  if (tid < 32) Bs[256 * 24 + tid] = 0;
  {
    const int tg = cidx * CHUNK + r - 3;
    us8v xv = z8;
    if (tg >= 0)
      xv = *(const us8v*)(xT + (((size_t)(b * NHEADS + h) * SEQLEN + tg) << 4) + 8 * hf);
    *(us8v*)&xraw[r * 16 + 8 * hf] = xv;
    if (tid < 6) {
      const int rr2 = 256 + (tid >> 1);
      const int hf2 = tid & 1;
      const int tg2 = cidx * CHUNK + rr2 - 3;
      us8v xv2 = *(const us8v*)(xT + (((size_t)(b * NHEADS + h) * SEQLEN + tg2) << 4) + 8 * hf2);
      *(us8v*)&xraw[rr2 * 16 + 8 * hf2] = xv2;
    }
  }
  __syncthreads();   // #1

  us8v xsil, xdt8;
  {
    us8v tA = *(const us8v*)&xraw[(r + 0) * 16 + 8 * hf];
    us8v tB = *(const us8v*)&xraw[(r + 1) * 16 + 8 * hf];
    us8v tC = *(const us8v*)&xraw[(r + 2) * 16 + 8 * hf];
    us8v tD = *(const us8v*)&xraw[(r + 3) * 16 + 8 * hf];
    const int cbase = h * HEADDIM + 8 * hf;
#pragma unroll
    for (int ch = 0; ch < 8; ++ch) {
      const float4 wv = *(const float4*)(conv_w + (cbase + ch) * 4);
      float acc = conv_b[cbase + ch] + wv.x * bf2f(tA[ch]) + wv.y * bf2f(tB[ch])
                + wv.z * bf2f(tC[ch]) + wv.w * bf2f(tD[ch]);
      float sv = silu_f(acc);
      xsil[ch] = f2bf(sv);
      xdt8[ch] = f2bf(sv * rdtv);
    }
  }
  const float ctot  = wsum[0] + wsum[1] + wsum[2] + wsum[3];
  const float ctot2 = ctot * LOG2E;
  if (tid < CHUNK) {
    float pre = 0.f;
#pragma unroll
    for (int w = 0; w < 4; ++w) if (w < wid) pre += wsum[w];
    v += pre;
    sc2[tid] = v * LOG2E;
    acum_g[(size_t)(b * NHEADS + h) * SEQLEN + (size_t)cidx * CHUNK + tid] = v;
    if (tid == CHUNK - 1) csum_g[(b * NHEADS + h) * NCHUNKS + cidx] = v;
  }
  __syncthreads();   // #2

  *(us8v*)&xraw[(r + 3) * 16 + 8 * hf] = xsil;
#pragma unroll
  for (int q = 0; q < 8; ++q)
    xsT[(q + 8 * hf) * 264 + r] = xdt8[q];
  {
    const float wdv = exp2f(ctot2 - sc2[r]);
    const float ed  = exp2f(sc2[r | 15] - sc2[r]);   // <= 1
    us8v bscaled;
#pragma unroll
    for (int q = 0; q < 8; ++q) {
      BwT[(q + 8 * hf) * 264 + r] = f2bf(bf2f(bh[q]) * wdv);
      bscaled[q] = f2bf(bf2f(bh[q]) * ed);
    }
    *(us8v*)&Bs[r * 24 + 8 * hf] = bscaled;
  }
  if (tid < 16) scE[tid] = sc2[tid * 16 + 15];
  __syncthreads();   // #3 (last barrier)

  if (wid == 0) {
    f32x4 accS = {};
#pragma unroll
    for (int k2 = 0; k2 < 8; ++k2) {
      bf16x8 af = *(const bf16x8*)&BwT[fr * 264 + 32 * k2 + 8 * g];
      bf16x8 bb = *(const bf16x8*)&xsT[fr * 264 + 32 * k2 + 8 * g];
      accS = __builtin_amdgcn_mfma_f32_16x16x32_bf16(af, bb, accS, 0, 0, 0);
    }
    *(f32x4*)&stloc[((size_t)(b * NCHUNKS + cidx) * NHEADS + h) * 256 + fr * 16 + 4 * g] = accS;
  }

  const f32x4 zf = { 0.f, 0.f, 0.f, 0.f };
  const unsigned short* Cbase = Co + rowbase * D_STATE;
  const float Dh = Dvec[h];
  const int strips[2] = { wid, 15 - wid };

  bf16x8 brawq[2];
#pragma unroll
  for (int q = 0; q < 2; ++q) {
    us8v bv = z8;
    if (g < 2)
      bv = *(const us8v*)(Bo + (rowbase + strips[q] * 16 + fr) * D_STATE + 8 * g);
    brawq[q] = __builtin_bit_cast(bf16x8, bv);
  }

#if HAVE_MFMA16
#pragma unroll
  for (int q = 0; q < 2; ++q) {
    const int lt = strips[q];
    f32x4 acc = zf;
    bf16x8 cf = { 0, 0, 0, 0, 0, 0, 0, 0 };
    if (g < 2) cf = *(const bf16x8*)(Cbase + (size_t)(lt * 16 + fr) * D_STATE + 8 * g);
    const float acl2 = sc2[lt * 16 + fr];
    const int   lg   = lt * 16 + fr;
    for (int st = 0; st <= lt; ++st) {
      uint2 pp;
      if (st < lt) {
        bf16x8 bfg = *(const bf16x8*)&Bs[(st * 16 + fr) * 24 + 8 * g];
        f32x4 G = __builtin_amdgcn_mfma_f32_16x16x32_bf16(bfg, cf, zf, 0, 0, 0);
        const float wl = exp2f(acl2 - scE[st]);
        pp.x = pk_bf(G[0] * wl, G[1] * wl);
        pp.y = pk_bf(G[2] * wl, G[3] * wl);
      } else {
        f32x4 G = __builtin_amdgcn_mfma_f32_16x16x32_bf16(brawq[q], cf, zf, 0, 0, 0);
        f32x4 se2 = *(const f32x4*)&sc2[st * 16 + 4 * g];
        const int sbase = st * 16 + 4 * g;
        float w0 = (sbase + 0 <= lg) ? exp2f(acl2 - se2[0]) : 0.f;
        float w1 = (sbase + 1 <= lg) ? exp2f(acl2 - se2[1]) : 0.f;
        float w2 = (sbase + 2 <= lg) ? exp2f(acl2 - se2[2]) : 0.f;
        float w3 = (sbase + 3 <= lg) ? exp2f(acl2 - se2[3]) : 0.f;
        pp.x = pk_bf(G[0] * w0, G[1] * w1);
        pp.y = pk_bf(G[2] * w2, G[3] * w3);
      }
      const bf16x4 p4 = __builtin_bit_cast(bf16x4, pp);
      const bf16x4 x4 = *(const bf16x4*)&xsT[fr * 264 + st * 16 + 4 * g];
      acc = MFMA16(x4, p4, acc);
    }
    us4v xs4 = *(const us4v*)&xraw[(lt * 16 + fr + 3) * 16 + 4 * g];
    us4v o = { f2bf(acc[0] + Dh * bf2f(xs4[0])),
               f2bf(acc[1] + Dh * bf2f(xs4[1])),
               f2bf(acc[2] + Dh * bf2f(xs4[2])),
               f2bf(acc[3] + Dh * bf2f(xs4[3])) };
    *(us4v*)(YdT + (rhrow - r + (size_t)lt * 16 + fr) * HEADDIM + 4 * g) = o;
  }
#else
  const int Ls0 = fr + ((g & 1) << 5);
  const int Ls1 = Ls0 + 16;
  const bool hiq = (g >= 2);
#pragma unroll
  for (int q = 0; q < 2; ++q) {
    const int lt = strips[q];
    f32x4 acc = zf;
    bf16x8 cf = { 0, 0, 0, 0, 0, 0, 0, 0 };
    if (g < 2) cf = *(const bf16x8*)(Cbase + (size_t)(lt * 16 + fr) * D_STATE + 8 * g);
    const float acl2 = sc2[lt * 16 + fr];
    const int   lg   = lt * 16 + fr;
    const int npair = (lt + 2) >> 1;
    for (int sp = 0; sp < npair; ++sp) {
      uint2 pk[2];
#pragma unroll
      for (int ti = 0; ti < 2; ++ti) {
        const int st = 2 * sp + ti;
        if (st < lt) {
          bf16x8 bfg = *(const bf16x8*)&Bs[(st * 16 + fr) * 24 + 8 * g];
          f32x4 G = __builtin_amdgcn_mfma_f32_16x16x32_bf16(bfg, cf, zf, 0, 0, 0);
          const float wl = exp2f(acl2 - scE[st]);
          pk[ti].x = pk_bf(G[0] * wl, G[1] * wl);
          pk[ti].y = pk_bf(G[2] * wl, G[3] * wl);
        } else if (st == lt) {
          f32x4 G = __builtin_amdgcn_mfma_f32_16x16x32_bf16(brawq[q], cf, zf, 0, 0, 0);
          f32x4 se2 = *(const f32x4*)&sc2[st * 16 + 4 * g];
          const int sbase = st * 16 + 4 * g;
          float w0 = (sbase + 0 <= lg) ? exp2f(acl2 - se2[0]) : 0.f;
          float w1 = (sbase + 1 <= lg) ? exp2f(acl2 - se2[1]) : 0.f;
          float w2 = (sbase + 2 <= lg) ? exp2f(acl2 - se2[2]) : 0.f;
          float w3 = (sbase + 3 <= lg) ? exp2f(acl2 - se2[3]) : 0.f;
          pk[ti].x = pk_bf(G[0] * w0, G[1] * w1);
          pk[ti].y = pk_bf(G[2] * w2, G[3] * w3);
        } else {
          pk[ti].x = 0u; pk[ti].y = 0u;
        }
      }
      const int a00 = __shfl((int)pk[0].x, Ls0, 64);
      const int a10 = __shfl((int)pk[0].y, Ls0, 64);
      const int a01 = __shfl((int)pk[0].x, Ls1, 64);
      const int a11 = __shfl((int)pk[0].y, Ls1, 64);
      const int b00 = __shfl((int)pk[1].x, Ls0, 64);
      const int b10 = __shfl((int)pk[1].y, Ls0, 64);
      const int b01 = __shfl((int)pk[1].x, Ls1, 64);
      const int b11 = __shfl((int)pk[1].y, Ls1, 64);
      u32x4 pw;
      pw[0] = (unsigned)(hiq ? b00 : a00);
      pw[1] = (unsigned)(hiq ? b10 : a10);
      pw[2] = (unsigned)(hiq ? b01 : a01);
      pw[3] = (unsigned)(hiq ? b11 : a11);
      const bf16x8 pf = __builtin_bit_cast(bf16x8, pw);
      const bf16x8 xf = *(const bf16x8*)&xsT[fr * 264 + sp * 32 + 8 * g];
      acc = __builtin_amdgcn_mfma_f32_16x16x32_bf16(xf, pf, acc, 0, 0, 0);
    }
    us4v xs4 = *(const us4v*)&xraw[(lt * 16 + fr + 3) * 16 + 4 * g];
    us4v o = { f2bf(acc[0] + Dh * bf2f(xs4[0])),
               f2bf(acc[1] + Dh * bf2f(xs4[1])),
               f2bf(acc[2] + Dh * bf2f(xs4[2])),
               f2bf(acc[3] + Dh * bf2f(xs4[3])) };
    *(us4v*)(YdT + (rhrow - r + (size_t)lt * 16 + fr) * HEADDIM + 4 * g) = o;
  }
#endif
  // no tail barrier: waves retire independently
}

// ---------------------------------------------------------------------------
// K4: sequential inter-chunk state recurrence
// ---------------------------------------------------------------------------
__global__ __launch_bounds__(256)
void chunk_scan_kernel(const float* __restrict__ stloc, const float* __restrict__ csum_g,
                       float* __restrict__ stpre) {
  const int b  = blockIdx.x / NHEADS;
  const int h  = blockIdx.x % NHEADS;
  const int pn = threadIdx.x;
  float S = 0.0f;
  for (int c = 0; c < NCHUNKS; ++c) {
    const size_t idx = ((size_t)(b * NCHUNKS + c) * NHEADS + h) * 256 + pn;
    stpre[idx] = S;
    S = __expf(csum_g[(b * NHEADS + h) * NCHUNKS + c]) * S + stloc[idx];
  }
}

// ---------------------------------------------------------------------------
// K5 (fused, 12 waves): Y_off, silu(z) gate, RMSNorm, out = yn @ W_out^T.
// ---------------------------------------------------------------------------
#define TT 16
#define LDY 392
__global__ __launch_bounds__(768)
void yoff_norm_gemm(const unsigned short* __restrict__ YdT,
                    const unsigned short* __restrict__ Co, const float* __restrict__ acum_g,
                    const float* __restrict__ stpre,
                    const unsigned short* __restrict__ zbuf, const float* __restrict__ norm_w,
                    const unsigned short* __restrict__ Wo,
                    float* __restrict__ out) {
  const int r0   = blockIdx.x * TT;
  const int b    = r0 / SEQLEN;
  const int t0   = r0 % SEQLEN;
  const int cidx = t0 / CHUNK;
  const int tid  = threadIdx.x;
  const int d    = tid % 384;
  const int half = tid / 384;
  const int h    = d >> 4, p = d & 15;
  const int wv   = tid >> 6;

  __shared__ unsigned short Yt[NHEADS * TT * 16];
  __shared__ unsigned short zL[TT * 384];
  __shared__ unsigned short ynL[TT * LDY];
  __shared__ float At[NHEADS * TT];
  __shared__ float Ct[TT * 16];
  __shared__ float red[TT][6];

  {
    us8v* Yt8 = (us8v*)Yt;
    int hh = tid >> 5, q = tid & 31;
    const size_t src = ((size_t)(b * NHEADS + hh) * SEQLEN + t0) * HEADDIM + q * 8;
    Yt8[tid] = *(const us8v*)(YdT + src);
    const int zr = tid / 48, zc = (tid % 48) * 8;
    *(us8v*)&zL[zr * 384 + zc] = *(const us8v*)(zbuf + (size_t)(r0 + zr) * 384 + zc);
    if (tid < NHEADS * TT)
      At[tid] = __expf(acum_g[(size_t)(b * NHEADS + (tid >> 4)) * SEQLEN + t0 + (tid & 15)]);
    if (tid < TT * 16) Ct[tid] = bf2f(Co[(size_t)r0 * D_STATE + tid]);
  }

  float S[16];
  {
    const float* Sp = stpre + ((size_t)(b * NCHUNKS + cidx) * NHEADS + h) * 256 + p * 16;
#pragma unroll
    for (int q = 0; q < 4; ++q) {
      float4 v4 = *(const float4*)(Sp + 4 * q);
      S[4 * q + 0] = v4.x; S[4 * q + 1] = v4.y; S[4 * q + 2] = v4.z; S[4 * q + 3] = v4.w;
    }
  }
  const float nw = norm_w[d];
  __syncthreads();

  const int tb = half * 8;
  float yg[8];
#pragma unroll
  for (int ti = 0; ti < 8; ++ti) {
    const int tt = tb + ti;
    float dot = 0.f;
#pragma unroll
    for (int n = 0; n < 16; ++n) dot += Ct[tt * 16 + n] * S[n];
    const float eA = At[h * TT + tt];
    float y = bf2f(Yt[h * 256 + tt * 16 + p]) + eA * dot;
    const float z = bf2f(zL[tt * 384 + d]);
    yg[ti] = y * silu_f(z);
    float s = yg[ti] * yg[ti];
#pragma unroll
    for (int off = 32; off > 0; off >>= 1) s += __shfl_down(s, off);
    if ((tid & 63) == 0) red[tt][wv - half * 6] = s;
  }
  __syncthreads();

#pragma unroll
  for (int ti = 0; ti < 8; ++ti) {
    const int tt = tb + ti;
    const float tot = red[tt][0] + red[tt][1] + red[tt][2] + red[tt][3] + red[tt][4] + red[tt][5];
    const float scale = rsqrtf(tot * (1.0f / D_INNER) + EPS);
    ynL[tt * LDY + d] = f2bf(yg[ti] * scale * nw);
  }
  __syncthreads();

  const int lane = tid & 63;
  const int fr = lane & 15, fq = lane >> 4;
  const int n0 = wv * 16;
  f32x4 accg = {};
  __builtin_amdgcn_s_setprio(1);
#pragma unroll
  for (int kt = 0; kt < 12; ++kt) {
    const bf16x8 af = *(const bf16x8*)&ynL[fr * LDY + kt * 32 + 8 * fq];
    const int col = n0 + fr;
    const bf16x8 bfr = *(const bf16x8*)(Wo + (size_t)col * D_INNER + kt * 32 + 8 * fq);
    accg = __builtin_amdgcn_mfma_f32_16x16x32_bf16(bfr, af, accg, 0, 0, 0);
  }
  __builtin_amdgcn_s_setprio(0);
  float4 o = make_float4(accg[0], accg[1], accg[2], accg[3]);
  *(float4*)(out + (size_t)(r0 + fr) * D_MODEL + n0 + fq * 4) = o;
}

// ---------------------------------------------------------------------------
extern "C" void kernel_launch(void* const* d_in, const int* in_sizes, int n_in,
                              void* d_out, int out_size, void* d_ws, size_t ws_size,
                              hipStream_t stream) {
  const float* u        = (const float*)d_in[0];
  const float* support  = (const float*)d_in[1];
  const float* W_in     = (const float*)d_in[2];
  const float* W_in_b   = (const float*)d_in[3];
  const float* conv_w   = (const float*)d_in[4];
  const float* conv_b   = (const float*)d_in[5];
  const float* conv_w_b = (const float*)d_in[6];
  const float* conv_b_b = (const float*)d_in[7];
  const float* dt_bias  = (const float*)d_in[8];
  const float* A_log    = (const float*)d_in[9];
  const float* Dvec     = (const float*)d_in[10];
  const float* norm_w   = (const float*)d_in[11];
  const float* W_out    = (const float*)d_in[12];
  float* out = (float*)d_out;
  char* wsb  = (char*)d_ws;

  unsigned short* Wi_b  = (unsigned short*)(wsb);
  unsigned short* Wo_b  = Wi_b + (size_t)D_IN_PROJ * D_MODEL;
  unsigned short* Wib_b = Wo_b + (size_t)D_MODEL * D_INNER;
  unsigned short* zbuf  = Wib_b + (size_t)D_STATE * D_MODEL;
  unsigned short* xT    = zbuf + (size_t)ROWS * D_INNER;
  unsigned short* Braw  = xT + (size_t)ROWS * D_INNER;
  unsigned short* draw  = Braw + (size_t)ROWS * D_STATE;
  unsigned short* craw  = draw + (size_t)ROWS * NHEADS;
  unsigned short* Bo    = craw + (size_t)ROWS * D_STATE;
  unsigned short* Co    = Bo + (size_t)ROWS * D_STATE;
  unsigned short* YdT   = Co + (size_t)ROWS * D_STATE;
  float* dtoT  = (float*)(YdT + (size_t)ROWS * D_INNER);
  float* acum  = dtoT  + (size_t)ROWS * NHEADS;
  float* csum  = acum  + (size_t)BATCH * NHEADS * SEQLEN;
  float* stloc = csum  + (size_t)BATCH * NHEADS * NCHUNKS;
  float* stpre = stloc + (size_t)BATCH * NCHUNKS * NHEADS * 256;

  cvt3_kernel<<<224, 256, 0, stream>>>(W_in, Wi_b, (long)D_IN_PROJ * D_MODEL,
                                       W_out, Wo_b, (long)D_MODEL * D_INNER,
                                       W_in_b, Wib_b, (long)D_STATE * D_MODEL);
  gemm_in_merged<<<dim3(8, ROWS / 128), 256, 0, stream>>>(
      u, Wi_b, support, Wib_b, craw, zbuf, xT, Braw, draw);
  conv_bcdt<<<CBC_NB + CDT_NB, 256, 0, stream>>>(
      Braw, craw, draw, conv_w, conv_b, conv_w_b, conv_b_b, dt_bias, Bo, Co, dtoT);
  ssd_mfma_kernel<<<dim3(NHEADS, NCHUNKS, BATCH), 512, 0, stream>>>(
      xT, Bo, Co, dtoT, A_log, conv_w, conv_b, Dvec, YdT, acum, csum, stloc);
  chunk_scan_kernel<<<BATCH * NHEADS, 256, 0, stream>>>(stloc, csum, stpre);
  yoff_norm_gemm<<<ROWS / TT, 768, 0, stream>>>(YdT, Co, acum, stpre, zbuf, norm_w,
                                                Wo_b, out);
}

// Round 27
// 114.935 us; speedup vs baseline: 1.1940x; 1.0019x over previous
//
#include <hip/hip_runtime.h>
#include <cmath>

#define ROWS      16384
#define SEQLEN    8192
#define BATCH     2
#define NHEADS    24
#define HEADDIM   16
#define D_STATE   16
#define D_INNER   384
#define D_MODEL   192
#define D_IN_PROJ 808
#define CONV_DIM  400
#define NCHUNKS   32
#define CHUNK     256
#define EPS       1e-5f
#define LOG2E     1.44269504088896f

typedef short bf16x8 __attribute__((ext_vector_type(8)));
typedef short bf16x4 __attribute__((ext_vector_type(4)));
typedef float f32x4  __attribute__((ext_vector_type(4)));
typedef unsigned short us4v __attribute__((ext_vector_type(4)));
typedef unsigned short us8v __attribute__((ext_vector_type(8)));
typedef unsigned int  u32x4 __attribute__((ext_vector_type(4)));

#if __has_builtin(__builtin_amdgcn_mfma_f32_16x16x16bf16_1k)
#define MFMA16(a, b, c) __builtin_amdgcn_mfma_f32_16x16x16bf16_1k((a), (b), (c), 0, 0, 0)
#define HAVE_MFMA16 1
#elif __has_builtin(__builtin_amdgcn_mfma_f32_16x16x16_bf16)
#define MFMA16(a, b, c) __builtin_amdgcn_mfma_f32_16x16x16_bf16((a), (b), (c), 0, 0, 0)
#define HAVE_MFMA16 1
#else
#define HAVE_MFMA16 0
#endif

__device__ __forceinline__ float silu_f(float x) { return x / (1.0f + expf(-x)); }
__device__ __forceinline__ float softplus_f(float x) { return (x > 20.0f) ? x : log1pf(expf(x)); }
__device__ __forceinline__ unsigned short f2bf(float x) {
  unsigned u = __builtin_bit_cast(unsigned, x);
  u += 0x7fff + ((u >> 16) & 1);
  return (unsigned short)(u >> 16);
}
__device__ __forceinline__ float bf2f(unsigned short s) {
  unsigned u = (unsigned)s << 16;
  return __builtin_bit_cast(float, u);
}
__device__ __forceinline__ unsigned pk_bf(float a, float b) {
  unsigned ua = __builtin_bit_cast(unsigned, a) + 0x7fffu;
  unsigned ub = __builtin_bit_cast(unsigned, b) + 0x7fffu;
  return __builtin_amdgcn_perm(ub, ua, 0x07060302u);
}

// ---------------------------------------------------------------------------
// K0: fp32 -> bf16 weights (W_in, W_out, W_in_b)
// ---------------------------------------------------------------------------
__global__ __launch_bounds__(256)
void cvt3_kernel(const float* __restrict__ a, unsigned short* __restrict__ ao, long na,
                 const float* __restrict__ b, unsigned short* __restrict__ bo, long nb,
                 const float* __restrict__ c, unsigned short* __restrict__ co, long nc) {
  const long t0 = na >> 2, t1 = t0 + (nb >> 2), t2 = t1 + (nc >> 2);
  const long stride = (long)gridDim.x * blockDim.x;
  for (long i = (long)blockIdx.x * blockDim.x + threadIdx.x; i < t2; i += stride) {
    const float4* s; us4v* d; long j;
    if (i < t0)      { s = (const float4*)a; d = (us4v*)ao; j = i; }
    else if (i < t1) { s = (const float4*)b; d = (us4v*)bo; j = i - t0; }
    else             { s = (const float4*)c; d = (us4v*)co; j = i - t1; }
    float4 v = s[j];
    us4v o = { f2bf(v.x), f2bf(v.y), f2bf(v.z), f2bf(v.w) };
    d[j] = o;
  }
}

// ---------------------------------------------------------------------------
// GEMM body (device fn; LDS passed in).
// ---------------------------------------------------------------------------
template<bool OUT_BF16, bool ROUTE>
__device__ __forceinline__
void gemm_body(unsigned short* __restrict__ As, unsigned short* __restrict__ Ws,
               const float* __restrict__ A, const unsigned short* __restrict__ W,
               void* __restrict__ Cp, int M, int N, int K, int bx, int by,
               unsigned short* __restrict__ zbuf, unsigned short* __restrict__ xT,
               unsigned short* __restrict__ Braw, unsigned short* __restrict__ draw) {
  constexpr int BM = 128, BN = 128, BK = 32, LDK = 40;
  const int tid  = threadIdx.x;
  const int wid  = tid >> 6, lane = tid & 63;
  const int wr   = wid >> 1, wc = wid & 1;
  const int fr   = lane & 15, fq = lane >> 4;
  const long m0  = (long)by * BM;
  const int  n0  = bx * BN;

  f32x4 acc[4][4] = {};

  auto stage = [&](int k0, int buf) {
#pragma unroll
    for (int p = 0; p < 2; ++p) {
      int flat = p * 2048 + tid * 8;
      int r = flat >> 5, c = flat & 31;
      const float4* src = (const float4*)(A + (m0 + r) * (long)K + k0 + c);
      float4 v0 = src[0], v1 = src[1];
      us8v o = { f2bf(v0.x), f2bf(v0.y), f2bf(v0.z), f2bf(v0.w),
                 f2bf(v1.x), f2bf(v1.y), f2bf(v1.z), f2bf(v1.w) };
      *(us8v*)&As[buf * BM * LDK + r * LDK + c] = o;
    }
#pragma unroll
    for (int p = 0; p < 2; ++p) {
      int flat = p * 2048 + tid * 8;
      int r = flat >> 5, c = flat & 31;
      int gn = n0 + r;
      us8v v = { 0, 0, 0, 0, 0, 0, 0, 0 };
      if (gn < N) v = *(const us8v*)(W + (long)gn * K + k0 + c);
      *(us8v*)&Ws[buf * BN * LDK + r * LDK + c] = v;
    }
  };

  const int nk = K / BK;
  stage(0, 0);
  __syncthreads();
  for (int kt = 0; kt < nk; ++kt) {
    const int cur = kt & 1;
    if (kt + 1 < nk) stage((kt + 1) * BK, cur ^ 1);
    bf16x8 af[4], bfr[4];
#pragma unroll
    for (int m = 0; m < 4; ++m)
      af[m] = *(const bf16x8*)&As[cur * BM * LDK + (wr * 64 + m * 16 + fr) * LDK + fq * 8];
#pragma unroll
    for (int n = 0; n < 4; ++n)
      bfr[n] = *(const bf16x8*)&Ws[cur * BN * LDK + (wc * 64 + n * 16 + fr) * LDK + fq * 8];
#pragma unroll
    for (int m = 0; m < 4; ++m)
#pragma unroll
      for (int n = 0; n < 4; ++n)
        acc[m][n] = __builtin_amdgcn_mfma_f32_16x16x32_bf16(bfr[n], af[m], acc[m][n], 0, 0, 0);
    __syncthreads();
  }

#pragma unroll
  for (int m = 0; m < 4; ++m) {
    const long gm = m0 + wr * 64 + m * 16 + fr;
#pragma unroll
    for (int n = 0; n < 4; ++n) {
      const int gn = n0 + wc * 64 + n * 16 + fq * 4;
      if (gn < N) {
        if (ROUTE) {
          us4v o = { f2bf(acc[m][n][0]), f2bf(acc[m][n][1]),
                     f2bf(acc[m][n][2]), f2bf(acc[m][n][3]) };
          const int bb = (int)(gm >> 13);
          const long t = gm & 8191;
          if (gn < 384) {
            *(us4v*)(zbuf + gm * 384 + gn) = o;
          } else if (gn < 768) {
            const int c = gn - 384, hh = c >> 4, ii = c & 15;
            *(us4v*)(xT + (((size_t)(bb * NHEADS + hh) * SEQLEN + t) << 4) + ii) = o;
          } else if (gn < 784) {
            *(us4v*)(Braw + gm * 16 + (gn - 768)) = o;
          } else {
            *(us4v*)(draw + gm * 24 + (gn - 784)) = o;
          }
        } else if (OUT_BF16) {
          us4v o = { f2bf(acc[m][n][0]), f2bf(acc[m][n][1]),
                     f2bf(acc[m][n][2]), f2bf(acc[m][n][3]) };
          *(us4v*)((unsigned short*)Cp + gm * N + gn) = o;
        } else {
          float4 o = make_float4(acc[m][n][0], acc[m][n][1], acc[m][n][2], acc[m][n][3]);
          *(float4*)((float*)Cp + gm * N + gn) = o;
        }
      }
    }
  }
}

// ---------------------------------------------------------------------------
// K1 (merged): bx<7 -> routed in-proj (u @ W_in^T); bx==7 -> support @ W_in_b^T
// ---------------------------------------------------------------------------
__global__ __launch_bounds__(256, 3)
void gemm_in_merged(const float* __restrict__ u, const unsigned short* __restrict__ Wi,
                    const float* __restrict__ support, const unsigned short* __restrict__ Wib,
                    unsigned short* __restrict__ craw,
                    unsigned short* __restrict__ zbuf, unsigned short* __restrict__ xT,
                    unsigned short* __restrict__ Braw, unsigned short* __restrict__ draw) {
  __shared__ unsigned short As[2 * 128 * 40];
  __shared__ unsigned short Ws[2 * 128 * 40];
  if (blockIdx.x < 7)
    gemm_body<true, true>(As, Ws, u, Wi, nullptr, ROWS, D_IN_PROJ, D_MODEL,
                          blockIdx.x, blockIdx.y, zbuf, xT, Braw, draw);
  else
    gemm_body<true, false>(As, Ws, support, Wib, craw, ROWS, D_STATE, D_MODEL,
                           0, blockIdx.y, nullptr, nullptr, nullptr, nullptr);
}

// ---------------------------------------------------------------------------
// K2: B/C conv + dt softplus, dense raw buffers. 448 role-pure blocks.
// ---------------------------------------------------------------------------
#define CBC_NB  (ROWS * 4 / 256)    // 256
#define CDT_NB  (ROWS * 3 / 256)    // 192

__global__ __launch_bounds__(256)
void conv_bcdt(const unsigned short* __restrict__ Braw, const unsigned short* __restrict__ craw,
               const unsigned short* __restrict__ draw,
               const float* __restrict__ conv_w, const float* __restrict__ conv_b,
               const float* __restrict__ conv_w_b, const float* __restrict__ conv_b_b,
               const float* __restrict__ dt_bias,
               unsigned short* __restrict__ Bo, unsigned short* __restrict__ Co,
               float* __restrict__ dtoT) {
  const int blk = blockIdx.x;
  const us8v z8 = { 0, 0, 0, 0, 0, 0, 0, 0 };

  if (blk < CBC_NB) {
    const int idx = blk * 256 + threadIdx.x;
    const int row = idx / 4, q = idx % 4;
    const int b = row / SEQLEN, t = row % SEQLEN;

    const unsigned short* src = (q < 2) ? Braw : craw;
    const float* cw = (q < 2) ? conv_w + 384 * 4 : conv_w_b;
    const float* cb = (q < 2) ? conv_b + 384 : conv_b_b;
    const int c0 = (q & 1) * 8;
    const unsigned short* base = src + (size_t)row * D_STATE + c0;
    us8v x0 = (t >= 3) ? *(const us8v*)(base - 3 * D_STATE) : z8;
    us8v x1 = (t >= 2) ? *(const us8v*)(base - 2 * D_STATE) : z8;
    us8v x2 = (t >= 1) ? *(const us8v*)(base - 1 * D_STATE) : z8;
    us8v x3 = *(const us8v*)base;
    us8v o;
#pragma unroll
    for (int ch = 0; ch < 8; ++ch) {
      const float4 wv = *(const float4*)(cw + (c0 + ch) * 4);
      float acc = cb[c0 + ch] + wv.x * bf2f(x0[ch]) + wv.y * bf2f(x1[ch])
                + wv.z * bf2f(x2[ch]) + wv.w * bf2f(x3[ch]);
      o[ch] = f2bf(silu_f(acc));
    }
    if (q < 2) *(us8v*)(Bo + (size_t)row * D_STATE + c0) = o;
    else       *(us8v*)(Co + (size_t)row * D_STATE + c0) = o;
  } else {
    const int idx = (blk - CBC_NB) * 256 + threadIdx.x;
    const int row = idx / 3, q = idx % 3;
    const int b = row / SEQLEN, t = row % SEQLEN;
    const int h0 = q * 8;
    us8v dv = *(const us8v*)(draw + (size_t)row * 24 + h0);
#pragma unroll
    for (int j = 0; j < 8; ++j) {
      float v = bf2f(dv[j]) + dt_bias[h0 + j];
      dtoT[(size_t)(b * NHEADS + h0 + j) * SEQLEN + t] = softplus_f(v);
    }
  }
}

// ---------------------------------------------------------------------------
// K3 (MFMA, 8 waves, fused x-conv, factored decay, K16 PV):
// r27: 1D grid (1536) with XCD-aware remap so all 24 heads of a (b,chunk)
// land on one XCD -> shared Bo/Co chunk becomes XCD-L2-resident.
// ---------------------------------------------------------------------------
__global__ __launch_bounds__(512, 4)
void ssd_mfma_kernel(const unsigned short* __restrict__ xT, const unsigned short* __restrict__ Bo,
                     const unsigned short* __restrict__ Co, const float* __restrict__ dtoT,
                     const float* __restrict__ A_log, const float* __restrict__ conv_w,
                     const float* __restrict__ conv_b, const float* __restrict__ Dvec,
                     unsigned short* __restrict__ YdT, float* __restrict__ acum_g,
                     float* __restrict__ csum_g, float* __restrict__ stloc) {
  // XCD-aware bijective remap: 1536 blocks, 8 XCDs, 192 work items per XCD
  const int bid  = blockIdx.x;
  const int wrk  = (bid & 7) * 192 + (bid >> 3);
  const int b    = wrk / 768;
  const int rem  = wrk % 768;
  const int cidx = rem / NHEADS;
  const int h    = rem % NHEADS;
  const int tid  = threadIdx.x;
  const int wid  = tid >> 6, lane = tid & 63;
  const int fr   = lane & 15, g = lane >> 4;

  __shared__ unsigned short Bs[256 * 24 + 32];
  __shared__ unsigned short xsT[16 * 264];
  __shared__ unsigned short BwT[16 * 264];
  __shared__ unsigned short xraw[259 * 16 + 8];
  __shared__ float sc2[CHUNK];
  __shared__ float scE[16];
  __shared__ float wsum[4];

  const float Ah = -expf(A_log[h]);
  const us8v z8 = { 0, 0, 0, 0, 0, 0, 0, 0 };

  float v = 0.f;
  if (tid < CHUNK) {
    v = dtoT[(size_t)(b * NHEADS + h) * SEQLEN + (size_t)cidx * CHUNK + tid] * Ah;
#pragma unroll
    for (int off = 1; off < 64; off <<= 1) {
      float u = __shfl_up(v, off, 64);
      if (lane >= off) v += u;
    }
    if (lane == 63) wsum[wid] = v;
  }

  const int r  = tid >> 1;
  const int hf = tid & 1;
  const size_t rowbase = (size_t)b * SEQLEN + (size_t)cidx * CHUNK;
  const size_t rhrow = (size_t)(b * NHEADS + h) * SEQLEN + (size_t)cidx * CHUNK + r;
  const float rdtv = dtoT[rhrow];
  us8v bh = ((const us8v*)(Bo + (rowbase + r) * D_STATE))[hf];
  if (hf == 0) *(us8v*)&Bs[r * 24 + 16] = z8;
  if (tid < 32) Bs[256 * 24 + tid] = 0;
  {
    const int tg = cidx * CHUNK + r - 3;
    us8v xv = z8;
    if (tg >= 0)
      xv = *(const us8v*)(xT + (((size_t)(b * NHEADS + h) * SEQLEN + tg) << 4) + 8 * hf);
    *(us8v*)&xraw[r * 16 + 8 * hf] = xv;
    if (tid < 6) {
      const int rr2 = 256 + (tid >> 1);
      const int hf2 = tid & 1;
      const int tg2 = cidx * CHUNK + rr2 - 3;
      us8v xv2 = *(const us8v*)(xT + (((size_t)(b * NHEADS + h) * SEQLEN + tg2) << 4) + 8 * hf2);
      *(us8v*)&xraw[rr2 * 16 + 8 * hf2] = xv2;
    }
  }
  __syncthreads();   // #1

  us8v xsil, xdt8;
  {
    us8v tA = *(const us8v*)&xraw[(r + 0) * 16 + 8 * hf];
    us8v tB = *(const us8v*)&xraw[(r + 1) * 16 + 8 * hf];
    us8v tC = *(const us8v*)&xraw[(r + 2) * 16 + 8 * hf];
    us8v tD = *(const us8v*)&xraw[(r + 3) * 16 + 8 * hf];
    const int cbase = h * HEADDIM + 8 * hf;
#pragma unroll
    for (int ch = 0; ch < 8; ++ch) {
      const float4 wv = *(const float4*)(conv_w + (cbase + ch) * 4);
      float acc = conv_b[cbase + ch] + wv.x * bf2f(tA[ch]) + wv.y * bf2f(tB[ch])
                + wv.z * bf2f(tC[ch]) + wv.w * bf2f(tD[ch]);
      float sv = silu_f(acc);
      xsil[ch] = f2bf(sv);
      xdt8[ch] = f2bf(sv * rdtv);
    }
  }
  const float ctot  = wsum[0] + wsum[1] + wsum[2] + wsum[3];
  const float ctot2 = ctot * LOG2E;
  if (tid < CHUNK) {
    float pre = 0.f;
#pragma unroll
    for (int w = 0; w < 4; ++w) if (w < wid) pre += wsum[w];
    v += pre;
    sc2[tid] = v * LOG2E;
    acum_g[(size_t)(b * NHEADS + h) * SEQLEN + (size_t)cidx * CHUNK + tid] = v;
    if (tid == CHUNK - 1) csum_g[(b * NHEADS + h) * NCHUNKS + cidx] = v;
  }
  __syncthreads();   // #2

  *(us8v*)&xraw[(r + 3) * 16 + 8 * hf] = xsil;
#pragma unroll
  for (int q = 0; q < 8; ++q)
    xsT[(q + 8 * hf) * 264 + r] = xdt8[q];
  {
    const float wdv = exp2f(ctot2 - sc2[r]);
    const float ed  = exp2f(sc2[r | 15] - sc2[r]);   // <= 1
    us8v bscaled;
#pragma unroll
    for (int q = 0; q < 8; ++q) {
      BwT[(q + 8 * hf) * 264 + r] = f2bf(bf2f(bh[q]) * wdv);
      bscaled[q] = f2bf(bf2f(bh[q]) * ed);
    }
    *(us8v*)&Bs[r * 24 + 8 * hf] = bscaled;
  }
  if (tid < 16) scE[tid] = sc2[tid * 16 + 15];
  __syncthreads();   // #3 (last barrier)

  if (wid == 0) {
    f32x4 accS = {};
#pragma unroll
    for (int k2 = 0; k2 < 8; ++k2) {
      bf16x8 af = *(const bf16x8*)&BwT[fr * 264 + 32 * k2 + 8 * g];
      bf16x8 bb = *(const bf16x8*)&xsT[fr * 264 + 32 * k2 + 8 * g];
      accS = __builtin_amdgcn_mfma_f32_16x16x32_bf16(af, bb, accS, 0, 0, 0);
    }
    *(f32x4*)&stloc[((size_t)(b * NCHUNKS + cidx) * NHEADS + h) * 256 + fr * 16 + 4 * g] = accS;
  }

  const f32x4 zf = { 0.f, 0.f, 0.f, 0.f };
  const unsigned short* Cbase = Co + rowbase * D_STATE;
  const float Dh = Dvec[h];
  const int strips[2] = { wid, 15 - wid };

  bf16x8 brawq[2];
#pragma unroll
  for (int q = 0; q < 2; ++q) {
    us8v bv = z8;
    if (g < 2)
      bv = *(const us8v*)(Bo + (rowbase + strips[q] * 16 + fr) * D_STATE + 8 * g);
    brawq[q] = __builtin_bit_cast(bf16x8, bv);
  }

#if HAVE_MFMA16
#pragma unroll
  for (int q = 0; q < 2; ++q) {
    const int lt = strips[q];
    f32x4 acc = zf;
    bf16x8 cf = { 0, 0, 0, 0, 0, 0, 0, 0 };
    if (g < 2) cf = *(const bf16x8*)(Cbase + (size_t)(lt * 16 + fr) * D_STATE + 8 * g);
    const float acl2 = sc2[lt * 16 + fr];
    const int   lg   = lt * 16 + fr;
    for (int st = 0; st <= lt; ++st) {
      uint2 pp;
      if (st < lt) {
        bf16x8 bfg = *(const bf16x8*)&Bs[(st * 16 + fr) * 24 + 8 * g];
        f32x4 G = __builtin_amdgcn_mfma_f32_16x16x32_bf16(bfg, cf, zf, 0, 0, 0);
        const float wl = exp2f(acl2 - scE[st]);
        pp.x = pk_bf(G[0] * wl, G[1] * wl);
        pp.y = pk_bf(G[2] * wl, G[3] * wl);
      } else {
        f32x4 G = __builtin_amdgcn_mfma_f32_16x16x32_bf16(brawq[q], cf, zf, 0, 0, 0);
        f32x4 se2 = *(const f32x4*)&sc2[st * 16 + 4 * g];
        const int sbase = st * 16 + 4 * g;
        float w0 = (sbase + 0 <= lg) ? exp2f(acl2 - se2[0]) : 0.f;
        float w1 = (sbase + 1 <= lg) ? exp2f(acl2 - se2[1]) : 0.f;
        float w2 = (sbase + 2 <= lg) ? exp2f(acl2 - se2[2]) : 0.f;
        float w3 = (sbase + 3 <= lg) ? exp2f(acl2 - se2[3]) : 0.f;
        pp.x = pk_bf(G[0] * w0, G[1] * w1);
        pp.y = pk_bf(G[2] * w2, G[3] * w3);
      }
      const bf16x4 p4 = __builtin_bit_cast(bf16x4, pp);
      const bf16x4 x4 = *(const bf16x4*)&xsT[fr * 264 + st * 16 + 4 * g];
      acc = MFMA16(x4, p4, acc);
    }
    us4v xs4 = *(const us4v*)&xraw[(lt * 16 + fr + 3) * 16 + 4 * g];
    us4v o = { f2bf(acc[0] + Dh * bf2f(xs4[0])),
               f2bf(acc[1] + Dh * bf2f(xs4[1])),
               f2bf(acc[2] + Dh * bf2f(xs4[2])),
               f2bf(acc[3] + Dh * bf2f(xs4[3])) };
    *(us4v*)(YdT + (rhrow - r + (size_t)lt * 16 + fr) * HEADDIM + 4 * g) = o;
  }
#else
  const int Ls0 = fr + ((g & 1) << 5);
  const int Ls1 = Ls0 + 16;
  const bool hiq = (g >= 2);
#pragma unroll
  for (int q = 0; q < 2; ++q) {
    const int lt = strips[q];
    f32x4 acc = zf;
    bf16x8 cf = { 0, 0, 0, 0, 0, 0, 0, 0 };
    if (g < 2) cf = *(const bf16x8*)(Cbase + (size_t)(lt * 16 + fr) * D_STATE + 8 * g);
    const float acl2 = sc2[lt * 16 + fr];
    const int   lg   = lt * 16 + fr;
    const int npair = (lt + 2) >> 1;
    for (int sp = 0; sp < npair; ++sp) {
      uint2 pk[2];
#pragma unroll
      for (int ti = 0; ti < 2; ++ti) {
        const int st = 2 * sp + ti;
        if (st < lt) {
          bf16x8 bfg = *(const bf16x8*)&Bs[(st * 16 + fr) * 24 + 8 * g];
          f32x4 G = __builtin_amdgcn_mfma_f32_16x16x32_bf16(bfg, cf, zf, 0, 0, 0);
          const float wl = exp2f(acl2 - scE[st]);
          pk[ti].x = pk_bf(G[0] * wl, G[1] * wl);
          pk[ti].y = pk_bf(G[2] * wl, G[3] * wl);
        } else if (st == lt) {
          f32x4 G = __builtin_amdgcn_mfma_f32_16x16x32_bf16(brawq[q], cf, zf, 0, 0, 0);
          f32x4 se2 = *(const f32x4*)&sc2[st * 16 + 4 * g];
          const int sbase = st * 16 + 4 * g;
          float w0 = (sbase + 0 <= lg) ? exp2f(acl2 - se2[0]) : 0.f;
          float w1 = (sbase + 1 <= lg) ? exp2f(acl2 - se2[1]) : 0.f;
          float w2 = (sbase + 2 <= lg) ? exp2f(acl2 - se2[2]) : 0.f;
          float w3 = (sbase + 3 <= lg) ? exp2f(acl2 - se2[3]) : 0.f;
          pk[ti].x = pk_bf(G[0] * w0, G[1] * w1);
          pk[ti].y = pk_bf(G[2] * w2, G[3] * w3);
        } else {
          pk[ti].x = 0u; pk[ti].y = 0u;
        }
      }
      const int a00 = __shfl((int)pk[0].x, Ls0, 64);
      const int a10 = __shfl((int)pk[0].y, Ls0, 64);
      const int a01 = __shfl((int)pk[0].x, Ls1, 64);
      const int a11 = __shfl((int)pk[0].y, Ls1, 64);
      const int b00 = __shfl((int)pk[1].x, Ls0, 64);
      const int b10 = __shfl((int)pk[1].y, Ls0, 64);
      const int b01 = __shfl((int)pk[1].x, Ls1, 64);
      const int b11 = __shfl((int)pk[1].y, Ls1, 64);
      u32x4 pw;
      pw[0] = (unsigned)(hiq ? b00 : a00);
      pw[1] = (unsigned)(hiq ? b10 : a10);
      pw[2] = (unsigned)(hiq ? b01 : a01);
      pw[3] = (unsigned)(hiq ? b11 : a11);
      const bf16x8 pf = __builtin_bit_cast(bf16x8, pw);
      const bf16x8 xf = *(const bf16x8*)&xsT[fr * 264 + sp * 32 + 8 * g];
      acc = __builtin_amdgcn_mfma_f32_16x16x32_bf16(xf, pf, acc, 0, 0, 0);
    }
    us4v xs4 = *(const us4v*)&xraw[(lt * 16 + fr + 3) * 16 + 4 * g];
    us4v o = { f2bf(acc[0] + Dh * bf2f(xs4[0])),
               f2bf(acc[1] + Dh * bf2f(xs4[1])),
               f2bf(acc[2] + Dh * bf2f(xs4[2])),
               f2bf(acc[3] + Dh * bf2f(xs4[3])) };
    *(us4v*)(YdT + (rhrow - r + (size_t)lt * 16 + fr) * HEADDIM + 4 * g) = o;
  }
#endif
}

// ---------------------------------------------------------------------------
// K4: sequential inter-chunk state recurrence
// ---------------------------------------------------------------------------
__global__ __launch_bounds__(256)
void chunk_scan_kernel(const float* __restrict__ stloc, const float* __restrict__ csum_g,
                       float* __restrict__ stpre) {
  const int b  = blockIdx.x / NHEADS;
  const int h  = blockIdx.x % NHEADS;
  const int pn = threadIdx.x;
  float S = 0.0f;
  for (int c = 0; c < NCHUNKS; ++c) {
    const size_t idx = ((size_t)(b * NCHUNKS + c) * NHEADS + h) * 256 + pn;
    stpre[idx] = S;
    S = __expf(csum_g[(b * NHEADS + h) * NCHUNKS + c]) * S + stloc[idx];
  }
}

// ---------------------------------------------------------------------------
// K5 (fused, 12 waves): Y_off, silu(z) gate, RMSNorm, out = yn @ W_out^T.
// r27: XCD-aware block remap (1024 blocks, bijective) -> the 16 blocks of a
// chunk share the same stpre slice within one XCD's L2.
// ---------------------------------------------------------------------------
#define TT 16
#define LDY 392
__global__ __launch_bounds__(768)
void yoff_norm_gemm(const unsigned short* __restrict__ YdT,
                    const unsigned short* __restrict__ Co, const float* __restrict__ acum_g,
                    const float* __restrict__ stpre,
                    const unsigned short* __restrict__ zbuf, const float* __restrict__ norm_w,
                    const unsigned short* __restrict__ Wo,
                    float* __restrict__ out) {
  const int bid  = blockIdx.x;
  const int wz   = (bid & 7) * 128 + (bid >> 3);   // bijective: 1024 % 8 == 0
  const int r0   = wz * TT;
  const int b    = r0 / SEQLEN;
  const int t0   = r0 % SEQLEN;
  const int cidx = t0 / CHUNK;
  const int tid  = threadIdx.x;
  const int d    = tid % 384;
  const int half = tid / 384;
  const int h    = d >> 4, p = d & 15;
  const int wv   = tid >> 6;

  __shared__ unsigned short Yt[NHEADS * TT * 16];
  __shared__ unsigned short zL[TT * 384];
  __shared__ unsigned short ynL[TT * LDY];
  __shared__ float At[NHEADS * TT];
  __shared__ float Ct[TT * 16];
  __shared__ float red[TT][6];

  {
    us8v* Yt8 = (us8v*)Yt;
    int hh = tid >> 5, q = tid & 31;
    const size_t src = ((size_t)(b * NHEADS + hh) * SEQLEN + t0) * HEADDIM + q * 8;
    Yt8[tid] = *(const us8v*)(YdT + src);
    const int zr = tid / 48, zc = (tid % 48) * 8;
    *(us8v*)&zL[zr * 384 + zc] = *(const us8v*)(zbuf + (size_t)(r0 + zr) * 384 + zc);
    if (tid < NHEADS * TT)
      At[tid] = __expf(acum_g[(size_t)(b * NHEADS + (tid >> 4)) * SEQLEN + t0 + (tid & 15)]);
    if (tid < TT * 16) Ct[tid] = bf2f(Co[(size_t)r0 * D_STATE + tid]);
  }

  float S[16];
  {
    const float* Sp = stpre + ((size_t)(b * NCHUNKS + cidx) * NHEADS + h) * 256 + p * 16;
#pragma unroll
    for (int q = 0; q < 4; ++q) {
      float4 v4 = *(const float4*)(Sp + 4 * q);
      S[4 * q + 0] = v4.x; S[4 * q + 1] = v4.y; S[4 * q + 2] = v4.z; S[4 * q + 3] = v4.w;
    }
  }
  const float nw = norm_w[d];
  __syncthreads();

  const int tb = half * 8;
  float yg[8];
#pragma unroll
  for (int ti = 0; ti < 8; ++ti) {
    const int tt = tb + ti;
    float dot = 0.f;
#pragma unroll
    for (int n = 0; n < 16; ++n) dot += Ct[tt * 16 + n] * S[n];
    const float eA = At[h * TT + tt];
    float y = bf2f(Yt[h * 256 + tt * 16 + p]) + eA * dot;
    const float z = bf2f(zL[tt * 384 + d]);
    yg[ti] = y * silu_f(z);
    float s = yg[ti] * yg[ti];
#pragma unroll
    for (int off = 32; off > 0; off >>= 1) s += __shfl_down(s, off);
    if ((tid & 63) == 0) red[tt][wv - half * 6] = s;
  }
  __syncthreads();

#pragma unroll
  for (int ti = 0; ti < 8; ++ti) {
    const int tt = tb + ti;
    const float tot = red[tt][0] + red[tt][1] + red[tt][2] + red[tt][3] + red[tt][4] + red[tt][5];
    const float scale = rsqrtf(tot * (1.0f / D_INNER) + EPS);
    ynL[tt * LDY + d] = f2bf(yg[ti] * scale * nw);
  }
  __syncthreads();

  const int lane = tid & 63;
  const int fr = lane & 15, fq = lane >> 4;
  const int n0 = wv * 16;
  f32x4 accg = {};
  __builtin_amdgcn_s_setprio(1);
#pragma unroll
  for (int kt = 0; kt < 12; ++kt) {
    const bf16x8 af = *(const bf16x8*)&ynL[fr * LDY + kt * 32 + 8 * fq];
    const int col = n0 + fr;
    const bf16x8 bfr = *(const bf16x8*)(Wo + (size_t)col * D_INNER + kt * 32 + 8 * fq);
    accg = __builtin_amdgcn_mfma_f32_16x16x32_bf16(bfr, af, accg, 0, 0, 0);
  }
  __builtin_amdgcn_s_setprio(0);
  float4 o = make_float4(accg[0], accg[1], accg[2], accg[3]);
  *(float4*)(out + (size_t)(r0 + fr) * D_MODEL + n0 + fq * 4) = o;
}

// ---------------------------------------------------------------------------
extern "C" void kernel_launch(void* const* d_in, const int* in_sizes, int n_in,
                              void* d_out, int out_size, void* d_ws, size_t ws_size,
                              hipStream_t stream) {
  const float* u        = (const float*)d_in[0];
  const float* support  = (const float*)d_in[1];
  const float* W_in     = (const float*)d_in[2];
  const float* W_in_b   = (const float*)d_in[3];
  const float* conv_w   = (const float*)d_in[4];
  const float* conv_b   = (const float*)d_in[5];
  const float* conv_w_b = (const float*)d_in[6];
  const float* conv_b_b = (const float*)d_in[7];
  const float* dt_bias  = (const float*)d_in[8];
  const float* A_log    = (const float*)d_in[9];
  const float* Dvec     = (const float*)d_in[10];
  const float* norm_w   = (const float*)d_in[11];
  const float* W_out    = (const float*)d_in[12];
  float* out = (float*)d_out;
  char* wsb  = (char*)d_ws;

  unsigned short* Wi_b  = (unsigned short*)(wsb);
  unsigned short* Wo_b  = Wi_b + (size_t)D_IN_PROJ * D_MODEL;
  unsigned short* Wib_b = Wo_b + (size_t)D_MODEL * D_INNER;
  unsigned short* zbuf  = Wib_b + (size_t)D_STATE * D_MODEL;
  unsigned short* xT    = zbuf + (size_t)ROWS * D_INNER;
  unsigned short* Braw  = xT + (size_t)ROWS * D_INNER;
  unsigned short* draw  = Braw + (size_t)ROWS * D_STATE;
  unsigned short* craw  = draw + (size_t)ROWS * NHEADS;
  unsigned short* Bo    = craw + (size_t)ROWS * D_STATE;
  unsigned short* Co    = Bo + (size_t)ROWS * D_STATE;
  unsigned short* YdT   = Co + (size_t)ROWS * D_STATE;
  float* dtoT  = (float*)(YdT + (size_t)ROWS * D_INNER);
  float* acum  = dtoT  + (size_t)ROWS * NHEADS;
  float* csum  = acum  + (size_t)BATCH * NHEADS * SEQLEN;
  float* stloc = csum  + (size_t)BATCH * NHEADS * NCHUNKS;
  float* stpre = stloc + (size_t)BATCH * NCHUNKS * NHEADS * 256;

  cvt3_kernel<<<224, 256, 0, stream>>>(W_in, Wi_b, (long)D_IN_PROJ * D_MODEL,
                                       W_out, Wo_b, (long)D_MODEL * D_INNER,
                                       W_in_b, Wib_b, (long)D_STATE * D_MODEL);
  gemm_in_merged<<<dim3(8, ROWS / 128), 256, 0, stream>>>(
      u, Wi_b, support, Wib_b, craw, zbuf, xT, Braw, draw);
  conv_bcdt<<<CBC_NB + CDT_NB, 256, 0, stream>>>(
      Braw, craw, draw, conv_w, conv_b, conv_w_b, conv_b_b, dt_bias, Bo, Co, dtoT);
  ssd_mfma_kernel<<<NHEADS * NCHUNKS * BATCH, 512, 0, stream>>>(
      xT, Bo, Co, dtoT, A_log, conv_w, conv_b, Dvec, YdT, acum, csum, stloc);
  chunk_scan_kernel<<<BATCH * NHEADS, 256, 0, stream>>>(stloc, csum, stpre);
  yoff_norm_gemm<<<ROWS / TT, 768, 0, stream>>>(YdT, Co, acum, stpre, zbuf, norm_w,
                                                Wo_b, out);
}

// Round 28
// 113.948 us; speedup vs baseline: 1.2043x; 1.0087x over previous
//
#include <hip/hip_runtime.h>
#include <cmath>

#define ROWS      16384
#define SEQLEN    8192
#define BATCH     2
#define NHEADS    24
#define HEADDIM   16
#define D_STATE   16
#define D_INNER   384
#define D_MODEL   192
#define D_IN_PROJ 808
#define CONV_DIM  400
#define NCHUNKS   32
#define CHUNK     256
#define EPS       1e-5f
#define LOG2E     1.44269504088896f

typedef short bf16x8 __attribute__((ext_vector_type(8)));
typedef short bf16x4 __attribute__((ext_vector_type(4)));
typedef float f32x4  __attribute__((ext_vector_type(4)));
typedef unsigned short us4v __attribute__((ext_vector_type(4)));
typedef unsigned short us8v __attribute__((ext_vector_type(8)));
typedef unsigned int  u32x4 __attribute__((ext_vector_type(4)));

#if __has_builtin(__builtin_amdgcn_mfma_f32_16x16x16bf16_1k)
#define MFMA16(a, b, c) __builtin_amdgcn_mfma_f32_16x16x16bf16_1k((a), (b), (c), 0, 0, 0)
#define HAVE_MFMA16 1
#elif __has_builtin(__builtin_amdgcn_mfma_f32_16x16x16_bf16)
#define MFMA16(a, b, c) __builtin_amdgcn_mfma_f32_16x16x16_bf16((a), (b), (c), 0, 0, 0)
#define HAVE_MFMA16 1
#else
#define HAVE_MFMA16 0
#endif

__device__ __forceinline__ float silu_f(float x) { return x / (1.0f + expf(-x)); }
__device__ __forceinline__ float softplus_f(float x) { return (x > 20.0f) ? x : log1pf(expf(x)); }
__device__ __forceinline__ unsigned short f2bf(float x) {
  unsigned u = __builtin_bit_cast(unsigned, x);
  u += 0x7fff + ((u >> 16) & 1);
  return (unsigned short)(u >> 16);
}
__device__ __forceinline__ float bf2f(unsigned short s) {
  unsigned u = (unsigned)s << 16;
  return __builtin_bit_cast(float, u);
}
__device__ __forceinline__ unsigned pk_bf(float a, float b) {
  unsigned ua = __builtin_bit_cast(unsigned, a) + 0x7fffu;
  unsigned ub = __builtin_bit_cast(unsigned, b) + 0x7fffu;
  return __builtin_amdgcn_perm(ub, ua, 0x07060302u);
}

// ---------------------------------------------------------------------------
// K0: fp32 -> bf16 weights (W_in, W_out, W_in_b)
// ---------------------------------------------------------------------------
__global__ __launch_bounds__(256)
void cvt3_kernel(const float* __restrict__ a, unsigned short* __restrict__ ao, long na,
                 const float* __restrict__ b, unsigned short* __restrict__ bo, long nb,
                 const float* __restrict__ c, unsigned short* __restrict__ co, long nc) {
  const long t0 = na >> 2, t1 = t0 + (nb >> 2), t2 = t1 + (nc >> 2);
  const long stride = (long)gridDim.x * blockDim.x;
  for (long i = (long)blockIdx.x * blockDim.x + threadIdx.x; i < t2; i += stride) {
    const float4* s; us4v* d; long j;
    if (i < t0)      { s = (const float4*)a; d = (us4v*)ao; j = i; }
    else if (i < t1) { s = (const float4*)b; d = (us4v*)bo; j = i - t0; }
    else             { s = (const float4*)c; d = (us4v*)co; j = i - t1; }
    float4 v = s[j];
    us4v o = { f2bf(v.x), f2bf(v.y), f2bf(v.z), f2bf(v.w) };
    d[j] = o;
  }
}

// ---------------------------------------------------------------------------
// GEMM body (device fn; LDS passed in).
// ---------------------------------------------------------------------------
template<bool OUT_BF16, bool ROUTE>
__device__ __forceinline__
void gemm_body(unsigned short* __restrict__ As, unsigned short* __restrict__ Ws,
               const float* __restrict__ A, const unsigned short* __restrict__ W,
               void* __restrict__ Cp, int M, int N, int K, int bx, int by,
               unsigned short* __restrict__ zbuf, unsigned short* __restrict__ xT,
               unsigned short* __restrict__ Braw, unsigned short* __restrict__ draw) {
  constexpr int BM = 128, BN = 128, BK = 32, LDK = 40;
  const int tid  = threadIdx.x;
  const int wid  = tid >> 6, lane = tid & 63;
  const int wr   = wid >> 1, wc = wid & 1;
  const int fr   = lane & 15, fq = lane >> 4;
  const long m0  = (long)by * BM;
  const int  n0  = bx * BN;

  f32x4 acc[4][4] = {};

  auto stage = [&](int k0, int buf) {
#pragma unroll
    for (int p = 0; p < 2; ++p) {
      int flat = p * 2048 + tid * 8;
      int r = flat >> 5, c = flat & 31;
      const float4* src = (const float4*)(A + (m0 + r) * (long)K + k0 + c);
      float4 v0 = src[0], v1 = src[1];
      us8v o = { f2bf(v0.x), f2bf(v0.y), f2bf(v0.z), f2bf(v0.w),
                 f2bf(v1.x), f2bf(v1.y), f2bf(v1.z), f2bf(v1.w) };
      *(us8v*)&As[buf * BM * LDK + r * LDK + c] = o;
    }
#pragma unroll
    for (int p = 0; p < 2; ++p) {
      int flat = p * 2048 + tid * 8;
      int r = flat >> 5, c = flat & 31;
      int gn = n0 + r;
      us8v v = { 0, 0, 0, 0, 0, 0, 0, 0 };
      if (gn < N) v = *(const us8v*)(W + (long)gn * K + k0 + c);
      *(us8v*)&Ws[buf * BN * LDK + r * LDK + c] = v;
    }
  };

  const int nk = K / BK;
  stage(0, 0);
  __syncthreads();
  for (int kt = 0; kt < nk; ++kt) {
    const int cur = kt & 1;
    if (kt + 1 < nk) stage((kt + 1) * BK, cur ^ 1);
    bf16x8 af[4], bfr[4];
#pragma unroll
    for (int m = 0; m < 4; ++m)
      af[m] = *(const bf16x8*)&As[cur * BM * LDK + (wr * 64 + m * 16 + fr) * LDK + fq * 8];
#pragma unroll
    for (int n = 0; n < 4; ++n)
      bfr[n] = *(const bf16x8*)&Ws[cur * BN * LDK + (wc * 64 + n * 16 + fr) * LDK + fq * 8];
#pragma unroll
    for (int m = 0; m < 4; ++m)
#pragma unroll
      for (int n = 0; n < 4; ++n)
        acc[m][n] = __builtin_amdgcn_mfma_f32_16x16x32_bf16(bfr[n], af[m], acc[m][n], 0, 0, 0);
    __syncthreads();
  }

#pragma unroll
  for (int m = 0; m < 4; ++m) {
    const long gm = m0 + wr * 64 + m * 16 + fr;
#pragma unroll
    for (int n = 0; n < 4; ++n) {
      const int gn = n0 + wc * 64 + n * 16 + fq * 4;
      if (gn < N) {
        if (ROUTE) {
          us4v o = { f2bf(acc[m][n][0]), f2bf(acc[m][n][1]),
                     f2bf(acc[m][n][2]), f2bf(acc[m][n][3]) };
          const int bb = (int)(gm >> 13);
          const long t = gm & 8191;
          if (gn < 384) {
            *(us4v*)(zbuf + gm * 384 + gn) = o;
          } else if (gn < 768) {
            const int c = gn - 384, hh = c >> 4, ii = c & 15;
            *(us4v*)(xT + (((size_t)(bb * NHEADS + hh) * SEQLEN + t) << 4) + ii) = o;
          } else if (gn < 784) {
            *(us4v*)(Braw + gm * 16 + (gn - 768)) = o;
          } else {
            *(us4v*)(draw + gm * 24 + (gn - 784)) = o;
          }
        } else if (OUT_BF16) {
          us4v o = { f2bf(acc[m][n][0]), f2bf(acc[m][n][1]),
                     f2bf(acc[m][n][2]), f2bf(acc[m][n][3]) };
          *(us4v*)((unsigned short*)Cp + gm * N + gn) = o;
        } else {
          float4 o = make_float4(acc[m][n][0], acc[m][n][1], acc[m][n][2], acc[m][n][3]);
          *(float4*)((float*)Cp + gm * N + gn) = o;
        }
      }
    }
  }
}

// ---------------------------------------------------------------------------
// K1 (merged): bx<7 -> routed in-proj (u @ W_in^T); bx==7 -> support @ W_in_b^T
// ---------------------------------------------------------------------------
__global__ __launch_bounds__(256, 3)
void gemm_in_merged(const float* __restrict__ u, const unsigned short* __restrict__ Wi,
                    const float* __restrict__ support, const unsigned short* __restrict__ Wib,
                    unsigned short* __restrict__ craw,
                    unsigned short* __restrict__ zbuf, unsigned short* __restrict__ xT,
                    unsigned short* __restrict__ Braw, unsigned short* __restrict__ draw) {
  __shared__ unsigned short As[2 * 128 * 40];
  __shared__ unsigned short Ws[2 * 128 * 40];
  if (blockIdx.x < 7)
    gemm_body<true, true>(As, Ws, u, Wi, nullptr, ROWS, D_IN_PROJ, D_MODEL,
                          blockIdx.x, blockIdx.y, zbuf, xT, Braw, draw);
  else
    gemm_body<true, false>(As, Ws, support, Wib, craw, ROWS, D_STATE, D_MODEL,
                           0, blockIdx.y, nullptr, nullptr, nullptr, nullptr);
}

// ---------------------------------------------------------------------------
// K2: B/C conv + dt softplus, dense raw buffers. 448 role-pure blocks.
// ---------------------------------------------------------------------------
#define CBC_NB  (ROWS * 4 / 256)    // 256
#define CDT_NB  (ROWS * 3 / 256)    // 192

__global__ __launch_bounds__(256)
void conv_bcdt(const unsigned short* __restrict__ Braw, const unsigned short* __restrict__ craw,
               const unsigned short* __restrict__ draw,
               const float* __restrict__ conv_w, const float* __restrict__ conv_b,
               const float* __restrict__ conv_w_b, const float* __restrict__ conv_b_b,
               const float* __restrict__ dt_bias,
               unsigned short* __restrict__ Bo, unsigned short* __restrict__ Co,
               float* __restrict__ dtoT) {
  const int blk = blockIdx.x;
  const us8v z8 = { 0, 0, 0, 0, 0, 0, 0, 0 };

  if (blk < CBC_NB) {
    const int idx = blk * 256 + threadIdx.x;
    const int row = idx / 4, q = idx % 4;
    const int b = row / SEQLEN, t = row % SEQLEN;

    const unsigned short* src = (q < 2) ? Braw : craw;
    const float* cw = (q < 2) ? conv_w + 384 * 4 : conv_w_b;
    const float* cb = (q < 2) ? conv_b + 384 : conv_b_b;
    const int c0 = (q & 1) * 8;
    const unsigned short* base = src + (size_t)row * D_STATE + c0;
    us8v x0 = (t >= 3) ? *(const us8v*)(base - 3 * D_STATE) : z8;
    us8v x1 = (t >= 2) ? *(const us8v*)(base - 2 * D_STATE) : z8;
    us8v x2 = (t >= 1) ? *(const us8v*)(base - 1 * D_STATE) : z8;
    us8v x3 = *(const us8v*)base;
    us8v o;
#pragma unroll
    for (int ch = 0; ch < 8; ++ch) {
      const float4 wv = *(const float4*)(cw + (c0 + ch) * 4);
      float acc = cb[c0 + ch] + wv.x * bf2f(x0[ch]) + wv.y * bf2f(x1[ch])
                + wv.z * bf2f(x2[ch]) + wv.w * bf2f(x3[ch]);
      o[ch] = f2bf(silu_f(acc));
    }
    if (q < 2) *(us8v*)(Bo + (size_t)row * D_STATE + c0) = o;
    else       *(us8v*)(Co + (size_t)row * D_STATE + c0) = o;
  } else {
    const int idx = (blk - CBC_NB) * 256 + threadIdx.x;
    const int row = idx / 3, q = idx % 3;
    const int b = row / SEQLEN, t = row % SEQLEN;
    const int h0 = q * 8;
    us8v dv = *(const us8v*)(draw + (size_t)row * 24 + h0);
#pragma unroll
    for (int j = 0; j < 8; ++j) {
      float v = bf2f(dv[j]) + dt_bias[h0 + j];
      dtoT[(size_t)(b * NHEADS + h0 + j) * SEQLEN + t] = softplus_f(v);
    }
  }
}

// ---------------------------------------------------------------------------
// K3 (MFMA, 8 waves, fused x-conv, factored decay, K16 PV):
// 1D grid (1536) with XCD-aware remap (r27).
// ---------------------------------------------------------------------------
__global__ __launch_bounds__(512, 4)
void ssd_mfma_kernel(const unsigned short* __restrict__ xT, const unsigned short* __restrict__ Bo,
                     const unsigned short* __restrict__ Co, const float* __restrict__ dtoT,
                     const float* __restrict__ A_log, const float* __restrict__ conv_w,
                     const float* __restrict__ conv_b, const float* __restrict__ Dvec,
                     unsigned short* __restrict__ YdT, float* __restrict__ acum_g,
                     float* __restrict__ csum_g, float* __restrict__ stloc) {
  const int bid  = blockIdx.x;
  const int wrk  = (bid & 7) * 192 + (bid >> 3);
  const int b    = wrk / 768;
  const int rem  = wrk % 768;
  const int cidx = rem / NHEADS;
  const int h    = rem % NHEADS;
  const int tid  = threadIdx.x;
  const int wid  = tid >> 6, lane = tid & 63;
  const int fr   = lane & 15, g = lane >> 4;

  __shared__ unsigned short Bs[256 * 24 + 32];
  __shared__ unsigned short xsT[16 * 264];
  __shared__ unsigned short BwT[16 * 264];
  __shared__ unsigned short xraw[259 * 16 + 8];
  __shared__ float sc2[CHUNK];
  __shared__ float scE[16];
  __shared__ float wsum[4];

  const float Ah = -expf(A_log[h]);
  const us8v z8 = { 0, 0, 0, 0, 0, 0, 0, 0 };

  float v = 0.f;
  if (tid < CHUNK) {
    v = dtoT[(size_t)(b * NHEADS + h) * SEQLEN + (size_t)cidx * CHUNK + tid] * Ah;
#pragma unroll
    for (int off = 1; off < 64; off <<= 1) {
      float u = __shfl_up(v, off, 64);
      if (lane >= off) v += u;
    }
    if (lane == 63) wsum[wid] = v;
  }

  const int r  = tid >> 1;
  const int hf = tid & 1;
  const size_t rowbase = (size_t)b * SEQLEN + (size_t)cidx * CHUNK;
  const size_t rhrow = (size_t)(b * NHEADS + h) * SEQLEN + (size_t)cidx * CHUNK + r;
  const float rdtv = dtoT[rhrow];
  us8v bh = ((const us8v*)(Bo + (rowbase + r) * D_STATE))[hf];
  if (hf == 0) *(us8v*)&Bs[r * 24 + 16] = z8;
  if (tid < 32) Bs[256 * 24 + tid] = 0;
  {
    const int tg = cidx * CHUNK + r - 3;
    us8v xv = z8;
    if (tg >= 0)
      xv = *(const us8v*)(xT + (((size_t)(b * NHEADS + h) * SEQLEN + tg) << 4) + 8 * hf);
    *(us8v*)&xraw[r * 16 + 8 * hf] = xv;
    if (tid < 6) {
      const int rr2 = 256 + (tid >> 1);
      const int hf2 = tid & 1;
      const int tg2 = cidx * CHUNK + rr2 - 3;
      us8v xv2 = *(const us8v*)(xT + (((size_t)(b * NHEADS + h) * SEQLEN + tg2) << 4) + 8 * hf2);
      *(us8v*)&xraw[rr2 * 16 + 8 * hf2] = xv2;
    }
  }
  __syncthreads();   // #1

  us8v xsil, xdt8;
  {
    us8v tA = *(const us8v*)&xraw[(r + 0) * 16 + 8 * hf];
    us8v tB = *(const us8v*)&xraw[(r + 1) * 16 + 8 * hf];
    us8v tC = *(const us8v*)&xraw[(r + 2) * 16 + 8 * hf];
    us8v tD = *(const us8v*)&xraw[(r + 3) * 16 + 8 * hf];
    const int cbase = h * HEADDIM + 8 * hf;
#pragma unroll
    for (int ch = 0; ch < 8; ++ch) {
      const float4 wv = *(const float4*)(conv_w + (cbase + ch) * 4);
      float acc = conv_b[cbase + ch] + wv.x * bf2f(tA[ch]) + wv.y * bf2f(tB[ch])
                + wv.z * bf2f(tC[ch]) + wv.w * bf2f(tD[ch]);
      float sv = silu_f(acc);
      xsil[ch] = f2bf(sv);
      xdt8[ch] = f2bf(sv * rdtv);
    }
  }
  const float ctot  = wsum[0] + wsum[1] + wsum[2] + wsum[3];
  const float ctot2 = ctot * LOG2E;
  if (tid < CHUNK) {
    float pre = 0.f;
#pragma unroll
    for (int w = 0; w < 4; ++w) if (w < wid) pre += wsum[w];
    v += pre;
    sc2[tid] = v * LOG2E;
    acum_g[(size_t)(b * NHEADS + h) * SEQLEN + (size_t)cidx * CHUNK + tid] = v;
    if (tid == CHUNK - 1) csum_g[(b * NHEADS + h) * NCHUNKS + cidx] = v;
  }
  __syncthreads();   // #2

  *(us8v*)&xraw[(r + 3) * 16 + 8 * hf] = xsil;
#pragma unroll
  for (int q = 0; q < 8; ++q)
    xsT[(q + 8 * hf) * 264 + r] = xdt8[q];
  {
    const float wdv = exp2f(ctot2 - sc2[r]);
    const float ed  = exp2f(sc2[r | 15] - sc2[r]);   // <= 1
    us8v bscaled;
#pragma unroll
    for (int q = 0; q < 8; ++q) {
      BwT[(q + 8 * hf) * 264 + r] = f2bf(bf2f(bh[q]) * wdv);
      bscaled[q] = f2bf(bf2f(bh[q]) * ed);
    }
    *(us8v*)&Bs[r * 24 + 8 * hf] = bscaled;
  }
  if (tid < 16) scE[tid] = sc2[tid * 16 + 15];
  __syncthreads();   // #3 (last barrier)

  if (wid == 0) {
    f32x4 accS = {};
#pragma unroll
    for (int k2 = 0; k2 < 8; ++k2) {
      bf16x8 af = *(const bf16x8*)&BwT[fr * 264 + 32 * k2 + 8 * g];
      bf16x8 bb = *(const bf16x8*)&xsT[fr * 264 + 32 * k2 + 8 * g];
      accS = __builtin_amdgcn_mfma_f32_16x16x32_bf16(af, bb, accS, 0, 0, 0);
    }
    *(f32x4*)&stloc[((size_t)(b * NCHUNKS + cidx) * NHEADS + h) * 256 + fr * 16 + 4 * g] = accS;
  }

  const f32x4 zf = { 0.f, 0.f, 0.f, 0.f };
  const unsigned short* Cbase = Co + rowbase * D_STATE;
  const float Dh = Dvec[h];
  const int strips[2] = { wid, 15 - wid };

  bf16x8 brawq[2];
#pragma unroll
  for (int q = 0; q < 2; ++q) {
    us8v bv = z8;
    if (g < 2)
      bv = *(const us8v*)(Bo + (rowbase + strips[q] * 16 + fr) * D_STATE + 8 * g);
    brawq[q] = __builtin_bit_cast(bf16x8, bv);
  }

#if HAVE_MFMA16
#pragma unroll
  for (int q = 0; q < 2; ++q) {
    const int lt = strips[q];
    f32x4 acc = zf;
    bf16x8 cf = { 0, 0, 0, 0, 0, 0, 0, 0 };
    if (g < 2) cf = *(const bf16x8*)(Cbase + (size_t)(lt * 16 + fr) * D_STATE + 8 * g);
    const float acl2 = sc2[lt * 16 + fr];
    const int   lg   = lt * 16 + fr;
    for (int st = 0; st <= lt; ++st) {
      uint2 pp;
      if (st < lt) {
        bf16x8 bfg = *(const bf16x8*)&Bs[(st * 16 + fr) * 24 + 8 * g];
        f32x4 G = __builtin_amdgcn_mfma_f32_16x16x32_bf16(bfg, cf, zf, 0, 0, 0);
        const float wl = exp2f(acl2 - scE[st]);
        pp.x = pk_bf(G[0] * wl, G[1] * wl);
        pp.y = pk_bf(G[2] * wl, G[3] * wl);
      } else {
        f32x4 G = __builtin_amdgcn_mfma_f32_16x16x32_bf16(brawq[q], cf, zf, 0, 0, 0);
        f32x4 se2 = *(const f32x4*)&sc2[st * 16 + 4 * g];
        const int sbase = st * 16 + 4 * g;
        float w0 = (sbase + 0 <= lg) ? exp2f(acl2 - se2[0]) : 0.f;
        float w1 = (sbase + 1 <= lg) ? exp2f(acl2 - se2[1]) : 0.f;
        float w2 = (sbase + 2 <= lg) ? exp2f(acl2 - se2[2]) : 0.f;
        float w3 = (sbase + 3 <= lg) ? exp2f(acl2 - se2[3]) : 0.f;
        pp.x = pk_bf(G[0] * w0, G[1] * w1);
        pp.y = pk_bf(G[2] * w2, G[3] * w3);
      }
      const bf16x4 p4 = __builtin_bit_cast(bf16x4, pp);
      const bf16x4 x4 = *(const bf16x4*)&xsT[fr * 264 + st * 16 + 4 * g];
      acc = MFMA16(x4, p4, acc);
    }
    us4v xs4 = *(const us4v*)&xraw[(lt * 16 + fr + 3) * 16 + 4 * g];
    us4v o = { f2bf(acc[0] + Dh * bf2f(xs4[0])),
               f2bf(acc[1] + Dh * bf2f(xs4[1])),
               f2bf(acc[2] + Dh * bf2f(xs4[2])),
               f2bf(acc[3] + Dh * bf2f(xs4[3])) };
    *(us4v*)(YdT + (rhrow - r + (size_t)lt * 16 + fr) * HEADDIM + 4 * g) = o;
  }
#else
  const int Ls0 = fr + ((g & 1) << 5);
  const int Ls1 = Ls0 + 16;
  const bool hiq = (g >= 2);
#pragma unroll
  for (int q = 0; q < 2; ++q) {
    const int lt = strips[q];
    f32x4 acc = zf;
    bf16x8 cf = { 0, 0, 0, 0, 0, 0, 0, 0 };
    if (g < 2) cf = *(const bf16x8*)(Cbase + (size_t)(lt * 16 + fr) * D_STATE + 8 * g);
    const float acl2 = sc2[lt * 16 + fr];
    const int   lg   = lt * 16 + fr;
    const int npair = (lt + 2) >> 1;
    for (int sp = 0; sp < npair; ++sp) {
      uint2 pk[2];
#pragma unroll
      for (int ti = 0; ti < 2; ++ti) {
        const int st = 2 * sp + ti;
        if (st < lt) {
          bf16x8 bfg = *(const bf16x8*)&Bs[(st * 16 + fr) * 24 + 8 * g];
          f32x4 G = __builtin_amdgcn_mfma_f32_16x16x32_bf16(bfg, cf, zf, 0, 0, 0);
          const float wl = exp2f(acl2 - scE[st]);
          pk[ti].x = pk_bf(G[0] * wl, G[1] * wl);
          pk[ti].y = pk_bf(G[2] * wl, G[3] * wl);
        } else if (st == lt) {
          f32x4 G = __builtin_amdgcn_mfma_f32_16x16x32_bf16(brawq[q], cf, zf, 0, 0, 0);
          f32x4 se2 = *(const f32x4*)&sc2[st * 16 + 4 * g];
          const int sbase = st * 16 + 4 * g;
          float w0 = (sbase + 0 <= lg) ? exp2f(acl2 - se2[0]) : 0.f;
          float w1 = (sbase + 1 <= lg) ? exp2f(acl2 - se2[1]) : 0.f;
          float w2 = (sbase + 2 <= lg) ? exp2f(acl2 - se2[2]) : 0.f;
          float w3 = (sbase + 3 <= lg) ? exp2f(acl2 - se2[3]) : 0.f;
          pk[ti].x = pk_bf(G[0] * w0, G[1] * w1);
          pk[ti].y = pk_bf(G[2] * w2, G[3] * w3);
        } else {
          pk[ti].x = 0u; pk[ti].y = 0u;
        }
      }
      const int a00 = __shfl((int)pk[0].x, Ls0, 64);
      const int a10 = __shfl((int)pk[0].y, Ls0, 64);
      const int a01 = __shfl((int)pk[0].x, Ls1, 64);
      const int a11 = __shfl((int)pk[0].y, Ls1, 64);
      const int b00 = __shfl((int)pk[1].x, Ls0, 64);
      const int b10 = __shfl((int)pk[1].y, Ls0, 64);
      const int b01 = __shfl((int)pk[1].x, Ls1, 64);
      const int b11 = __shfl((int)pk[1].y, Ls1, 64);
      u32x4 pw;
      pw[0] = (unsigned)(hiq ? b00 : a00);
      pw[1] = (unsigned)(hiq ? b10 : a10);
      pw[2] = (unsigned)(hiq ? b01 : a01);
      pw[3] = (unsigned)(hiq ? b11 : a11);
      const bf16x8 pf = __builtin_bit_cast(bf16x8, pw);
      const bf16x8 xf = *(const bf16x8*)&xsT[fr * 264 + sp * 32 + 8 * g];
      acc = __builtin_amdgcn_mfma_f32_16x16x32_bf16(xf, pf, acc, 0, 0, 0);
    }
    us4v xs4 = *(const us4v*)&xraw[(lt * 16 + fr + 3) * 16 + 4 * g];
    us4v o = { f2bf(acc[0] + Dh * bf2f(xs4[0])),
               f2bf(acc[1] + Dh * bf2f(xs4[1])),
               f2bf(acc[2] + Dh * bf2f(xs4[2])),
               f2bf(acc[3] + Dh * bf2f(xs4[3])) };
    *(us4v*)(YdT + (rhrow - r + (size_t)lt * 16 + fr) * HEADDIM + 4 * g) = o;
  }
#endif
}

// ---------------------------------------------------------------------------
// K4: sequential inter-chunk state recurrence
// ---------------------------------------------------------------------------
__global__ __launch_bounds__(256)
void chunk_scan_kernel(const float* __restrict__ stloc, const float* __restrict__ csum_g,
                       float* __restrict__ stpre) {
  const int b  = blockIdx.x / NHEADS;
  const int h  = blockIdx.x % NHEADS;
  const int pn = threadIdx.x;
  float S = 0.0f;
  for (int c = 0; c < NCHUNKS; ++c) {
    const size_t idx = ((size_t)(b * NCHUNKS + c) * NHEADS + h) * 256 + pn;
    stpre[idx] = S;
    S = __expf(csum_g[(b * NHEADS + h) * NCHUNKS + c]) * S + stloc[idx];
  }
}

// ---------------------------------------------------------------------------
// K5 (fused, 12 waves): Y_off, silu(z) gate, RMSNorm, out = yn @ W_out^T.
// r28: LDS-issue pressure cut — Ct dot via f32x4 ds_read_b128 (128->32 LDS
// ops/thread), red[] padded to 8 and read vectorized (48->24).
// ---------------------------------------------------------------------------
#define TT 16
#define LDY 392
__global__ __launch_bounds__(768)
void yoff_norm_gemm(const unsigned short* __restrict__ YdT,
                    const unsigned short* __restrict__ Co, const float* __restrict__ acum_g,
                    const float* __restrict__ stpre,
                    const unsigned short* __restrict__ zbuf, const float* __restrict__ norm_w,
                    const unsigned short* __restrict__ Wo,
                    float* __restrict__ out) {
  const int bid  = blockIdx.x;
  const int wz   = (bid & 7) * 128 + (bid >> 3);   // bijective: 1024 % 8 == 0
  const int r0   = wz * TT;
  const int b    = r0 / SEQLEN;
  const int t0   = r0 % SEQLEN;
  const int cidx = t0 / CHUNK;
  const int tid  = threadIdx.x;
  const int d    = tid % 384;
  const int half = tid / 384;
  const int h    = d >> 4, p = d & 15;
  const int wv   = tid >> 6;

  __shared__ unsigned short Yt[NHEADS * TT * 16];
  __shared__ unsigned short zL[TT * 384];
  __shared__ unsigned short ynL[TT * LDY];
  __shared__ float At[NHEADS * TT];
  __shared__ float Ct[TT * 16];
  __shared__ float red[TT][8];     // padded to 32B rows for vector reads

  {
    us8v* Yt8 = (us8v*)Yt;
    int hh = tid >> 5, q = tid & 31;
    const size_t src = ((size_t)(b * NHEADS + hh) * SEQLEN + t0) * HEADDIM + q * 8;
    Yt8[tid] = *(const us8v*)(YdT + src);
    const int zr = tid / 48, zc = (tid % 48) * 8;
    *(us8v*)&zL[zr * 384 + zc] = *(const us8v*)(zbuf + (size_t)(r0 + zr) * 384 + zc);
    if (tid < NHEADS * TT)
      At[tid] = __expf(acum_g[(size_t)(b * NHEADS + (tid >> 4)) * SEQLEN + t0 + (tid & 15)]);
    if (tid < TT * 16) Ct[tid] = bf2f(Co[(size_t)r0 * D_STATE + tid]);
    if (tid < TT * 2) red[tid >> 1][6 + (tid & 1)] = 0.f;
  }

  f32x4 S4[4];
  {
    const float* Sp = stpre + ((size_t)(b * NCHUNKS + cidx) * NHEADS + h) * 256 + p * 16;
#pragma unroll
    for (int q = 0; q < 4; ++q) S4[q] = *(const f32x4*)(Sp + 4 * q);
  }
  const float nw = norm_w[d];
  __syncthreads();

  const int tb = half * 8;
  float yg[8];
#pragma unroll
  for (int ti = 0; ti < 8; ++ti) {
    const int tt = tb + ti;
    const f32x4* C4 = (const f32x4*)&Ct[tt * 16];
    f32x4 d4 = C4[0] * S4[0];
    d4 = d4 + C4[1] * S4[1];
    d4 = d4 + C4[2] * S4[2];
    d4 = d4 + C4[3] * S4[3];
    const float dot = (d4[0] + d4[1]) + (d4[2] + d4[3]);
    const float eA = At[h * TT + tt];
    float y = bf2f(Yt[h * 256 + tt * 16 + p]) + eA * dot;
    const float z = bf2f(zL[tt * 384 + d]);
    yg[ti] = y * silu_f(z);
    float s = yg[ti] * yg[ti];
#pragma unroll
    for (int off = 32; off > 0; off >>= 1) s += __shfl_down(s, off);
    if ((tid & 63) == 0) red[tt][wv - half * 6] = s;
  }
  __syncthreads();

#pragma unroll
  for (int ti = 0; ti < 8; ++ti) {
    const int tt = tb + ti;
    const f32x4 r4 = *(const f32x4*)&red[tt][0];
    const float tot = ((r4[0] + r4[1]) + (r4[2] + r4[3])) + (red[tt][4] + red[tt][5]);
    const float scale = rsqrtf(tot * (1.0f / D_INNER) + EPS);
    ynL[tt * LDY + d] = f2bf(yg[ti] * scale * nw);
  }
  __syncthreads();

  const int lane = tid & 63;
  const int fr = lane & 15, fq = lane >> 4;
  const int n0 = wv * 16;
  f32x4 accg = {};
  __builtin_amdgcn_s_setprio(1);
#pragma unroll
  for (int kt = 0; kt < 12; ++kt) {
    const bf16x8 af = *(const bf16x8*)&ynL[fr * LDY + kt * 32 + 8 * fq];
    const int col = n0 + fr;
    const bf16x8 bfr = *(const bf16x8*)(Wo + (size_t)col * D_INNER + kt * 32 + 8 * fq);
    accg = __builtin_amdgcn_mfma_f32_16x16x32_bf16(bfr, af, accg, 0, 0, 0);
  }
  __builtin_amdgcn_s_setprio(0);
  float4 o = make_float4(accg[0], accg[1], accg[2], accg[3]);
  *(float4*)(out + (size_t)(r0 + fr) * D_MODEL + n0 + fq * 4) = o;
}

// ---------------------------------------------------------------------------
extern "C" void kernel_launch(void* const* d_in, const int* in_sizes, int n_in,
                              void* d_out, int out_size, void* d_ws, size_t ws_size,
                              hipStream_t stream) {
  const float* u        = (const float*)d_in[0];
  const float* support  = (const float*)d_in[1];
  const float* W_in     = (const float*)d_in[2];
  const float* W_in_b   = (const float*)d_in[3];
  const float* conv_w   = (const float*)d_in[4];
  const float* conv_b   = (const float*)d_in[5];
  const float* conv_w_b = (const float*)d_in[6];
  const float* conv_b_b = (const float*)d_in[7];
  const float* dt_bias  = (const float*)d_in[8];
  const float* A_log    = (const float*)d_in[9];
  const float* Dvec     = (const float*)d_in[10];
  const float* norm_w   = (const float*)d_in[11];
  const float* W_out    = (const float*)d_in[12];
  float* out = (float*)d_out;
  char* wsb  = (char*)d_ws;

  unsigned short* Wi_b  = (unsigned short*)(wsb);
  unsigned short* Wo_b  = Wi_b + (size_t)D_IN_PROJ * D_MODEL;
  unsigned short* Wib_b = Wo_b + (size_t)D_MODEL * D_INNER;
  unsigned short* zbuf  = Wib_b + (size_t)D_STATE * D_MODEL;
  unsigned short* xT    = zbuf + (size_t)ROWS * D_INNER;
  unsigned short* Braw  = xT + (size_t)ROWS * D_INNER;
  unsigned short* draw  = Braw + (size_t)ROWS * D_STATE;
  unsigned short* craw  = draw + (size_t)ROWS * NHEADS;
  unsigned short* Bo    = craw + (size_t)ROWS * D_STATE;
  unsigned short* Co    = Bo + (size_t)ROWS * D_STATE;
  unsigned short* YdT   = Co + (size_t)ROWS * D_STATE;
  float* dtoT  = (float*)(YdT + (size_t)ROWS * D_INNER);
  float* acum  = dtoT  + (size_t)ROWS * NHEADS;
  float* csum  = acum  + (size_t)BATCH * NHEADS * SEQLEN;
  float* stloc = csum  + (size_t)BATCH * NHEADS * NCHUNKS;
  float* stpre = stloc + (size_t)BATCH * NCHUNKS * NHEADS * 256;

  cvt3_kernel<<<224, 256, 0, stream>>>(W_in, Wi_b, (long)D_IN_PROJ * D_MODEL,
                                       W_out, Wo_b, (long)D_MODEL * D_INNER,
                                       W_in_b, Wib_b, (long)D_STATE * D_MODEL);
  gemm_in_merged<<<dim3(8, ROWS / 128), 256, 0, stream>>>(
      u, Wi_b, support, Wib_b, craw, zbuf, xT, Braw, draw);
  conv_bcdt<<<CBC_NB + CDT_NB, 256, 0, stream>>>(
      Braw, craw, draw, conv_w, conv_b, conv_w_b, conv_b_b, dt_bias, Bo, Co, dtoT);
  ssd_mfma_kernel<<<NHEADS * NCHUNKS * BATCH, 512, 0, stream>>>(
      xT, Bo, Co, dtoT, A_log, conv_w, conv_b, Dvec, YdT, acum, csum, stloc);
  chunk_scan_kernel<<<BATCH * NHEADS, 256, 0, stream>>>(stloc, csum, stpre);
  yoff_norm_gemm<<<ROWS / TT, 768, 0, stream>>>(YdT, Co, acum, stpre, zbuf, norm_w,
                                                Wo_b, out);
}

// Round 29
// 113.327 us; speedup vs baseline: 1.2109x; 1.0055x over previous
//
#include <hip/hip_runtime.h>
#include <cmath>

#define ROWS      16384
#define SEQLEN    8192
#define BATCH     2
#define NHEADS    24
#define HEADDIM   16
#define D_STATE   16
#define D_INNER   384
#define D_MODEL   192
#define D_IN_PROJ 808
#define CONV_DIM  400
#define NCHUNKS   32
#define CHUNK     256
#define EPS       1e-5f
#define LOG2E     1.44269504088896f

typedef short bf16x8 __attribute__((ext_vector_type(8)));
typedef short bf16x4 __attribute__((ext_vector_type(4)));
typedef float f32x4  __attribute__((ext_vector_type(4)));
typedef unsigned short us4v __attribute__((ext_vector_type(4)));
typedef unsigned short us8v __attribute__((ext_vector_type(8)));
typedef unsigned int  u32x4 __attribute__((ext_vector_type(4)));

#if __has_builtin(__builtin_amdgcn_mfma_f32_16x16x16bf16_1k)
#define MFMA16(a, b, c) __builtin_amdgcn_mfma_f32_16x16x16bf16_1k((a), (b), (c), 0, 0, 0)
#define HAVE_MFMA16 1
#elif __has_builtin(__builtin_amdgcn_mfma_f32_16x16x16_bf16)
#define MFMA16(a, b, c) __builtin_amdgcn_mfma_f32_16x16x16_bf16((a), (b), (c), 0, 0, 0)
#define HAVE_MFMA16 1
#else
#define HAVE_MFMA16 0
#endif

__device__ __forceinline__ float silu_f(float x) { return x / (1.0f + expf(-x)); }
__device__ __forceinline__ float softplus_f(float x) { return (x > 20.0f) ? x : log1pf(expf(x)); }
__device__ __forceinline__ unsigned short f2bf(float x) {
  unsigned u = __builtin_bit_cast(unsigned, x);
  u += 0x7fff + ((u >> 16) & 1);
  return (unsigned short)(u >> 16);
}
__device__ __forceinline__ float bf2f(unsigned short s) {
  unsigned u = (unsigned)s << 16;
  return __builtin_bit_cast(float, u);
}
__device__ __forceinline__ unsigned pk_bf(float a, float b) {
  unsigned ua = __builtin_bit_cast(unsigned, a) + 0x7fffu;
  unsigned ub = __builtin_bit_cast(unsigned, b) + 0x7fffu;
  return __builtin_amdgcn_perm(ub, ua, 0x07060302u);
}

// ---------------------------------------------------------------------------
// K0: fp32 -> bf16 weights (W_in, W_out, W_in_b)
// ---------------------------------------------------------------------------
__global__ __launch_bounds__(256)
void cvt3_kernel(const float* __restrict__ a, unsigned short* __restrict__ ao, long na,
                 const float* __restrict__ b, unsigned short* __restrict__ bo, long nb,
                 const float* __restrict__ c, unsigned short* __restrict__ co, long nc) {
  const long t0 = na >> 2, t1 = t0 + (nb >> 2), t2 = t1 + (nc >> 2);
  const long stride = (long)gridDim.x * blockDim.x;
  for (long i = (long)blockIdx.x * blockDim.x + threadIdx.x; i < t2; i += stride) {
    const float4* s; us4v* d; long j;
    if (i < t0)      { s = (const float4*)a; d = (us4v*)ao; j = i; }
    else if (i < t1) { s = (const float4*)b; d = (us4v*)bo; j = i - t0; }
    else             { s = (const float4*)c; d = (us4v*)co; j = i - t1; }
    float4 v = s[j];
    us4v o = { f2bf(v.x), f2bf(v.y), f2bf(v.z), f2bf(v.w) };
    d[j] = o;
  }
}

// ---------------------------------------------------------------------------
// GEMM body (device fn; LDS passed in).
// ---------------------------------------------------------------------------
template<bool OUT_BF16, bool ROUTE>
__device__ __forceinline__
void gemm_body(unsigned short* __restrict__ As, unsigned short* __restrict__ Ws,
               const float* __restrict__ A, const unsigned short* __restrict__ W,
               void* __restrict__ Cp, int M, int N, int K, int bx, int by,
               unsigned short* __restrict__ zbuf, unsigned short* __restrict__ xT,
               unsigned short* __restrict__ Braw, unsigned short* __restrict__ draw) {
  constexpr int BM = 128, BN = 128, BK = 32, LDK = 40;
  const int tid  = threadIdx.x;
  const int wid  = tid >> 6, lane = tid & 63;
  const int wr   = wid >> 1, wc = wid & 1;
  const int fr   = lane & 15, fq = lane >> 4;
  const long m0  = (long)by * BM;
  const int  n0  = bx * BN;

  f32x4 acc[4][4] = {};

  auto stage = [&](int k0, int buf) {
#pragma unroll
    for (int p = 0; p < 2; ++p) {
      int flat = p * 2048 + tid * 8;
      int r = flat >> 5, c = flat & 31;
      const float4* src = (const float4*)(A + (m0 + r) * (long)K + k0 + c);
      float4 v0 = src[0], v1 = src[1];
      us8v o = { f2bf(v0.x), f2bf(v0.y), f2bf(v0.z), f2bf(v0.w),
                 f2bf(v1.x), f2bf(v1.y), f2bf(v1.z), f2bf(v1.w) };
      *(us8v*)&As[buf * BM * LDK + r * LDK + c] = o;
    }
#pragma unroll
    for (int p = 0; p < 2; ++p) {
      int flat = p * 2048 + tid * 8;
      int r = flat >> 5, c = flat & 31;
      int gn = n0 + r;
      us8v v = { 0, 0, 0, 0, 0, 0, 0, 0 };
      if (gn < N) v = *(const us8v*)(W + (long)gn * K + k0 + c);
      *(us8v*)&Ws[buf * BN * LDK + r * LDK + c] = v;
    }
  };

  const int nk = K / BK;
  stage(0, 0);
  __syncthreads();
  for (int kt = 0; kt < nk; ++kt) {
    const int cur = kt & 1;
    if (kt + 1 < nk) stage((kt + 1) * BK, cur ^ 1);
    bf16x8 af[4], bfr[4];
#pragma unroll
    for (int m = 0; m < 4; ++m)
      af[m] = *(const bf16x8*)&As[cur * BM * LDK + (wr * 64 + m * 16 + fr) * LDK + fq * 8];
#pragma unroll
    for (int n = 0; n < 4; ++n)
      bfr[n] = *(const bf16x8*)&Ws[cur * BN * LDK + (wc * 64 + n * 16 + fr) * LDK + fq * 8];
#pragma unroll
    for (int m = 0; m < 4; ++m)
#pragma unroll
      for (int n = 0; n < 4; ++n)
        acc[m][n] = __builtin_amdgcn_mfma_f32_16x16x32_bf16(bfr[n], af[m], acc[m][n], 0, 0, 0);
    __syncthreads();
  }

#pragma unroll
  for (int m = 0; m < 4; ++m) {
    const long gm = m0 + wr * 64 + m * 16 + fr;
#pragma unroll
    for (int n = 0; n < 4; ++n) {
      const int gn = n0 + wc * 64 + n * 16 + fq * 4;
      if (gn < N) {
        if (ROUTE) {
          us4v o = { f2bf(acc[m][n][0]), f2bf(acc[m][n][1]),
                     f2bf(acc[m][n][2]), f2bf(acc[m][n][3]) };
          const int bb = (int)(gm >> 13);
          const long t = gm & 8191;
          if (gn < 384) {
            *(us4v*)(zbuf + gm * 384 + gn) = o;
          } else if (gn < 768) {
            const int c = gn - 384, hh = c >> 4, ii = c & 15;
            *(us4v*)(xT + (((size_t)(bb * NHEADS + hh) * SEQLEN + t) << 4) + ii) = o;
          } else if (gn < 784) {
            *(us4v*)(Braw + gm * 16 + (gn - 768)) = o;
          } else {
            *(us4v*)(draw + gm * 24 + (gn - 784)) = o;
          }
        } else if (OUT_BF16) {
          us4v o = { f2bf(acc[m][n][0]), f2bf(acc[m][n][1]),
                     f2bf(acc[m][n][2]), f2bf(acc[m][n][3]) };
          *(us4v*)((unsigned short*)Cp + gm * N + gn) = o;
        } else {
          float4 o = make_float4(acc[m][n][0], acc[m][n][1], acc[m][n][2], acc[m][n][3]);
          *(float4*)((float*)Cp + gm * N + gn) = o;
        }
      }
    }
  }
}

// ---------------------------------------------------------------------------
// K1 (merged): bx<7 -> routed in-proj (u @ W_in^T); bx==7 -> support @ W_in_b^T
// ---------------------------------------------------------------------------
__global__ __launch_bounds__(256, 3)
void gemm_in_merged(const float* __restrict__ u, const unsigned short* __restrict__ Wi,
                    const float* __restrict__ support, const unsigned short* __restrict__ Wib,
                    unsigned short* __restrict__ craw,
                    unsigned short* __restrict__ zbuf, unsigned short* __restrict__ xT,
                    unsigned short* __restrict__ Braw, unsigned short* __restrict__ draw) {
  __shared__ unsigned short As[2 * 128 * 40];
  __shared__ unsigned short Ws[2 * 128 * 40];
  if (blockIdx.x < 7)
    gemm_body<true, true>(As, Ws, u, Wi, nullptr, ROWS, D_IN_PROJ, D_MODEL,
                          blockIdx.x, blockIdx.y, zbuf, xT, Braw, draw);
  else
    gemm_body<true, false>(As, Ws, support, Wib, craw, ROWS, D_STATE, D_MODEL,
                           0, blockIdx.y, nullptr, nullptr, nullptr, nullptr);
}

// ---------------------------------------------------------------------------
// K2: B/C conv + dt softplus, dense raw buffers. 448 role-pure blocks.
// ---------------------------------------------------------------------------
#define CBC_NB  (ROWS * 4 / 256)    // 256
#define CDT_NB  (ROWS * 3 / 256)    // 192

__global__ __launch_bounds__(256)
void conv_bcdt(const unsigned short* __restrict__ Braw, const unsigned short* __restrict__ craw,
               const unsigned short* __restrict__ draw,
               const float* __restrict__ conv_w, const float* __restrict__ conv_b,
               const float* __restrict__ conv_w_b, const float* __restrict__ conv_b_b,
               const float* __restrict__ dt_bias,
               unsigned short* __restrict__ Bo, unsigned short* __restrict__ Co,
               float* __restrict__ dtoT) {
  const int blk = blockIdx.x;
  const us8v z8 = { 0, 0, 0, 0, 0, 0, 0, 0 };

  if (blk < CBC_NB) {
    const int idx = blk * 256 + threadIdx.x;
    const int row = idx / 4, q = idx % 4;
    const int b = row / SEQLEN, t = row % SEQLEN;

    const unsigned short* src = (q < 2) ? Braw : craw;
    const float* cw = (q < 2) ? conv_w + 384 * 4 : conv_w_b;
    const float* cb = (q < 2) ? conv_b + 384 : conv_b_b;
    const int c0 = (q & 1) * 8;
    const unsigned short* base = src + (size_t)row * D_STATE + c0;
    us8v x0 = (t >= 3) ? *(const us8v*)(base - 3 * D_STATE) : z8;
    us8v x1 = (t >= 2) ? *(const us8v*)(base - 2 * D_STATE) : z8;
    us8v x2 = (t >= 1) ? *(const us8v*)(base - 1 * D_STATE) : z8;
    us8v x3 = *(const us8v*)base;
    us8v o;
#pragma unroll
    for (int ch = 0; ch < 8; ++ch) {
      const float4 wv = *(const float4*)(cw + (c0 + ch) * 4);
      float acc = cb[c0 + ch] + wv.x * bf2f(x0[ch]) + wv.y * bf2f(x1[ch])
                + wv.z * bf2f(x2[ch]) + wv.w * bf2f(x3[ch]);
      o[ch] = f2bf(silu_f(acc));
    }
    if (q < 2) *(us8v*)(Bo + (size_t)row * D_STATE + c0) = o;
    else       *(us8v*)(Co + (size_t)row * D_STATE + c0) = o;
  } else {
    const int idx = (blk - CBC_NB) * 256 + threadIdx.x;
    const int row = idx / 3, q = idx % 3;
    const int b = row / SEQLEN, t = row % SEQLEN;
    const int h0 = q * 8;
    us8v dv = *(const us8v*)(draw + (size_t)row * 24 + h0);
#pragma unroll
    for (int j = 0; j < 8; ++j) {
      float v = bf2f(dv[j]) + dt_bias[h0 + j];
      dtoT[(size_t)(b * NHEADS + h0 + j) * SEQLEN + t] = softplus_f(v);
    }
  }
}

// ---------------------------------------------------------------------------
// K3 (MFMA, 8 waves, fused x-conv, factored decay, K16 PV):
// 1D grid (1536) with XCD-aware remap (r27).
// ---------------------------------------------------------------------------
__global__ __launch_bounds__(512, 4)
void ssd_mfma_kernel(const unsigned short* __restrict__ xT, const unsigned short* __restrict__ Bo,
                     const unsigned short* __restrict__ Co, const float* __restrict__ dtoT,
                     const float* __restrict__ A_log, const float* __restrict__ conv_w,
                     const float* __restrict__ conv_b, const float* __restrict__ Dvec,
                     unsigned short* __restrict__ YdT, float* __restrict__ acum_g,
                     float* __restrict__ csum_g, float* __restrict__ stloc) {
  const int bid  = blockIdx.x;
  const int wrk  = (bid & 7) * 192 + (bid >> 3);
  const int b    = wrk / 768;
  const int rem  = wrk % 768;
  const int cidx = rem / NHEADS;
  const int h    = rem % NHEADS;
  const int tid  = threadIdx.x;
  const int wid  = tid >> 6, lane = tid & 63;
  const int fr   = lane & 15, g = lane >> 4;

  __shared__ unsigned short Bs[256 * 24 + 32];
  __shared__ unsigned short xsT[16 * 264];
  __shared__ unsigned short BwT[16 * 264];
  __shared__ unsigned short xraw[259 * 16 + 8];
  __shared__ float sc2[CHUNK];
  __shared__ float scE[16];
  __shared__ float wsum[4];

  const float Ah = -expf(A_log[h]);
  const us8v z8 = { 0, 0, 0, 0, 0, 0, 0, 0 };

  float v = 0.f;
  if (tid < CHUNK) {
    v = dtoT[(size_t)(b * NHEADS + h) * SEQLEN + (size_t)cidx * CHUNK + tid] * Ah;
#pragma unroll
    for (int off = 1; off < 64; off <<= 1) {
      float u = __shfl_up(v, off, 64);
      if (lane >= off) v += u;
    }
    if (lane == 63) wsum[wid] = v;
  }

  const int r  = tid >> 1;
  const int hf = tid & 1;
  const size_t rowbase = (size_t)b * SEQLEN + (size_t)cidx * CHUNK;
  const size_t rhrow = (size_t)(b * NHEADS + h) * SEQLEN + (size_t)cidx * CHUNK + r;
  const float rdtv = dtoT[rhrow];
  us8v bh = ((const us8v*)(Bo + (rowbase + r) * D_STATE))[hf];
  if (hf == 0) *(us8v*)&Bs[r * 24 + 16] = z8;
  if (tid < 32) Bs[256 * 24 + tid] = 0;
  {
    const int tg = cidx * CHUNK + r - 3;
    us8v xv = z8;
    if (tg >= 0)
      xv = *(const us8v*)(xT + (((size_t)(b * NHEADS + h) * SEQLEN + tg) << 4) + 8 * hf);
    *(us8v*)&xraw[r * 16 + 8 * hf] = xv;
    if (tid < 6) {
      const int rr2 = 256 + (tid >> 1);
      const int hf2 = tid & 1;
      const int tg2 = cidx * CHUNK + rr2 - 3;
      us8v xv2 = *(const us8v*)(xT + (((size_t)(b * NHEADS + h) * SEQLEN + tg2) << 4) + 8 * hf2);
      *(us8v*)&xraw[rr2 * 16 + 8 * hf2] = xv2;
    }
  }
  __syncthreads();   // #1

  us8v xsil, xdt8;
  {
    us8v tA = *(const us8v*)&xraw[(r + 0) * 16 + 8 * hf];
    us8v tB = *(const us8v*)&xraw[(r + 1) * 16 + 8 * hf];
    us8v tC = *(const us8v*)&xraw[(r + 2) * 16 + 8 * hf];
    us8v tD = *(const us8v*)&xraw[(r + 3) * 16 + 8 * hf];
    const int cbase = h * HEADDIM + 8 * hf;
#pragma unroll
    for (int ch = 0; ch < 8; ++ch) {
      const float4 wv = *(const float4*)(conv_w + (cbase + ch) * 4);
      float acc = conv_b[cbase + ch] + wv.x * bf2f(tA[ch]) + wv.y * bf2f(tB[ch])
                + wv.z * bf2f(tC[ch]) + wv.w * bf2f(tD[ch]);
      float sv = silu_f(acc);
      xsil[ch] = f2bf(sv);
      xdt8[ch] = f2bf(sv * rdtv);
    }
  }
  const float ctot  = wsum[0] + wsum[1] + wsum[2] + wsum[3];
  const float ctot2 = ctot * LOG2E;
  if (tid < CHUNK) {
    float pre = 0.f;
#pragma unroll
    for (int w = 0; w < 4; ++w) if (w < wid) pre += wsum[w];
    v += pre;
    sc2[tid] = v * LOG2E;
    acum_g[(size_t)(b * NHEADS + h) * SEQLEN + (size_t)cidx * CHUNK + tid] = v;
    if (tid == CHUNK - 1) csum_g[(b * NHEADS + h) * NCHUNKS + cidx] = v;
  }
  __syncthreads();   // #2

  *(us8v*)&xraw[(r + 3) * 16 + 8 * hf] = xsil;
#pragma unroll
  for (int q = 0; q < 8; ++q)
    xsT[(q + 8 * hf) * 264 + r] = xdt8[q];
  {
    const float wdv = exp2f(ctot2 - sc2[r]);
    const float ed  = exp2f(sc2[r | 15] - sc2[r]);   // <= 1
    us8v bscaled;
#pragma unroll
    for (int q = 0; q < 8; ++q) {
      BwT[(q + 8 * hf) * 264 + r] = f2bf(bf2f(bh[q]) * wdv);
      bscaled[q] = f2bf(bf2f(bh[q]) * ed);
    }
    *(us8v*)&Bs[r * 24 + 8 * hf] = bscaled;
  }
  if (tid < 16) scE[tid] = sc2[tid * 16 + 15];
  __syncthreads();   // #3 (last barrier)

  if (wid == 0) {
    f32x4 accS = {};
#pragma unroll
    for (int k2 = 0; k2 < 8; ++k2) {
      bf16x8 af = *(const bf16x8*)&BwT[fr * 264 + 32 * k2 + 8 * g];
      bf16x8 bb = *(const bf16x8*)&xsT[fr * 264 + 32 * k2 + 8 * g];
      accS = __builtin_amdgcn_mfma_f32_16x16x32_bf16(af, bb, accS, 0, 0, 0);
    }
    *(f32x4*)&stloc[((size_t)(b * NCHUNKS + cidx) * NHEADS + h) * 256 + fr * 16 + 4 * g] = accS;
  }

  const f32x4 zf = { 0.f, 0.f, 0.f, 0.f };
  const unsigned short* Cbase = Co + rowbase * D_STATE;
  const float Dh = Dvec[h];
  const int strips[2] = { wid, 15 - wid };

  bf16x8 brawq[2];
#pragma unroll
  for (int q = 0; q < 2; ++q) {
    us8v bv = z8;
    if (g < 2)
      bv = *(const us8v*)(Bo + (rowbase + strips[q] * 16 + fr) * D_STATE + 8 * g);
    brawq[q] = __builtin_bit_cast(bf16x8, bv);
  }

#if HAVE_MFMA16
#pragma unroll
  for (int q = 0; q < 2; ++q) {
    const int lt = strips[q];
    f32x4 acc = zf;
    bf16x8 cf = { 0, 0, 0, 0, 0, 0, 0, 0 };
    if (g < 2) cf = *(const bf16x8*)(Cbase + (size_t)(lt * 16 + fr) * D_STATE + 8 * g);
    const float acl2 = sc2[lt * 16 + fr];
    const int   lg   = lt * 16 + fr;
    for (int st = 0; st <= lt; ++st) {
      uint2 pp;
      if (st < lt) {
        bf16x8 bfg = *(const bf16x8*)&Bs[(st * 16 + fr) * 24 + 8 * g];
        f32x4 G = __builtin_amdgcn_mfma_f32_16x16x32_bf16(bfg, cf, zf, 0, 0, 0);
        const float wl = exp2f(acl2 - scE[st]);
        pp.x = pk_bf(G[0] * wl, G[1] * wl);
        pp.y = pk_bf(G[2] * wl, G[3] * wl);
      } else {
        f32x4 G = __builtin_amdgcn_mfma_f32_16x16x32_bf16(brawq[q], cf, zf, 0, 0, 0);
        f32x4 se2 = *(const f32x4*)&sc2[st * 16 + 4 * g];
        const int sbase = st * 16 + 4 * g;
        float w0 = (sbase + 0 <= lg) ? exp2f(acl2 - se2[0]) : 0.f;
        float w1 = (sbase + 1 <= lg) ? exp2f(acl2 - se2[1]) : 0.f;
        float w2 = (sbase + 2 <= lg) ? exp2f(acl2 - se2[2]) : 0.f;
        float w3 = (sbase + 3 <= lg) ? exp2f(acl2 - se2[3]) : 0.f;
        pp.x = pk_bf(G[0] * w0, G[1] * w1);
        pp.y = pk_bf(G[2] * w2, G[3] * w3);
      }
      const bf16x4 p4 = __builtin_bit_cast(bf16x4, pp);
      const bf16x4 x4 = *(const bf16x4*)&xsT[fr * 264 + st * 16 + 4 * g];
      acc = MFMA16(x4, p4, acc);
    }
    us4v xs4 = *(const us4v*)&xraw[(lt * 16 + fr + 3) * 16 + 4 * g];
    us4v o = { f2bf(acc[0] + Dh * bf2f(xs4[0])),
               f2bf(acc[1] + Dh * bf2f(xs4[1])),
               f2bf(acc[2] + Dh * bf2f(xs4[2])),
               f2bf(acc[3] + Dh * bf2f(xs4[3])) };
    *(us4v*)(YdT + (rhrow - r + (size_t)lt * 16 + fr) * HEADDIM + 4 * g) = o;
  }
#else
  const int Ls0 = fr + ((g & 1) << 5);
  const int Ls1 = Ls0 + 16;
  const bool hiq = (g >= 2);
#pragma unroll
  for (int q = 0; q < 2; ++q) {
    const int lt = strips[q];
    f32x4 acc = zf;
    bf16x8 cf = { 0, 0, 0, 0, 0, 0, 0, 0 };
    if (g < 2) cf = *(const bf16x8*)(Cbase + (size_t)(lt * 16 + fr) * D_STATE + 8 * g);
    const float acl2 = sc2[lt * 16 + fr];
    const int   lg   = lt * 16 + fr;
    const int npair = (lt + 2) >> 1;
    for (int sp = 0; sp < npair; ++sp) {
      uint2 pk[2];
#pragma unroll
      for (int ti = 0; ti < 2; ++ti) {
        const int st = 2 * sp + ti;
        if (st < lt) {
          bf16x8 bfg = *(const bf16x8*)&Bs[(st * 16 + fr) * 24 + 8 * g];
          f32x4 G = __builtin_amdgcn_mfma_f32_16x16x32_bf16(bfg, cf, zf, 0, 0, 0);
          const float wl = exp2f(acl2 - scE[st]);
          pk[ti].x = pk_bf(G[0] * wl, G[1] * wl);
          pk[ti].y = pk_bf(G[2] * wl, G[3] * wl);
        } else if (st == lt) {
          f32x4 G = __builtin_amdgcn_mfma_f32_16x16x32_bf16(brawq[q], cf, zf, 0, 0, 0);
          f32x4 se2 = *(const f32x4*)&sc2[st * 16 + 4 * g];
          const int sbase = st * 16 + 4 * g;
          float w0 = (sbase + 0 <= lg) ? exp2f(acl2 - se2[0]) : 0.f;
          float w1 = (sbase + 1 <= lg) ? exp2f(acl2 - se2[1]) : 0.f;
          float w2 = (sbase + 2 <= lg) ? exp2f(acl2 - se2[2]) : 0.f;
          float w3 = (sbase + 3 <= lg) ? exp2f(acl2 - se2[3]) : 0.f;
          pk[ti].x = pk_bf(G[0] * w0, G[1] * w1);
          pk[ti].y = pk_bf(G[2] * w2, G[3] * w3);
        } else {
          pk[ti].x = 0u; pk[ti].y = 0u;
        }
      }
      const int a00 = __shfl((int)pk[0].x, Ls0, 64);
      const int a10 = __shfl((int)pk[0].y, Ls0, 64);
      const int a01 = __shfl((int)pk[0].x, Ls1, 64);
      const int a11 = __shfl((int)pk[0].y, Ls1, 64);
      const int b00 = __shfl((int)pk[1].x, Ls0, 64);
      const int b10 = __shfl((int)pk[1].y, Ls0, 64);
      const int b01 = __shfl((int)pk[1].x, Ls1, 64);
      const int b11 = __shfl((int)pk[1].y, Ls1, 64);
      u32x4 pw;
      pw[0] = (unsigned)(hiq ? b00 : a00);
      pw[1] = (unsigned)(hiq ? b10 : a10);
      pw[2] = (unsigned)(hiq ? b01 : a01);
      pw[3] = (unsigned)(hiq ? b11 : a11);
      const bf16x8 pf = __builtin_bit_cast(bf16x8, pw);
      const bf16x8 xf = *(const bf16x8*)&xsT[fr * 264 + sp * 32 + 8 * g];
      acc = __builtin_amdgcn_mfma_f32_16x16x32_bf16(xf, pf, acc, 0, 0, 0);
    }
    us4v xs4 = *(const us4v*)&xraw[(lt * 16 + fr + 3) * 16 + 4 * g];
    us4v o = { f2bf(acc[0] + Dh * bf2f(xs4[0])),
               f2bf(acc[1] + Dh * bf2f(xs4[1])),
               f2bf(acc[2] + Dh * bf2f(xs4[2])),
               f2bf(acc[3] + Dh * bf2f(xs4[3])) };
    *(us4v*)(YdT + (rhrow - r + (size_t)lt * 16 + fr) * HEADDIM + 4 * g) = o;
  }
#endif
}

// ---------------------------------------------------------------------------
// K4: sequential inter-chunk state recurrence
// ---------------------------------------------------------------------------
__global__ __launch_bounds__(256)
void chunk_scan_kernel(const float* __restrict__ stloc, const float* __restrict__ csum_g,
                       float* __restrict__ stpre) {
  const int b  = blockIdx.x / NHEADS;
  const int h  = blockIdx.x % NHEADS;
  const int pn = threadIdx.x;
  float S = 0.0f;
  for (int c = 0; c < NCHUNKS; ++c) {
    const size_t idx = ((size_t)(b * NCHUNKS + c) * NHEADS + h) * 256 + pn;
    stpre[idx] = S;
    S = __expf(csum_g[(b * NHEADS + h) * NCHUNKS + c]) * S + stloc[idx];
  }
}

// ---------------------------------------------------------------------------
// K5 (fused, 12 waves): Y_off, silu(z) gate, RMSNorm, out = yn @ W_out^T.
// r29: RMSNorm row-scale commuted into the GEMM epilogue —
// ynL holds bf16(yg*nw) (unnormalized), loop 2 + barrier #3 removed;
// each GEMM lane computes scale[fr] once and scales the f32 accumulator.
// ---------------------------------------------------------------------------
#define TT 16
#define LDY 392
__global__ __launch_bounds__(768)
void yoff_norm_gemm(const unsigned short* __restrict__ YdT,
                    const unsigned short* __restrict__ Co, const float* __restrict__ acum_g,
                    const float* __restrict__ stpre,
                    const unsigned short* __restrict__ zbuf, const float* __restrict__ norm_w,
                    const unsigned short* __restrict__ Wo,
                    float* __restrict__ out) {
  const int bid  = blockIdx.x;
  const int wz   = (bid & 7) * 128 + (bid >> 3);   // bijective: 1024 % 8 == 0
  const int r0   = wz * TT;
  const int b    = r0 / SEQLEN;
  const int t0   = r0 % SEQLEN;
  const int cidx = t0 / CHUNK;
  const int tid  = threadIdx.x;
  const int d    = tid % 384;
  const int half = tid / 384;
  const int h    = d >> 4, p = d & 15;
  const int wv   = tid >> 6;

  __shared__ unsigned short Yt[NHEADS * TT * 16];
  __shared__ unsigned short zL[TT * 384];
  __shared__ unsigned short ynL[TT * LDY];
  __shared__ float At[NHEADS * TT];
  __shared__ float Ct[TT * 16];
  __shared__ float red[TT][8];     // padded to 32B rows for vector reads

  {
    us8v* Yt8 = (us8v*)Yt;
    int hh = tid >> 5, q = tid & 31;
    const size_t src = ((size_t)(b * NHEADS + hh) * SEQLEN + t0) * HEADDIM + q * 8;
    Yt8[tid] = *(const us8v*)(YdT + src);
    const int zr = tid / 48, zc = (tid % 48) * 8;
    *(us8v*)&zL[zr * 384 + zc] = *(const us8v*)(zbuf + (size_t)(r0 + zr) * 384 + zc);
    if (tid < NHEADS * TT)
      At[tid] = __expf(acum_g[(size_t)(b * NHEADS + (tid >> 4)) * SEQLEN + t0 + (tid & 15)]);
    if (tid < TT * 16) Ct[tid] = bf2f(Co[(size_t)r0 * D_STATE + tid]);
    if (tid < TT * 2) red[tid >> 1][6 + (tid & 1)] = 0.f;
  }

  f32x4 S4[4];
  {
    const float* Sp = stpre + ((size_t)(b * NCHUNKS + cidx) * NHEADS + h) * 256 + p * 16;
#pragma unroll
    for (int q = 0; q < 4; ++q) S4[q] = *(const f32x4*)(Sp + 4 * q);
  }
  const float nw = norm_w[d];
  __syncthreads();   // #1

  const int tb = half * 8;
#pragma unroll
  for (int ti = 0; ti < 8; ++ti) {
    const int tt = tb + ti;
    const f32x4* C4 = (const f32x4*)&Ct[tt * 16];
    f32x4 d4 = C4[0] * S4[0];
    d4 = d4 + C4[1] * S4[1];
    d4 = d4 + C4[2] * S4[2];
    d4 = d4 + C4[3] * S4[3];
    const float dot = (d4[0] + d4[1]) + (d4[2] + d4[3]);
    const float eA = At[h * TT + tt];
    float y = bf2f(Yt[h * 256 + tt * 16 + p]) + eA * dot;
    const float z = bf2f(zL[tt * 384 + d]);
    const float yg = y * silu_f(z);
    ynL[tt * LDY + d] = f2bf(yg * nw);       // unnormalized; scale in epilogue
    float s = yg * yg;
#pragma unroll
    for (int off = 32; off > 0; off >>= 1) s += __shfl_down(s, off);
    if ((tid & 63) == 0) red[tt][wv - half * 6] = s;
  }
  __syncthreads();   // #2 (last barrier)

  const int lane = tid & 63;
  const int fr = lane & 15, fq = lane >> 4;
  const int n0 = wv * 16;
  // per-lane row scale from red[fr][]
  const f32x4 r4 = *(const f32x4*)&red[fr][0];
  const float tot = ((r4[0] + r4[1]) + (r4[2] + r4[3])) + (red[fr][4] + red[fr][5]);
  const float scale = rsqrtf(tot * (1.0f / D_INNER) + EPS);
  f32x4 accg = {};
  __builtin_amdgcn_s_setprio(1);
#pragma unroll
  for (int kt = 0; kt < 12; ++kt) {
    const bf16x8 af = *(const bf16x8*)&ynL[fr * LDY + kt * 32 + 8 * fq];
    const int col = n0 + fr;
    const bf16x8 bfr = *(const bf16x8*)(Wo + (size_t)col * D_INNER + kt * 32 + 8 * fq);
    accg = __builtin_amdgcn_mfma_f32_16x16x32_bf16(bfr, af, accg, 0, 0, 0);
  }
  __builtin_amdgcn_s_setprio(0);
  float4 o = make_float4(accg[0] * scale, accg[1] * scale,
                         accg[2] * scale, accg[3] * scale);
  *(float4*)(out + (size_t)(r0 + fr) * D_MODEL + n0 + fq * 4) = o;
}

// ---------------------------------------------------------------------------
extern "C" void kernel_launch(void* const* d_in, const int* in_sizes, int n_in,
                              void* d_out, int out_size, void* d_ws, size_t ws_size,
                              hipStream_t stream) {
  const float* u        = (const float*)d_in[0];
  const float* support  = (const float*)d_in[1];
  const float* W_in     = (const float*)d_in[2];
  const float* W_in_b   = (const float*)d_in[3];
  const float* conv_w   = (const float*)d_in[4];
  const float* conv_b   = (const float*)d_in[5];
  const float* conv_w_b = (const float*)d_in[6];
  const float* conv_b_b = (const float*)d_in[7];
  const float* dt_bias  = (const float*)d_in[8];
  const float* A_log    = (const float*)d_in[9];
  const float* Dvec     = (const float*)d_in[10];
  const float* norm_w   = (const float*)d_in[11];
  const float* W_out    = (const float*)d_in[12];
  float* out = (float*)d_out;
  char* wsb  = (char*)d_ws;

  unsigned short* Wi_b  = (unsigned short*)(wsb);
  unsigned short* Wo_b  = Wi_b + (size_t)D_IN_PROJ * D_MODEL;
  unsigned short* Wib_b = Wo_b + (size_t)D_MODEL * D_INNER;
  unsigned short* zbuf  = Wib_b + (size_t)D_STATE * D_MODEL;
  unsigned short* xT    = zbuf + (size_t)ROWS * D_INNER;
  unsigned short* Braw  = xT + (size_t)ROWS * D_INNER;
  unsigned short* draw  = Braw + (size_t)ROWS * D_STATE;
  unsigned short* craw  = draw + (size_t)ROWS * NHEADS;
  unsigned short* Bo    = craw + (size_t)ROWS * D_STATE;
  unsigned short* Co    = Bo + (size_t)ROWS * D_STATE;
  unsigned short* YdT   = Co + (size_t)ROWS * D_STATE;
  float* dtoT  = (float*)(YdT + (size_t)ROWS * D_INNER);
  float* acum  = dtoT  + (size_t)ROWS * NHEADS;
  float* csum  = acum  + (size_t)BATCH * NHEADS * SEQLEN;
  float* stloc = csum  + (size_t)BATCH * NHEADS * NCHUNKS;
  float* stpre = stloc + (size_t)BATCH * NCHUNKS * NHEADS * 256;

  cvt3_kernel<<<224, 256, 0, stream>>>(W_in, Wi_b, (long)D_IN_PROJ * D_MODEL,
                                       W_out, Wo_b, (long)D_MODEL * D_INNER,
                                       W_in_b, Wib_b, (long)D_STATE * D_MODEL);
  gemm_in_merged<<<dim3(8, ROWS / 128), 256, 0, stream>>>(
      u, Wi_b, support, Wib_b, craw, zbuf, xT, Braw, draw);
  conv_bcdt<<<CBC_NB + CDT_NB, 256, 0, stream>>>(
      Braw, craw, draw, conv_w, conv_b, conv_w_b, conv_b_b, dt_bias, Bo, Co, dtoT);
  ssd_mfma_kernel<<<NHEADS * NCHUNKS * BATCH, 512, 0, stream>>>(
      xT, Bo, Co, dtoT, A_log, conv_w, conv_b, Dvec, YdT, acum, csum, stloc);
  chunk_scan_kernel<<<BATCH * NHEADS, 256, 0, stream>>>(stloc, csum, stpre);
  yoff_norm_gemm<<<ROWS / TT, 768, 0, stream>>>(YdT, Co, acum, stpre, zbuf, norm_w,
                                                Wo_b, out);
}

// Round 30
// 106.560 us; speedup vs baseline: 1.2878x; 1.0635x over previous
//
#include <hip/hip_runtime.h>
#include <cmath>

#define ROWS      16384
#define SEQLEN    8192
#define BATCH     2
#define NHEADS    24
#define HEADDIM   16
#define D_STATE   16
#define D_INNER   384
#define D_MODEL   192
#define D_IN_PROJ 808
#define CONV_DIM  400
#define NCHUNKS   32
#define CHUNK     256
#define EPS       1e-5f
#define LOG2E     1.44269504088896f

typedef short bf16x8 __attribute__((ext_vector_type(8)));
typedef short bf16x4 __attribute__((ext_vector_type(4)));
typedef float f32x4  __attribute__((ext_vector_type(4)));
typedef unsigned short us4v __attribute__((ext_vector_type(4)));
typedef unsigned short us8v __attribute__((ext_vector_type(8)));
typedef unsigned int  u32x4 __attribute__((ext_vector_type(4)));

#if __has_builtin(__builtin_amdgcn_mfma_f32_16x16x16bf16_1k)
#define MFMA16(a, b, c) __builtin_amdgcn_mfma_f32_16x16x16bf16_1k((a), (b), (c), 0, 0, 0)
#define HAVE_MFMA16 1
#elif __has_builtin(__builtin_amdgcn_mfma_f32_16x16x16_bf16)
#define MFMA16(a, b, c) __builtin_amdgcn_mfma_f32_16x16x16_bf16((a), (b), (c), 0, 0, 0)
#define HAVE_MFMA16 1
#else
#define HAVE_MFMA16 0
#endif

__device__ __forceinline__ float silu_f(float x) { return x / (1.0f + expf(-x)); }
__device__ __forceinline__ float softplus_f(float x) { return (x > 20.0f) ? x : log1pf(expf(x)); }
__device__ __forceinline__ unsigned short f2bf(float x) {
  unsigned u = __builtin_bit_cast(unsigned, x);
  u += 0x7fff + ((u >> 16) & 1);
  return (unsigned short)(u >> 16);
}
__device__ __forceinline__ float bf2f(unsigned short s) {
  unsigned u = (unsigned)s << 16;
  return __builtin_bit_cast(float, u);
}
__device__ __forceinline__ unsigned pk_bf(float a, float b) {
  unsigned ua = __builtin_bit_cast(unsigned, a) + 0x7fffu;
  unsigned ub = __builtin_bit_cast(unsigned, b) + 0x7fffu;
  return __builtin_amdgcn_perm(ub, ua, 0x07060302u);
}

// ---------------------------------------------------------------------------
// K0: fp32 -> bf16 weights (W_in, W_out * norm_w, W_in_b).
// r30: norm_w folded into W_out columns (nw is per-d; Wo row-major [192][384]).
// ---------------------------------------------------------------------------
__global__ __launch_bounds__(256)
void cvt3_kernel(const float* __restrict__ a, unsigned short* __restrict__ ao, long na,
                 const float* __restrict__ b, unsigned short* __restrict__ bo, long nb,
                 const float* __restrict__ c, unsigned short* __restrict__ co, long nc,
                 const float* __restrict__ nwp) {
  const long t0 = na >> 2, t1 = t0 + (nb >> 2), t2 = t1 + (nc >> 2);
  const long stride = (long)gridDim.x * blockDim.x;
  for (long i = (long)blockIdx.x * blockDim.x + threadIdx.x; i < t2; i += stride) {
    if (i < t0) {
      float4 v = ((const float4*)a)[i];
      us4v o = { f2bf(v.x), f2bf(v.y), f2bf(v.z), f2bf(v.w) };
      ((us4v*)ao)[i] = o;
    } else if (i < t1) {
      const long j = i - t0;
      float4 v = ((const float4*)b)[j];
      const int d0 = (int)((j * 4) % D_INNER);
      const float4 nw4 = *(const float4*)(nwp + d0);
      us4v o = { f2bf(v.x * nw4.x), f2bf(v.y * nw4.y),
                 f2bf(v.z * nw4.z), f2bf(v.w * nw4.w) };
      ((us4v*)bo)[j] = o;
    } else {
      const long j = i - t1;
      float4 v = ((const float4*)c)[j];
      us4v o = { f2bf(v.x), f2bf(v.y), f2bf(v.z), f2bf(v.w) };
      ((us4v*)co)[j] = o;
    }
  }
}

// ---------------------------------------------------------------------------
// GEMM body (device fn; LDS passed in).
// ---------------------------------------------------------------------------
template<bool OUT_BF16, bool ROUTE>
__device__ __forceinline__
void gemm_body(unsigned short* __restrict__ As, unsigned short* __restrict__ Ws,
               const float* __restrict__ A, const unsigned short* __restrict__ W,
               void* __restrict__ Cp, int M, int N, int K, int bx, int by,
               unsigned short* __restrict__ zbuf, unsigned short* __restrict__ xT,
               unsigned short* __restrict__ Braw, unsigned short* __restrict__ draw) {
  constexpr int BM = 128, BN = 128, BK = 32, LDK = 40;
  const int tid  = threadIdx.x;
  const int wid  = tid >> 6, lane = tid & 63;
  const int wr   = wid >> 1, wc = wid & 1;
  const int fr   = lane & 15, fq = lane >> 4;
  const long m0  = (long)by * BM;
  const int  n0  = bx * BN;

  f32x4 acc[4][4] = {};

  auto stage = [&](int k0, int buf) {
#pragma unroll
    for (int p = 0; p < 2; ++p) {
      int flat = p * 2048 + tid * 8;
      int r = flat >> 5, c = flat & 31;
      const float4* src = (const float4*)(A + (m0 + r) * (long)K + k0 + c);
      float4 v0 = src[0], v1 = src[1];
      us8v o = { f2bf(v0.x), f2bf(v0.y), f2bf(v0.z), f2bf(v0.w),
                 f2bf(v1.x), f2bf(v1.y), f2bf(v1.z), f2bf(v1.w) };
      *(us8v*)&As[buf * BM * LDK + r * LDK + c] = o;
    }
#pragma unroll
    for (int p = 0; p < 2; ++p) {
      int flat = p * 2048 + tid * 8;
      int r = flat >> 5, c = flat & 31;
      int gn = n0 + r;
      us8v v = { 0, 0, 0, 0, 0, 0, 0, 0 };
      if (gn < N) v = *(const us8v*)(W + (long)gn * K + k0 + c);
      *(us8v*)&Ws[buf * BN * LDK + r * LDK + c] = v;
    }
  };

  const int nk = K / BK;
  stage(0, 0);
  __syncthreads();
  for (int kt = 0; kt < nk; ++kt) {
    const int cur = kt & 1;
    if (kt + 1 < nk) stage((kt + 1) * BK, cur ^ 1);
    bf16x8 af[4], bfr[4];
#pragma unroll
    for (int m = 0; m < 4; ++m)
      af[m] = *(const bf16x8*)&As[cur * BM * LDK + (wr * 64 + m * 16 + fr) * LDK + fq * 8];
#pragma unroll
    for (int n = 0; n < 4; ++n)
      bfr[n] = *(const bf16x8*)&Ws[cur * BN * LDK + (wc * 64 + n * 16 + fr) * LDK + fq * 8];
#pragma unroll
    for (int m = 0; m < 4; ++m)
#pragma unroll
      for (int n = 0; n < 4; ++n)
        acc[m][n] = __builtin_amdgcn_mfma_f32_16x16x32_bf16(bfr[n], af[m], acc[m][n], 0, 0, 0);
    __syncthreads();
  }

#pragma unroll
  for (int m = 0; m < 4; ++m) {
    const long gm = m0 + wr * 64 + m * 16 + fr;
#pragma unroll
    for (int n = 0; n < 4; ++n) {
      const int gn = n0 + wc * 64 + n * 16 + fq * 4;
      if (gn < N) {
        if (ROUTE) {
          us4v o = { f2bf(acc[m][n][0]), f2bf(acc[m][n][1]),
                     f2bf(acc[m][n][2]), f2bf(acc[m][n][3]) };
          const int bb = (int)(gm >> 13);
          const long t = gm & 8191;
          if (gn < 384) {
            *(us4v*)(zbuf + gm * 384 + gn) = o;
          } else if (gn < 768) {
            const int c = gn - 384, hh = c >> 4, ii = c & 15;
            *(us4v*)(xT + (((size_t)(bb * NHEADS + hh) * SEQLEN + t) << 4) + ii) = o;
          } else if (gn < 784) {
            *(us4v*)(Braw + gm * 16 + (gn - 768)) = o;
          } else {
            *(us4v*)(draw + gm * 24 + (gn - 784)) = o;
          }
        } else if (OUT_BF16) {
          us4v o = { f2bf(acc[m][n][0]), f2bf(acc[m][n][1]),
                     f2bf(acc[m][n][2]), f2bf(acc[m][n][3]) };
          *(us4v*)((unsigned short*)Cp + gm * N + gn) = o;
        } else {
          float4 o = make_float4(acc[m][n][0], acc[m][n][1], acc[m][n][2], acc[m][n][3]);
          *(float4*)((float*)Cp + gm * N + gn) = o;
        }
      }
    }
  }
}

// ---------------------------------------------------------------------------
// K1 (merged): bx<7 -> routed in-proj (u @ W_in^T); bx==7 -> support @ W_in_b^T
// ---------------------------------------------------------------------------
__global__ __launch_bounds__(256, 3)
void gemm_in_merged(const float* __restrict__ u, const unsigned short* __restrict__ Wi,
                    const float* __restrict__ support, const unsigned short* __restrict__ Wib,
                    unsigned short* __restrict__ craw,
                    unsigned short* __restrict__ zbuf, unsigned short* __restrict__ xT,
                    unsigned short* __restrict__ Braw, unsigned short* __restrict__ draw) {
  __shared__ unsigned short As[2 * 128 * 40];
  __shared__ unsigned short Ws[2 * 128 * 40];
  if (blockIdx.x < 7)
    gemm_body<true, true>(As, Ws, u, Wi, nullptr, ROWS, D_IN_PROJ, D_MODEL,
                          blockIdx.x, blockIdx.y, zbuf, xT, Braw, draw);
  else
    gemm_body<true, false>(As, Ws, support, Wib, craw, ROWS, D_STATE, D_MODEL,
                           0, blockIdx.y, nullptr, nullptr, nullptr, nullptr);
}

// ---------------------------------------------------------------------------
// K2: B/C conv + dt softplus, dense raw buffers. 448 role-pure blocks.
// ---------------------------------------------------------------------------
#define CBC_NB  (ROWS * 4 / 256)    // 256
#define CDT_NB  (ROWS * 3 / 256)    // 192

__global__ __launch_bounds__(256)
void conv_bcdt(const unsigned short* __restrict__ Braw, const unsigned short* __restrict__ craw,
               const unsigned short* __restrict__ draw,
               const float* __restrict__ conv_w, const float* __restrict__ conv_b,
               const float* __restrict__ conv_w_b, const float* __restrict__ conv_b_b,
               const float* __restrict__ dt_bias,
               unsigned short* __restrict__ Bo, unsigned short* __restrict__ Co,
               float* __restrict__ dtoT) {
  const int blk = blockIdx.x;
  const us8v z8 = { 0, 0, 0, 0, 0, 0, 0, 0 };

  if (blk < CBC_NB) {
    const int idx = blk * 256 + threadIdx.x;
    const int row = idx / 4, q = idx % 4;
    const int b = row / SEQLEN, t = row % SEQLEN;

    const unsigned short* src = (q < 2) ? Braw : craw;
    const float* cw = (q < 2) ? conv_w + 384 * 4 : conv_w_b;
    const float* cb = (q < 2) ? conv_b + 384 : conv_b_b;
    const int c0 = (q & 1) * 8;
    const unsigned short* base = src + (size_t)row * D_STATE + c0;
    us8v x0 = (t >= 3) ? *(const us8v*)(base - 3 * D_STATE) : z8;
    us8v x1 = (t >= 2) ? *(const us8v*)(base - 2 * D_STATE) : z8;
    us8v x2 = (t >= 1) ? *(const us8v*)(base - 1 * D_STATE) : z8;
    us8v x3 = *(const us8v*)base;
    us8v o;
#pragma unroll
    for (int ch = 0; ch < 8; ++ch) {
      const float4 wv = *(const float4*)(cw + (c0 + ch) * 4);
      float acc = cb[c0 + ch] + wv.x * bf2f(x0[ch]) + wv.y * bf2f(x1[ch])
                + wv.z * bf2f(x2[ch]) + wv.w * bf2f(x3[ch]);
      o[ch] = f2bf(silu_f(acc));
    }
    if (q < 2) *(us8v*)(Bo + (size_t)row * D_STATE + c0) = o;
    else       *(us8v*)(Co + (size_t)row * D_STATE + c0) = o;
  } else {
    const int idx = (blk - CBC_NB) * 256 + threadIdx.x;
    const int row = idx / 3, q = idx % 3;
    const int b = row / SEQLEN, t = row % SEQLEN;
    const int h0 = q * 8;
    us8v dv = *(const us8v*)(draw + (size_t)row * 24 + h0);
#pragma unroll
    for (int j = 0; j < 8; ++j) {
      float v = bf2f(dv[j]) + dt_bias[h0 + j];
      dtoT[(size_t)(b * NHEADS + h0 + j) * SEQLEN + t] = softplus_f(v);
    }
  }
}

// ---------------------------------------------------------------------------
// K3 (MFMA, 8 waves, fused x-conv, factored decay, K16 PV):
// 1D grid (1536) with XCD-aware remap (r27).
// ---------------------------------------------------------------------------
__global__ __launch_bounds__(512, 4)
void ssd_mfma_kernel(const unsigned short* __restrict__ xT, const unsigned short* __restrict__ Bo,
                     const unsigned short* __restrict__ Co, const float* __restrict__ dtoT,
                     const float* __restrict__ A_log, const float* __restrict__ conv_w,
                     const float* __restrict__ conv_b, const float* __restrict__ Dvec,
                     unsigned short* __restrict__ YdT, float* __restrict__ acum_g,
                     float* __restrict__ csum_g, float* __restrict__ stloc) {
  const int bid  = blockIdx.x;
  const int wrk  = (bid & 7) * 192 + (bid >> 3);
  const int b    = wrk / 768;
  const int rem  = wrk % 768;
  const int cidx = rem / NHEADS;
  const int h    = rem % NHEADS;
  const int tid  = threadIdx.x;
  const int wid  = tid >> 6, lane = tid & 63;
  const int fr   = lane & 15, g = lane >> 4;

  __shared__ unsigned short Bs[256 * 24 + 32];
  __shared__ unsigned short xsT[16 * 264];
  __shared__ unsigned short BwT[16 * 264];
  __shared__ unsigned short xraw[259 * 16 + 8];
  __shared__ float sc2[CHUNK];
  __shared__ float scE[16];
  __shared__ float wsum[4];

  const float Ah = -expf(A_log[h]);
  const us8v z8 = { 0, 0, 0, 0, 0, 0, 0, 0 };

  float v = 0.f;
  if (tid < CHUNK) {
    v = dtoT[(size_t)(b * NHEADS + h) * SEQLEN + (size_t)cidx * CHUNK + tid] * Ah;
#pragma unroll
    for (int off = 1; off < 64; off <<= 1) {
      float u = __shfl_up(v, off, 64);
      if (lane >= off) v += u;
    }
    if (lane == 63) wsum[wid] = v;
  }

  const int r  = tid >> 1;
  const int hf = tid & 1;
  const size_t rowbase = (size_t)b * SEQLEN + (size_t)cidx * CHUNK;
  const size_t rhrow = (size_t)(b * NHEADS + h) * SEQLEN + (size_t)cidx * CHUNK + r;
  const float rdtv = dtoT[rhrow];
  us8v bh = ((const us8v*)(Bo + (rowbase + r) * D_STATE))[hf];
  if (hf == 0) *(us8v*)&Bs[r * 24 + 16] = z8;
  if (tid < 32) Bs[256 * 24 + tid] = 0;
  {
    const int tg = cidx * CHUNK + r - 3;
    us8v xv = z8;
    if (tg >= 0)
      xv = *(const us8v*)(xT + (((size_t)(b * NHEADS + h) * SEQLEN + tg) << 4) + 8 * hf);
    *(us8v*)&xraw[r * 16 + 8 * hf] = xv;
    if (tid < 6) {
      const int rr2 = 256 + (tid >> 1);
      const int hf2 = tid & 1;
      const int tg2 = cidx * CHUNK + rr2 - 3;
      us8v xv2 = *(const us8v*)(xT + (((size_t)(b * NHEADS + h) * SEQLEN + tg2) << 4) + 8 * hf2);
      *(us8v*)&xraw[rr2 * 16 + 8 * hf2] = xv2;
    }
  }
  __syncthreads();   // #1

  us8v xsil, xdt8;
  {
    us8v tA = *(const us8v*)&xraw[(r + 0) * 16 + 8 * hf];
    us8v tB = *(const us8v*)&xraw[(r + 1) * 16 + 8 * hf];
    us8v tC = *(const us8v*)&xraw[(r + 2) * 16 + 8 * hf];
    us8v tD = *(const us8v*)&xraw[(r + 3) * 16 + 8 * hf];
    const int cbase = h * HEADDIM + 8 * hf;
#pragma unroll
    for (int ch = 0; ch < 8; ++ch) {
      const float4 wv = *(const float4*)(conv_w + (cbase + ch) * 4);
      float acc = conv_b[cbase + ch] + wv.x * bf2f(tA[ch]) + wv.y * bf2f(tB[ch])
                + wv.z * bf2f(tC[ch]) + wv.w * bf2f(tD[ch]);
      float sv = silu_f(acc);
      xsil[ch] = f2bf(sv);
      xdt8[ch] = f2bf(sv * rdtv);
    }
  }
  const float ctot  = wsum[0] + wsum[1] + wsum[2] + wsum[3];
  const float ctot2 = ctot * LOG2E;
  if (tid < CHUNK) {
    float pre = 0.f;
#pragma unroll
    for (int w = 0; w < 4; ++w) if (w < wid) pre += wsum[w];
    v += pre;
    sc2[tid] = v * LOG2E;
    acum_g[(size_t)(b * NHEADS + h) * SEQLEN + (size_t)cidx * CHUNK + tid] = v;
    if (tid == CHUNK - 1) csum_g[(b * NHEADS + h) * NCHUNKS + cidx] = v;
  }
  __syncthreads();   // #2

  *(us8v*)&xraw[(r + 3) * 16 + 8 * hf] = xsil;
#pragma unroll
  for (int q = 0; q < 8; ++q)
    xsT[(q + 8 * hf) * 264 + r] = xdt8[q];
  {
    const float wdv = exp2f(ctot2 - sc2[r]);
    const float ed  = exp2f(sc2[r | 15] - sc2[r]);   // <= 1
    us8v bscaled;
#pragma unroll
    for (int q = 0; q < 8; ++q) {
      BwT[(q + 8 * hf) * 264 + r] = f2bf(bf2f(bh[q]) * wdv);
      bscaled[q] = f2bf(bf2f(bh[q]) * ed);
    }
    *(us8v*)&Bs[r * 24 + 8 * hf] = bscaled;
  }
  if (tid < 16) scE[tid] = sc2[tid * 16 + 15];
  __syncthreads();   // #3 (last barrier)

  if (wid == 0) {
    f32x4 accS = {};
#pragma unroll
    for (int k2 = 0; k2 < 8; ++k2) {
      bf16x8 af = *(const bf16x8*)&BwT[fr * 264 + 32 * k2 + 8 * g];
      bf16x8 bb = *(const bf16x8*)&xsT[fr * 264 + 32 * k2 + 8 * g];
      accS = __builtin_amdgcn_mfma_f32_16x16x32_bf16(af, bb, accS, 0, 0, 0);
    }
    *(f32x4*)&stloc[((size_t)(b * NCHUNKS + cidx) * NHEADS + h) * 256 + fr * 16 + 4 * g] = accS;
  }

  const f32x4 zf = { 0.f, 0.f, 0.f, 0.f };
  const unsigned short* Cbase = Co + rowbase * D_STATE;
  const float Dh = Dvec[h];
  const int strips[2] = { wid, 15 - wid };

  bf16x8 brawq[2];
#pragma unroll
  for (int q = 0; q < 2; ++q) {
    us8v bv = z8;
    if (g < 2)
      bv = *(const us8v*)(Bo + (rowbase + strips[q] * 16 + fr) * D_STATE + 8 * g);
    brawq[q] = __builtin_bit_cast(bf16x8, bv);
  }

#if HAVE_MFMA16
#pragma unroll
  for (int q = 0; q < 2; ++q) {
    const int lt = strips[q];
    f32x4 acc = zf;
    bf16x8 cf = { 0, 0, 0, 0, 0, 0, 0, 0 };
    if (g < 2) cf = *(const bf16x8*)(Cbase + (size_t)(lt * 16 + fr) * D_STATE + 8 * g);
    const float acl2 = sc2[lt * 16 + fr];
    const int   lg   = lt * 16 + fr;
    for (int st = 0; st <= lt; ++st) {
      uint2 pp;
      if (st < lt) {
        bf16x8 bfg = *(const bf16x8*)&Bs[(st * 16 + fr) * 24 + 8 * g];
        f32x4 G = __builtin_amdgcn_mfma_f32_16x16x32_bf16(bfg, cf, zf, 0, 0, 0);
        const float wl = exp2f(acl2 - scE[st]);
        pp.x = pk_bf(G[0] * wl, G[1] * wl);
        pp.y = pk_bf(G[2] * wl, G[3] * wl);
      } else {
        f32x4 G = __builtin_amdgcn_mfma_f32_16x16x32_bf16(brawq[q], cf, zf, 0, 0, 0);
        f32x4 se2 = *(const f32x4*)&sc2[st * 16 + 4 * g];
        const int sbase = st * 16 + 4 * g;
        float w0 = (sbase + 0 <= lg) ? exp2f(acl2 - se2[0]) : 0.f;
        float w1 = (sbase + 1 <= lg) ? exp2f(acl2 - se2[1]) : 0.f;
        float w2 = (sbase + 2 <= lg) ? exp2f(acl2 - se2[2]) : 0.f;
        float w3 = (sbase + 3 <= lg) ? exp2f(acl2 - se2[3]) : 0.f;
        pp.x = pk_bf(G[0] * w0, G[1] * w1);
        pp.y = pk_bf(G[2] * w2, G[3] * w3);
      }
      const bf16x4 p4 = __builtin_bit_cast(bf16x4, pp);
      const bf16x4 x4 = *(const bf16x4*)&xsT[fr * 264 + st * 16 + 4 * g];
      acc = MFMA16(x4, p4, acc);
    }
    us4v xs4 = *(const us4v*)&xraw[(lt * 16 + fr + 3) * 16 + 4 * g];
    us4v o = { f2bf(acc[0] + Dh * bf2f(xs4[0])),
               f2bf(acc[1] + Dh * bf2f(xs4[1])),
               f2bf(acc[2] + Dh * bf2f(xs4[2])),
               f2bf(acc[3] + Dh * bf2f(xs4[3])) };
    *(us4v*)(YdT + (rhrow - r + (size_t)lt * 16 + fr) * HEADDIM + 4 * g) = o;
  }
#else
  const int Ls0 = fr + ((g & 1) << 5);
  const int Ls1 = Ls0 + 16;
  const bool hiq = (g >= 2);
#pragma unroll
  for (int q = 0; q < 2; ++q) {
    const int lt = strips[q];
    f32x4 acc = zf;
    bf16x8 cf = { 0, 0, 0, 0, 0, 0, 0, 0 };
    if (g < 2) cf = *(const bf16x8*)(Cbase + (size_t)(lt * 16 + fr) * D_STATE + 8 * g);
    const float acl2 = sc2[lt * 16 + fr];
    const int   lg   = lt * 16 + fr;
    const int npair = (lt + 2) >> 1;
    for (int sp = 0; sp < npair; ++sp) {
      uint2 pk[2];
#pragma unroll
      for (int ti = 0; ti < 2; ++ti) {
        const int st = 2 * sp + ti;
        if (st < lt) {
          bf16x8 bfg = *(const bf16x8*)&Bs[(st * 16 + fr) * 24 + 8 * g];
          f32x4 G = __builtin_amdgcn_mfma_f32_16x16x32_bf16(bfg, cf, zf, 0, 0, 0);
          const float wl = exp2f(acl2 - scE[st]);
          pk[ti].x = pk_bf(G[0] * wl, G[1] * wl);
          pk[ti].y = pk_bf(G[2] * wl, G[3] * wl);
        } else if (st == lt) {
          f32x4 G = __builtin_amdgcn_mfma_f32_16x16x32_bf16(brawq[q], cf, zf, 0, 0, 0);
          f32x4 se2 = *(const f32x4*)&sc2[st * 16 + 4 * g];
          const int sbase = st * 16 + 4 * g;
          float w0 = (sbase + 0 <= lg) ? exp2f(acl2 - se2[0]) : 0.f;
          float w1 = (sbase + 1 <= lg) ? exp2f(acl2 - se2[1]) : 0.f;
          float w2 = (sbase + 2 <= lg) ? exp2f(acl2 - se2[2]) : 0.f;
          float w3 = (sbase + 3 <= lg) ? exp2f(acl2 - se2[3]) : 0.f;
          pk[ti].x = pk_bf(G[0] * w0, G[1] * w1);
          pk[ti].y = pk_bf(G[2] * w2, G[3] * w3);
        } else {
          pk[ti].x = 0u; pk[ti].y = 0u;
        }
      }
      const int a00 = __shfl((int)pk[0].x, Ls0, 64);
      const int a10 = __shfl((int)pk[0].y, Ls0, 64);
      const int a01 = __shfl((int)pk[0].x, Ls1, 64);
      const int a11 = __shfl((int)pk[0].y, Ls1, 64);
      const int b00 = __shfl((int)pk[1].x, Ls0, 64);
      const int b10 = __shfl((int)pk[1].y, Ls0, 64);
      const int b01 = __shfl((int)pk[1].x, Ls1, 64);
      const int b11 = __shfl((int)pk[1].y, Ls1, 64);
      u32x4 pw;
      pw[0] = (unsigned)(hiq ? b00 : a00);
      pw[1] = (unsigned)(hiq ? b10 : a10);
      pw[2] = (unsigned)(hiq ? b01 : a01);
      pw[3] = (unsigned)(hiq ? b11 : a11);
      const bf16x8 pf = __builtin_bit_cast(bf16x8, pw);
      const bf16x8 xf = *(const bf16x8*)&xsT[fr * 264 + sp * 32 + 8 * g];
      acc = __builtin_amdgcn_mfma_f32_16x16x32_bf16(xf, pf, acc, 0, 0, 0);
    }
    us4v xs4 = *(const us4v*)&xraw[(lt * 16 + fr + 3) * 16 + 4 * g];
    us4v o = { f2bf(acc[0] + Dh * bf2f(xs4[0])),
               f2bf(acc[1] + Dh * bf2f(xs4[1])),
               f2bf(acc[2] + Dh * bf2f(xs4[2])),
               f2bf(acc[3] + Dh * bf2f(xs4[3])) };
    *(us4v*)(YdT + (rhrow - r + (size_t)lt * 16 + fr) * HEADDIM + 4 * g) = o;
  }
#endif
}

// ---------------------------------------------------------------------------
// K4: sequential inter-chunk state recurrence
// ---------------------------------------------------------------------------
__global__ __launch_bounds__(256)
void chunk_scan_kernel(const float* __restrict__ stloc, const float* __restrict__ csum_g,
                       float* __restrict__ stpre) {
  const int b  = blockIdx.x / NHEADS;
  const int h  = blockIdx.x % NHEADS;
  const int pn = threadIdx.x;
  float S = 0.0f;
  for (int c = 0; c < NCHUNKS; ++c) {
    const size_t idx = ((size_t)(b * NCHUNKS + c) * NHEADS + h) * 256 + pn;
    stpre[idx] = S;
    S = __expf(csum_g[(b * NHEADS + h) * NCHUNKS + c]) * S + stloc[idx];
  }
}

// ---------------------------------------------------------------------------
// K5 (fused, 12 waves): Y_off, silu(z) gate, RMSNorm, out = yn @ W_out'^T.
// r30: shuffle-free RMSNorm — row norms computed as the DIAGONAL of the
// Gram matrix ynL.ynL^T on the (idle) matrix pipe, sharing the GEMM's af
// fragments. Loop1 = {dot, gate, ynL write}; no shfl chains, no red[].
// norm_w pre-folded into Wo (cvt3), so ynL holds raw bf16(yg).
// ---------------------------------------------------------------------------
#define TT 16
#define LDY 392
__global__ __launch_bounds__(768)
void yoff_norm_gemm(const unsigned short* __restrict__ YdT,
                    const unsigned short* __restrict__ Co, const float* __restrict__ acum_g,
                    const float* __restrict__ stpre,
                    const unsigned short* __restrict__ zbuf,
                    const unsigned short* __restrict__ Wo,
                    float* __restrict__ out) {
  const int bid  = blockIdx.x;
  const int wz   = (bid & 7) * 128 + (bid >> 3);   // bijective: 1024 % 8 == 0
  const int r0   = wz * TT;
  const int b    = r0 / SEQLEN;
  const int t0   = r0 % SEQLEN;
  const int cidx = t0 / CHUNK;
  const int tid  = threadIdx.x;
  const int d    = tid % 384;
  const int half = tid / 384;
  const int h    = d >> 4, p = d & 15;
  const int wv   = tid >> 6;

  __shared__ unsigned short Yt[NHEADS * TT * 16];
  __shared__ unsigned short zL[TT * 384];
  __shared__ unsigned short ynL[TT * LDY];
  __shared__ float At[NHEADS * TT];
  __shared__ float Ct[TT * 16];

  {
    us8v* Yt8 = (us8v*)Yt;
    int hh = tid >> 5, q = tid & 31;
    const size_t src = ((size_t)(b * NHEADS + hh) * SEQLEN + t0) * HEADDIM + q * 8;
    Yt8[tid] = *(const us8v*)(YdT + src);
    const int zr = tid / 48, zc = (tid % 48) * 8;
    *(us8v*)&zL[zr * 384 + zc] = *(const us8v*)(zbuf + (size_t)(r0 + zr) * 384 + zc);
    if (tid < NHEADS * TT)
      At[tid] = __expf(acum_g[(size_t)(b * NHEADS + (tid >> 4)) * SEQLEN + t0 + (tid & 15)]);
    if (tid < TT * 16) Ct[tid] = bf2f(Co[(size_t)r0 * D_STATE + tid]);
  }

  f32x4 S4[4];
  {
    const float* Sp = stpre + ((size_t)(b * NCHUNKS + cidx) * NHEADS + h) * 256 + p * 16;
#pragma unroll
    for (int q = 0; q < 4; ++q) S4[q] = *(const f32x4*)(Sp + 4 * q);
  }
  __syncthreads();   // #1

  const int tb = half * 8;
#pragma unroll
  for (int ti = 0; ti < 8; ++ti) {
    const int tt = tb + ti;
    const f32x4* C4 = (const f32x4*)&Ct[tt * 16];
    f32x4 d4 = C4[0] * S4[0];
    d4 = d4 + C4[1] * S4[1];
    d4 = d4 + C4[2] * S4[2];
    d4 = d4 + C4[3] * S4[3];
    const float dot = (d4[0] + d4[1]) + (d4[2] + d4[3]);
    const float eA = At[h * TT + tt];
    float y = bf2f(Yt[h * 256 + tt * 16 + p]) + eA * dot;
    const float z = bf2f(zL[tt * 384 + d]);
    ynL[tt * LDY + d] = f2bf(y * silu_f(z));
  }
  __syncthreads();   // #2 (last barrier)

  const int lane = tid & 63;
  const int fr = lane & 15, fq = lane >> 4;
  const int n0 = wv * 16;
  f32x4 accg = {};
  f32x4 gacc = {};
  __builtin_amdgcn_s_setprio(1);
#pragma unroll
  for (int kt = 0; kt < 12; ++kt) {
    const bf16x8 af = *(const bf16x8*)&ynL[fr * LDY + kt * 32 + 8 * fq];
    const bf16x8 bfr = *(const bf16x8*)(Wo + (size_t)(n0 + fr) * D_INNER + kt * 32 + 8 * fq);
    accg = __builtin_amdgcn_mfma_f32_16x16x32_bf16(bfr, af, accg, 0, 0, 0);
    gacc = __builtin_amdgcn_mfma_f32_16x16x32_bf16(af, af, gacc, 0, 0, 0);
  }
  __builtin_amdgcn_s_setprio(0);
  // diag extraction: Gram[fr][fr] lives in lane (fr>>2)*16 + fr, reg fr&3.
  const int j0 = fr & 3;
  float vsel = (j0 == 0) ? gacc[0] : (j0 == 1) ? gacc[1]
             : (j0 == 2) ? gacc[2] : gacc[3];
  const float tot = __shfl(vsel, (fr >> 2) * 16 + fr, 64);
  const float scale = rsqrtf(tot * (1.0f / D_INNER) + EPS);
  float4 o = make_float4(accg[0] * scale, accg[1] * scale,
                         accg[2] * scale, accg[3] * scale);
  *(float4*)(out + (size_t)(r0 + fr) * D_MODEL + n0 + fq * 4) = o;
}

// ---------------------------------------------------------------------------
extern "C" void kernel_launch(void* const* d_in, const int* in_sizes, int n_in,
                              void* d_out, int out_size, void* d_ws, size_t ws_size,
                              hipStream_t stream) {
  const float* u        = (const float*)d_in[0];
  const float* support  = (const float*)d_in[1];
  const float* W_in     = (const float*)d_in[2];
  const float* W_in_b   = (const float*)d_in[3];
  const float* conv_w   = (const float*)d_in[4];
  const float* conv_b   = (const float*)d_in[5];
  const float* conv_w_b = (const float*)d_in[6];
  const float* conv_b_b = (const float*)d_in[7];
  const float* dt_bias  = (const float*)d_in[8];
  const float* A_log    = (const float*)d_in[9];
  const float* Dvec     = (const float*)d_in[10];
  const float* norm_w   = (const float*)d_in[11];
  const float* W_out    = (const float*)d_in[12];
  float* out = (float*)d_out;
  char* wsb  = (char*)d_ws;

  unsigned short* Wi_b  = (unsigned short*)(wsb);
  unsigned short* Wo_b  = Wi_b + (size_t)D_IN_PROJ * D_MODEL;
  unsigned short* Wib_b = Wo_b + (size_t)D_MODEL * D_INNER;
  unsigned short* zbuf  = Wib_b + (size_t)D_STATE * D_MODEL;
  unsigned short* xT    = zbuf + (size_t)ROWS * D_INNER;
  unsigned short* Braw  = xT + (size_t)ROWS * D_INNER;
  unsigned short* draw  = Braw + (size_t)ROWS * D_STATE;
  unsigned short* craw  = draw + (size_t)ROWS * NHEADS;
  unsigned short* Bo    = craw + (size_t)ROWS * D_STATE;
  unsigned short* Co    = Bo + (size_t)ROWS * D_STATE;
  unsigned short* YdT   = Co + (size_t)ROWS * D_STATE;
  float* dtoT  = (float*)(YdT + (size_t)ROWS * D_INNER);
  float* acum  = dtoT  + (size_t)ROWS * NHEADS;
  float* csum  = acum  + (size_t)BATCH * NHEADS * SEQLEN;
  float* stloc = csum  + (size_t)BATCH * NHEADS * NCHUNKS;
  float* stpre = stloc + (size_t)BATCH * NCHUNKS * NHEADS * 256;

  cvt3_kernel<<<224, 256, 0, stream>>>(W_in, Wi_b, (long)D_IN_PROJ * D_MODEL,
                                       W_out, Wo_b, (long)D_MODEL * D_INNER,
                                       W_in_b, Wib_b, (long)D_STATE * D_MODEL,
                                       norm_w);
  gemm_in_merged<<<dim3(8, ROWS / 128), 256, 0, stream>>>(
      u, Wi_b, support, Wib_b, craw, zbuf, xT, Braw, draw);
  conv_bcdt<<<CBC_NB + CDT_NB, 256, 0, stream>>>(
      Braw, craw, draw, conv_w, conv_b, conv_w_b, conv_b_b, dt_bias, Bo, Co, dtoT);
  ssd_mfma_kernel<<<NHEADS * NCHUNKS * BATCH, 512, 0, stream>>>(
      xT, Bo, Co, dtoT, A_log, conv_w, conv_b, Dvec, YdT, acum, csum, stloc);
  chunk_scan_kernel<<<BATCH * NHEADS, 256, 0, stream>>>(stloc, csum, stpre);
  yoff_norm_gemm<<<ROWS / TT, 768, 0, stream>>>(YdT, Co, acum, stpre, zbuf,
                                                Wo_b, out);
}

// Round 31
// 106.323 us; speedup vs baseline: 1.2907x; 1.0022x over previous
//
#include <hip/hip_runtime.h>
#include <cmath>

#define ROWS      16384
#define SEQLEN    8192
#define BATCH     2
#define NHEADS    24
#define HEADDIM   16
#define D_STATE   16
#define D_INNER   384
#define D_MODEL   192
#define D_IN_PROJ 808
#define CONV_DIM  400
#define NCHUNKS   32
#define CHUNK     256
#define EPS       1e-5f
#define LOG2E     1.44269504088896f

typedef short bf16x8 __attribute__((ext_vector_type(8)));
typedef short bf16x4 __attribute__((ext_vector_type(4)));
typedef float f32x4  __attribute__((ext_vector_type(4)));
typedef unsigned short us4v __attribute__((ext_vector_type(4)));
typedef unsigned short us8v __attribute__((ext_vector_type(8)));
typedef unsigned int  u32x4 __attribute__((ext_vector_type(4)));

#if __has_builtin(__builtin_amdgcn_mfma_f32_16x16x16bf16_1k)
#define MFMA16(a, b, c) __builtin_amdgcn_mfma_f32_16x16x16bf16_1k((a), (b), (c), 0, 0, 0)
#define HAVE_MFMA16 1
#elif __has_builtin(__builtin_amdgcn_mfma_f32_16x16x16_bf16)
#define MFMA16(a, b, c) __builtin_amdgcn_mfma_f32_16x16x16_bf16((a), (b), (c), 0, 0, 0)
#define HAVE_MFMA16 1
#else
#define HAVE_MFMA16 0
#endif

__device__ __forceinline__ float silu_f(float x) { return x / (1.0f + expf(-x)); }
__device__ __forceinline__ float softplus_f(float x) { return (x > 20.0f) ? x : log1pf(expf(x)); }
__device__ __forceinline__ unsigned short f2bf(float x) {
  unsigned u = __builtin_bit_cast(unsigned, x);
  u += 0x7fff + ((u >> 16) & 1);
  return (unsigned short)(u >> 16);
}
__device__ __forceinline__ float bf2f(unsigned short s) {
  unsigned u = (unsigned)s << 16;
  return __builtin_bit_cast(float, u);
}
__device__ __forceinline__ unsigned pk_bf(float a, float b) {
  unsigned ua = __builtin_bit_cast(unsigned, a) + 0x7fffu;
  unsigned ub = __builtin_bit_cast(unsigned, b) + 0x7fffu;
  return __builtin_amdgcn_perm(ub, ua, 0x07060302u);
}
// single-instruction pack of 2 f32 -> 2 bf16 (RTNE); low = a, high = b.
__device__ __forceinline__ unsigned cvt_pk(float a, float b) {
  unsigned r;
  asm("v_cvt_pk_bf16_f32 %0, %1, %2" : "=v"(r) : "v"(a), "v"(b));
  return r;
}

// ---------------------------------------------------------------------------
// K0: fp32 -> bf16 weights (W_in, W_out * norm_w, W_in_b).
// ---------------------------------------------------------------------------
__global__ __launch_bounds__(256)
void cvt3_kernel(const float* __restrict__ a, unsigned short* __restrict__ ao, long na,
                 const float* __restrict__ b, unsigned short* __restrict__ bo, long nb,
                 const float* __restrict__ c, unsigned short* __restrict__ co, long nc,
                 const float* __restrict__ nwp) {
  const long t0 = na >> 2, t1 = t0 + (nb >> 2), t2 = t1 + (nc >> 2);
  const long stride = (long)gridDim.x * blockDim.x;
  for (long i = (long)blockIdx.x * blockDim.x + threadIdx.x; i < t2; i += stride) {
    if (i < t0) {
      float4 v = ((const float4*)a)[i];
      us4v o = { f2bf(v.x), f2bf(v.y), f2bf(v.z), f2bf(v.w) };
      ((us4v*)ao)[i] = o;
    } else if (i < t1) {
      const long j = i - t0;
      float4 v = ((const float4*)b)[j];
      const int d0 = (int)((j * 4) % D_INNER);
      const float4 nw4 = *(const float4*)(nwp + d0);
      us4v o = { f2bf(v.x * nw4.x), f2bf(v.y * nw4.y),
                 f2bf(v.z * nw4.z), f2bf(v.w * nw4.w) };
      ((us4v*)bo)[j] = o;
    } else {
      const long j = i - t1;
      float4 v = ((const float4*)c)[j];
      us4v o = { f2bf(v.x), f2bf(v.y), f2bf(v.z), f2bf(v.w) };
      ((us4v*)co)[j] = o;
    }
  }
}

// ---------------------------------------------------------------------------
// GEMM body (device fn; LDS passed in).
// ---------------------------------------------------------------------------
template<bool OUT_BF16, bool ROUTE>
__device__ __forceinline__
void gemm_body(unsigned short* __restrict__ As, unsigned short* __restrict__ Ws,
               const float* __restrict__ A, const unsigned short* __restrict__ W,
               void* __restrict__ Cp, int M, int N, int K, int bx, int by,
               unsigned short* __restrict__ zbuf, unsigned short* __restrict__ xT,
               unsigned short* __restrict__ Braw, unsigned short* __restrict__ draw) {
  constexpr int BM = 128, BN = 128, BK = 32, LDK = 40;
  const int tid  = threadIdx.x;
  const int wid  = tid >> 6, lane = tid & 63;
  const int wr   = wid >> 1, wc = wid & 1;
  const int fr   = lane & 15, fq = lane >> 4;
  const long m0  = (long)by * BM;
  const int  n0  = bx * BN;

  f32x4 acc[4][4] = {};

  auto stage = [&](int k0, int buf) {
#pragma unroll
    for (int p = 0; p < 2; ++p) {
      int flat = p * 2048 + tid * 8;
      int r = flat >> 5, c = flat & 31;
      const float4* src = (const float4*)(A + (m0 + r) * (long)K + k0 + c);
      float4 v0 = src[0], v1 = src[1];
      us8v o = { f2bf(v0.x), f2bf(v0.y), f2bf(v0.z), f2bf(v0.w),
                 f2bf(v1.x), f2bf(v1.y), f2bf(v1.z), f2bf(v1.w) };
      *(us8v*)&As[buf * BM * LDK + r * LDK + c] = o;
    }
#pragma unroll
    for (int p = 0; p < 2; ++p) {
      int flat = p * 2048 + tid * 8;
      int r = flat >> 5, c = flat & 31;
      int gn = n0 + r;
      us8v v = { 0, 0, 0, 0, 0, 0, 0, 0 };
      if (gn < N) v = *(const us8v*)(W + (long)gn * K + k0 + c);
      *(us8v*)&Ws[buf * BN * LDK + r * LDK + c] = v;
    }
  };

  const int nk = K / BK;
  stage(0, 0);
  __syncthreads();
  for (int kt = 0; kt < nk; ++kt) {
    const int cur = kt & 1;
    if (kt + 1 < nk) stage((kt + 1) * BK, cur ^ 1);
    bf16x8 af[4], bfr[4];
#pragma unroll
    for (int m = 0; m < 4; ++m)
      af[m] = *(const bf16x8*)&As[cur * BM * LDK + (wr * 64 + m * 16 + fr) * LDK + fq * 8];
#pragma unroll
    for (int n = 0; n < 4; ++n)
      bfr[n] = *(const bf16x8*)&Ws[cur * BN * LDK + (wc * 64 + n * 16 + fr) * LDK + fq * 8];
#pragma unroll
    for (int m = 0; m < 4; ++m)
#pragma unroll
      for (int n = 0; n < 4; ++n)
        acc[m][n] = __builtin_amdgcn_mfma_f32_16x16x32_bf16(bfr[n], af[m], acc[m][n], 0, 0, 0);
    __syncthreads();
  }

#pragma unroll
  for (int m = 0; m < 4; ++m) {
    const long gm = m0 + wr * 64 + m * 16 + fr;
#pragma unroll
    for (int n = 0; n < 4; ++n) {
      const int gn = n0 + wc * 64 + n * 16 + fq * 4;
      if (gn < N) {
        if (ROUTE) {
          us4v o = { f2bf(acc[m][n][0]), f2bf(acc[m][n][1]),
                     f2bf(acc[m][n][2]), f2bf(acc[m][n][3]) };
          const int bb = (int)(gm >> 13);
          const long t = gm & 8191;
          if (gn < 384) {
            *(us4v*)(zbuf + gm * 384 + gn) = o;
          } else if (gn < 768) {
            const int c = gn - 384, hh = c >> 4, ii = c & 15;
            *(us4v*)(xT + (((size_t)(bb * NHEADS + hh) * SEQLEN + t) << 4) + ii) = o;
          } else if (gn < 784) {
            *(us4v*)(Braw + gm * 16 + (gn - 768)) = o;
          } else {
            *(us4v*)(draw + gm * 24 + (gn - 784)) = o;
          }
        } else if (OUT_BF16) {
          us4v o = { f2bf(acc[m][n][0]), f2bf(acc[m][n][1]),
                     f2bf(acc[m][n][2]), f2bf(acc[m][n][3]) };
          *(us4v*)((unsigned short*)Cp + gm * N + gn) = o;
        } else {
          float4 o = make_float4(acc[m][n][0], acc[m][n][1], acc[m][n][2], acc[m][n][3]);
          *(float4*)((float*)Cp + gm * N + gn) = o;
        }
      }
    }
  }
}

// ---------------------------------------------------------------------------
// K1 (merged): bx<7 -> routed in-proj (u @ W_in^T); bx==7 -> support @ W_in_b^T
// ---------------------------------------------------------------------------
__global__ __launch_bounds__(256, 3)
void gemm_in_merged(const float* __restrict__ u, const unsigned short* __restrict__ Wi,
                    const float* __restrict__ support, const unsigned short* __restrict__ Wib,
                    unsigned short* __restrict__ craw,
                    unsigned short* __restrict__ zbuf, unsigned short* __restrict__ xT,
                    unsigned short* __restrict__ Braw, unsigned short* __restrict__ draw) {
  __shared__ unsigned short As[2 * 128 * 40];
  __shared__ unsigned short Ws[2 * 128 * 40];
  if (blockIdx.x < 7)
    gemm_body<true, true>(As, Ws, u, Wi, nullptr, ROWS, D_IN_PROJ, D_MODEL,
                          blockIdx.x, blockIdx.y, zbuf, xT, Braw, draw);
  else
    gemm_body<true, false>(As, Ws, support, Wib, craw, ROWS, D_STATE, D_MODEL,
                           0, blockIdx.y, nullptr, nullptr, nullptr, nullptr);
}

// ---------------------------------------------------------------------------
// K2: B/C conv + dt softplus, dense raw buffers. 448 role-pure blocks.
// ---------------------------------------------------------------------------
#define CBC_NB  (ROWS * 4 / 256)    // 256
#define CDT_NB  (ROWS * 3 / 256)    // 192

__global__ __launch_bounds__(256)
void conv_bcdt(const unsigned short* __restrict__ Braw, const unsigned short* __restrict__ craw,
               const unsigned short* __restrict__ draw,
               const float* __restrict__ conv_w, const float* __restrict__ conv_b,
               const float* __restrict__ conv_w_b, const float* __restrict__ conv_b_b,
               const float* __restrict__ dt_bias,
               unsigned short* __restrict__ Bo, unsigned short* __restrict__ Co,
               float* __restrict__ dtoT) {
  const int blk = blockIdx.x;
  const us8v z8 = { 0, 0, 0, 0, 0, 0, 0, 0 };

  if (blk < CBC_NB) {
    const int idx = blk * 256 + threadIdx.x;
    const int row = idx / 4, q = idx % 4;
    const int b = row / SEQLEN, t = row % SEQLEN;

    const unsigned short* src = (q < 2) ? Braw : craw;
    const float* cw = (q < 2) ? conv_w + 384 * 4 : conv_w_b;
    const float* cb = (q < 2) ? conv_b + 384 : conv_b_b;
    const int c0 = (q & 1) * 8;
    const unsigned short* base = src + (size_t)row * D_STATE + c0;
    us8v x0 = (t >= 3) ? *(const us8v*)(base - 3 * D_STATE) : z8;
    us8v x1 = (t >= 2) ? *(const us8v*)(base - 2 * D_STATE) : z8;
    us8v x2 = (t >= 1) ? *(const us8v*)(base - 1 * D_STATE) : z8;
    us8v x3 = *(const us8v*)base;
    us8v o;
#pragma unroll
    for (int ch = 0; ch < 8; ++ch) {
      const float4 wv = *(const float4*)(cw + (c0 + ch) * 4);
      float acc = cb[c0 + ch] + wv.x * bf2f(x0[ch]) + wv.y * bf2f(x1[ch])
                + wv.z * bf2f(x2[ch]) + wv.w * bf2f(x3[ch]);
      o[ch] = f2bf(silu_f(acc));
    }
    if (q < 2) *(us8v*)(Bo + (size_t)row * D_STATE + c0) = o;
    else       *(us8v*)(Co + (size_t)row * D_STATE + c0) = o;
  } else {
    const int idx = (blk - CBC_NB) * 256 + threadIdx.x;
    const int row = idx / 3, q = idx % 3;
    const int b = row / SEQLEN, t = row % SEQLEN;
    const int h0 = q * 8;
    us8v dv = *(const us8v*)(draw + (size_t)row * 24 + h0);
#pragma unroll
    for (int j = 0; j < 8; ++j) {
      float v = bf2f(dv[j]) + dt_bias[h0 + j];
      dtoT[(size_t)(b * NHEADS + h0 + j) * SEQLEN + t] = softplus_f(v);
    }
  }
}

// ---------------------------------------------------------------------------
// K3 (MFMA, 8 waves, fused x-conv, factored decay, K16 PV):
// r31: PV loop — Bs b128 read predicated to g<2 (g>=2 multiplies cf=0, so
// the value is irrelevant; masking halves the 8-way bank conflict), and
// pk_bf (3 VALU) replaced by single v_cvt_pk_bf16_f32.
// ---------------------------------------------------------------------------
__global__ __launch_bounds__(512, 4)
void ssd_mfma_kernel(const unsigned short* __restrict__ xT, const unsigned short* __restrict__ Bo,
                     const unsigned short* __restrict__ Co, const float* __restrict__ dtoT,
                     const float* __restrict__ A_log, const float* __restrict__ conv_w,
                     const float* __restrict__ conv_b, const float* __restrict__ Dvec,
                     unsigned short* __restrict__ YdT, float* __restrict__ acum_g,
                     float* __restrict__ csum_g, float* __restrict__ stloc) {
  const int bid  = blockIdx.x;
  const int wrk  = (bid & 7) * 192 + (bid >> 3);
  const int b    = wrk / 768;
  const int rem  = wrk % 768;
  const int cidx = rem / NHEADS;
  const int h    = rem % NHEADS;
  const int tid  = threadIdx.x;
  const int wid  = tid >> 6, lane = tid & 63;
  const int fr   = lane & 15, g = lane >> 4;

  __shared__ unsigned short Bs[256 * 24 + 32];
  __shared__ unsigned short xsT[16 * 264];
  __shared__ unsigned short BwT[16 * 264];
  __shared__ unsigned short xraw[259 * 16 + 8];
  __shared__ float sc2[CHUNK];
  __shared__ float scE[16];
  __shared__ float wsum[4];

  const float Ah = -expf(A_log[h]);
  const us8v z8 = { 0, 0, 0, 0, 0, 0, 0, 0 };

  float v = 0.f;
  if (tid < CHUNK) {
    v = dtoT[(size_t)(b * NHEADS + h) * SEQLEN + (size_t)cidx * CHUNK + tid] * Ah;
#pragma unroll
    for (int off = 1; off < 64; off <<= 1) {
      float u = __shfl_up(v, off, 64);
      if (lane >= off) v += u;
    }
    if (lane == 63) wsum[wid] = v;
  }

  const int r  = tid >> 1;
  const int hf = tid & 1;
  const size_t rowbase = (size_t)b * SEQLEN + (size_t)cidx * CHUNK;
  const size_t rhrow = (size_t)(b * NHEADS + h) * SEQLEN + (size_t)cidx * CHUNK + r;
  const float rdtv = dtoT[rhrow];
  us8v bh = ((const us8v*)(Bo + (rowbase + r) * D_STATE))[hf];
  if (hf == 0) *(us8v*)&Bs[r * 24 + 16] = z8;
  if (tid < 32) Bs[256 * 24 + tid] = 0;
  {
    const int tg = cidx * CHUNK + r - 3;
    us8v xv = z8;
    if (tg >= 0)
      xv = *(const us8v*)(xT + (((size_t)(b * NHEADS + h) * SEQLEN + tg) << 4) + 8 * hf);
    *(us8v*)&xraw[r * 16 + 8 * hf] = xv;
    if (tid < 6) {
      const int rr2 = 256 + (tid >> 1);
      const int hf2 = tid & 1;
      const int tg2 = cidx * CHUNK + rr2 - 3;
      us8v xv2 = *(const us8v*)(xT + (((size_t)(b * NHEADS + h) * SEQLEN + tg2) << 4) + 8 * hf2);
      *(us8v*)&xraw[rr2 * 16 + 8 * hf2] = xv2;
    }
  }
  __syncthreads();   // #1

  us8v xsil, xdt8;
  {
    us8v tA = *(const us8v*)&xraw[(r + 0) * 16 + 8 * hf];
    us8v tB = *(const us8v*)&xraw[(r + 1) * 16 + 8 * hf];
    us8v tC = *(const us8v*)&xraw[(r + 2) * 16 + 8 * hf];
    us8v tD = *(const us8v*)&xraw[(r + 3) * 16 + 8 * hf];
    const int cbase = h * HEADDIM + 8 * hf;
#pragma unroll
    for (int ch = 0; ch < 8; ++ch) {
      const float4 wv = *(const float4*)(conv_w + (cbase + ch) * 4);
      float acc = conv_b[cbase + ch] + wv.x * bf2f(tA[ch]) + wv.y * bf2f(tB[ch])
                + wv.z * bf2f(tC[ch]) + wv.w * bf2f(tD[ch]);
      float sv = silu_f(acc);
      xsil[ch] = f2bf(sv);
      xdt8[ch] = f2bf(sv * rdtv);
    }
  }
  const float ctot  = wsum[0] + wsum[1] + wsum[2] + wsum[3];
  const float ctot2 = ctot * LOG2E;
  if (tid < CHUNK) {
    float pre = 0.f;
#pragma unroll
    for (int w = 0; w < 4; ++w) if (w < wid) pre += wsum[w];
    v += pre;
    sc2[tid] = v * LOG2E;
    acum_g[(size_t)(b * NHEADS + h) * SEQLEN + (size_t)cidx * CHUNK + tid] = v;
    if (tid == CHUNK - 1) csum_g[(b * NHEADS + h) * NCHUNKS + cidx] = v;
  }
  __syncthreads();   // #2

  *(us8v*)&xraw[(r + 3) * 16 + 8 * hf] = xsil;
#pragma unroll
  for (int q = 0; q < 8; ++q)
    xsT[(q + 8 * hf) * 264 + r] = xdt8[q];
  {
    const float wdv = exp2f(ctot2 - sc2[r]);
    const float ed  = exp2f(sc2[r | 15] - sc2[r]);   // <= 1
    us8v bscaled;
#pragma unroll
    for (int q = 0; q < 8; ++q) {
      BwT[(q + 8 * hf) * 264 + r] = f2bf(bf2f(bh[q]) * wdv);
      bscaled[q] = f2bf(bf2f(bh[q]) * ed);
    }
    *(us8v*)&Bs[r * 24 + 8 * hf] = bscaled;
  }
  if (tid < 16) scE[tid] = sc2[tid * 16 + 15];
  __syncthreads();   // #3 (last barrier)

  if (wid == 0) {
    f32x4 accS = {};
#pragma unroll
    for (int k2 = 0; k2 < 8; ++k2) {
      bf16x8 af = *(const bf16x8*)&BwT[fr * 264 + 32 * k2 + 8 * g];
      bf16x8 bb = *(const bf16x8*)&xsT[fr * 264 + 32 * k2 + 8 * g];
      accS = __builtin_amdgcn_mfma_f32_16x16x32_bf16(af, bb, accS, 0, 0, 0);
    }
    *(f32x4*)&stloc[((size_t)(b * NCHUNKS + cidx) * NHEADS + h) * 256 + fr * 16 + 4 * g] = accS;
  }

  const f32x4 zf = { 0.f, 0.f, 0.f, 0.f };
  const unsigned short* Cbase = Co + rowbase * D_STATE;
  const float Dh = Dvec[h];
  const int strips[2] = { wid, 15 - wid };
  const bool gl = (g < 2);

  bf16x8 brawq[2];
#pragma unroll
  for (int q = 0; q < 2; ++q) {
    us8v bv = z8;
    if (gl)
      bv = *(const us8v*)(Bo + (rowbase + strips[q] * 16 + fr) * D_STATE + 8 * g);
    brawq[q] = __builtin_bit_cast(bf16x8, bv);
  }

#if HAVE_MFMA16
#pragma unroll
  for (int q = 0; q < 2; ++q) {
    const int lt = strips[q];
    f32x4 acc = zf;
    bf16x8 cf = { 0, 0, 0, 0, 0, 0, 0, 0 };
    bf16x8 bfg = { 0, 0, 0, 0, 0, 0, 0, 0 };
    if (gl) cf = *(const bf16x8*)(Cbase + (size_t)(lt * 16 + fr) * D_STATE + 8 * g);
    const float acl2 = sc2[lt * 16 + fr];
    const int   lg   = lt * 16 + fr;
    for (int st = 0; st <= lt; ++st) {
      uint2 pp;
      if (st < lt) {
        if (gl) bfg = *(const bf16x8*)&Bs[(st * 16 + fr) * 24 + 8 * g];
        f32x4 G = __builtin_amdgcn_mfma_f32_16x16x32_bf16(bfg, cf, zf, 0, 0, 0);
        const float wl = exp2f(acl2 - scE[st]);
        pp.x = cvt_pk(G[0] * wl, G[1] * wl);
        pp.y = cvt_pk(G[2] * wl, G[3] * wl);
      } else {
        f32x4 G = __builtin_amdgcn_mfma_f32_16x16x32_bf16(brawq[q], cf, zf, 0, 0, 0);
        f32x4 se2 = *(const f32x4*)&sc2[st * 16 + 4 * g];
        const int sbase = st * 16 + 4 * g;
        float w0 = (sbase + 0 <= lg) ? exp2f(acl2 - se2[0]) : 0.f;
        float w1 = (sbase + 1 <= lg) ? exp2f(acl2 - se2[1]) : 0.f;
        float w2 = (sbase + 2 <= lg) ? exp2f(acl2 - se2[2]) : 0.f;
        float w3 = (sbase + 3 <= lg) ? exp2f(acl2 - se2[3]) : 0.f;
        pp.x = cvt_pk(G[0] * w0, G[1] * w1);
        pp.y = cvt_pk(G[2] * w2, G[3] * w3);
      }
      const bf16x4 p4 = __builtin_bit_cast(bf16x4, pp);
      const bf16x4 x4 = *(const bf16x4*)&xsT[fr * 264 + st * 16 + 4 * g];
      acc = MFMA16(x4, p4, acc);
    }
    us4v xs4 = *(const us4v*)&xraw[(lt * 16 + fr + 3) * 16 + 4 * g];
    us4v o = { f2bf(acc[0] + Dh * bf2f(xs4[0])),
               f2bf(acc[1] + Dh * bf2f(xs4[1])),
               f2bf(acc[2] + Dh * bf2f(xs4[2])),
               f2bf(acc[3] + Dh * bf2f(xs4[3])) };
    *(us4v*)(YdT + (rhrow - r + (size_t)lt * 16 + fr) * HEADDIM + 4 * g) = o;
  }
#else
  const int Ls0 = fr + ((g & 1) << 5);
  const int Ls1 = Ls0 + 16;
  const bool hiq = (g >= 2);
#pragma unroll
  for (int q = 0; q < 2; ++q) {
    const int lt = strips[q];
    f32x4 acc = zf;
    bf16x8 cf = { 0, 0, 0, 0, 0, 0, 0, 0 };
    bf16x8 bfg = { 0, 0, 0, 0, 0, 0, 0, 0 };
    if (gl) cf = *(const bf16x8*)(Cbase + (size_t)(lt * 16 + fr) * D_STATE + 8 * g);
    const float acl2 = sc2[lt * 16 + fr];
    const int   lg   = lt * 16 + fr;
    const int npair = (lt + 2) >> 1;
    for (int sp = 0; sp < npair; ++sp) {
      uint2 pk[2];
#pragma unroll
      for (int ti = 0; ti < 2; ++ti) {
        const int st = 2 * sp + ti;
        if (st < lt) {
          if (gl) bfg = *(const bf16x8*)&Bs[(st * 16 + fr) * 24 + 8 * g];
          f32x4 G = __builtin_amdgcn_mfma_f32_16x16x32_bf16(bfg, cf, zf, 0, 0, 0);
          const float wl = exp2f(acl2 - scE[st]);
          pk[ti].x = pk_bf(G[0] * wl, G[1] * wl);
          pk[ti].y = pk_bf(G[2] * wl, G[3] * wl);
        } else if (st == lt) {
          f32x4 G = __builtin_amdgcn_mfma_f32_16x16x32_bf16(brawq[q], cf, zf, 0, 0, 0);
          f32x4 se2 = *(const f32x4*)&sc2[st * 16 + 4 * g];
          const int sbase = st * 16 + 4 * g;
          float w0 = (sbase + 0 <= lg) ? exp2f(acl2 - se2[0]) : 0.f;
          float w1 = (sbase + 1 <= lg) ? exp2f(acl2 - se2[1]) : 0.f;
          float w2 = (sbase + 2 <= lg) ? exp2f(acl2 - se2[2]) : 0.f;
          float w3 = (sbase + 3 <= lg) ? exp2f(acl2 - se2[3]) : 0.f;
          pk[ti].x = pk_bf(G[0] * w0, G[1] * w1);
          pk[ti].y = pk_bf(G[2] * w2, G[3] * w3);
        } else {
          pk[ti].x = 0u; pk[ti].y = 0u;
        }
      }
      const int a00 = __shfl((int)pk[0].x, Ls0, 64);
      const int a10 = __shfl((int)pk[0].y, Ls0, 64);
      const int a01 = __shfl((int)pk[0].x, Ls1, 64);
      const int a11 = __shfl((int)pk[0].y, Ls1, 64);
      const int b00 = __shfl((int)pk[1].x, Ls0, 64);
      const int b10 = __shfl((int)pk[1].y, Ls0, 64);
      const int b01 = __shfl((int)pk[1].x, Ls1, 64);
      const int b11 = __shfl((int)pk[1].y, Ls1, 64);
      u32x4 pw;
      pw[0] = (unsigned)(hiq ? b00 : a00);
      pw[1] = (unsigned)(hiq ? b10 : a10);
      pw[2] = (unsigned)(hiq ? b01 : a01);
      pw[3] = (unsigned)(hiq ? b11 : a11);
      const bf16x8 pf = __builtin_bit_cast(bf16x8, pw);
      const bf16x8 xf = *(const bf16x8*)&xsT[fr * 264 + sp * 32 + 8 * g];
      acc = __builtin_amdgcn_mfma_f32_16x16x32_bf16(xf, pf, acc, 0, 0, 0);
    }
    us4v xs4 = *(const us4v*)&xraw[(lt * 16 + fr + 3) * 16 + 4 * g];
    us4v o = { f2bf(acc[0] + Dh * bf2f(xs4[0])),
               f2bf(acc[1] + Dh * bf2f(xs4[1])),
               f2bf(acc[2] + Dh * bf2f(xs4[2])),
               f2bf(acc[3] + Dh * bf2f(xs4[3])) };
    *(us4v*)(YdT + (rhrow - r + (size_t)lt * 16 + fr) * HEADDIM + 4 * g) = o;
  }
#endif
}

// ---------------------------------------------------------------------------
// K4: sequential inter-chunk state recurrence
// ---------------------------------------------------------------------------
__global__ __launch_bounds__(256)
void chunk_scan_kernel(const float* __restrict__ stloc, const float* __restrict__ csum_g,
                       float* __restrict__ stpre) {
  const int b  = blockIdx.x / NHEADS;
  const int h  = blockIdx.x % NHEADS;
  const int pn = threadIdx.x;
  float S = 0.0f;
  for (int c = 0; c < NCHUNKS; ++c) {
    const size_t idx = ((size_t)(b * NCHUNKS + c) * NHEADS + h) * 256 + pn;
    stpre[idx] = S;
    S = __expf(csum_g[(b * NHEADS + h) * NCHUNKS + c]) * S + stloc[idx];
  }
}

// ---------------------------------------------------------------------------
// K5 (fused, 12 waves): Y_off, silu(z) gate, RMSNorm, out = yn @ W_out'^T.
// r30: shuffle-free RMSNorm via Gram-matrix diagonal on the matrix pipe.
// ---------------------------------------------------------------------------
#define TT 16
#define LDY 392
__global__ __launch_bounds__(768)
void yoff_norm_gemm(const unsigned short* __restrict__ YdT,
                    const unsigned short* __restrict__ Co, const float* __restrict__ acum_g,
                    const float* __restrict__ stpre,
                    const unsigned short* __restrict__ zbuf,
                    const unsigned short* __restrict__ Wo,
                    float* __restrict__ out) {
  const int bid  = blockIdx.x;
  const int wz   = (bid & 7) * 128 + (bid >> 3);   // bijective: 1024 % 8 == 0
  const int r0   = wz * TT;
  const int b    = r0 / SEQLEN;
  const int t0   = r0 % SEQLEN;
  const int cidx = t0 / CHUNK;
  const int tid  = threadIdx.x;
  const int d    = tid % 384;
  const int half = tid / 384;
  const int h    = d >> 4, p = d & 15;
  const int wv   = tid >> 6;

  __shared__ unsigned short Yt[NHEADS * TT * 16];
  __shared__ unsigned short zL[TT * 384];
  __shared__ unsigned short ynL[TT * LDY];
  __shared__ float At[NHEADS * TT];
  __shared__ float Ct[TT * 16];

  {
    us8v* Yt8 = (us8v*)Yt;
    int hh = tid >> 5, q = tid & 31;
    const size_t src = ((size_t)(b * NHEADS + hh) * SEQLEN + t0) * HEADDIM + q * 8;
    Yt8[tid] = *(const us8v*)(YdT + src);
    const int zr = tid / 48, zc = (tid % 48) * 8;
    *(us8v*)&zL[zr * 384 + zc] = *(const us8v*)(zbuf + (size_t)(r0 + zr) * 384 + zc);
    if (tid < NHEADS * TT)
      At[tid] = __expf(acum_g[(size_t)(b * NHEADS + (tid >> 4)) * SEQLEN + t0 + (tid & 15)]);
    if (tid < TT * 16) Ct[tid] = bf2f(Co[(size_t)r0 * D_STATE + tid]);
  }

  f32x4 S4[4];
  {
    const float* Sp = stpre + ((size_t)(b * NCHUNKS + cidx) * NHEADS + h) * 256 + p * 16;
#pragma unroll
    for (int q = 0; q < 4; ++q) S4[q] = *(const f32x4*)(Sp + 4 * q);
  }
  __syncthreads();   // #1

  const int tb = half * 8;
#pragma unroll
  for (int ti = 0; ti < 8; ++ti) {
    const int tt = tb + ti;
    const f32x4* C4 = (const f32x4*)&Ct[tt * 16];
    f32x4 d4 = C4[0] * S4[0];
    d4 = d4 + C4[1] * S4[1];
    d4 = d4 + C4[2] * S4[2];
    d4 = d4 + C4[3] * S4[3];
    const float dot = (d4[0] + d4[1]) + (d4[2] + d4[3]);
    const float eA = At[h * TT + tt];
    float y = bf2f(Yt[h * 256 + tt * 16 + p]) + eA * dot;
    const float z = bf2f(zL[tt * 384 + d]);
    ynL[tt * LDY + d] = f2bf(y * silu_f(z));
  }
  __syncthreads();   // #2 (last barrier)

  const int lane = tid & 63;
  const int fr = lane & 15, fq = lane >> 4;
  const int n0 = wv * 16;
  f32x4 accg = {};
  f32x4 gacc = {};
  __builtin_amdgcn_s_setprio(1);
#pragma unroll
  for (int kt = 0; kt < 12; ++kt) {
    const bf16x8 af = *(const bf16x8*)&ynL[fr * LDY + kt * 32 + 8 * fq];
    const bf16x8 bfr = *(const bf16x8*)(Wo + (size_t)(n0 + fr) * D_INNER + kt * 32 + 8 * fq);
    accg = __builtin_amdgcn_mfma_f32_16x16x32_bf16(bfr, af, accg, 0, 0, 0);
    gacc = __builtin_amdgcn_mfma_f32_16x16x32_bf16(af, af, gacc, 0, 0, 0);
  }
  __builtin_amdgcn_s_setprio(0);
  // diag extraction: Gram[fr][fr] lives in lane (fr>>2)*16 + fr, reg fr&3.
  const int j0 = fr & 3;
  float vsel = (j0 == 0) ? gacc[0] : (j0 == 1) ? gacc[1]
             : (j0 == 2) ? gacc[2] : gacc[3];
  const float tot = __shfl(vsel, (fr >> 2) * 16 + fr, 64);
  const float scale = rsqrtf(tot * (1.0f / D_INNER) + EPS);
  float4 o = make_float4(accg[0] * scale, accg[1] * scale,
                         accg[2] * scale, accg[3] * scale);
  *(float4*)(out + (size_t)(r0 + fr) * D_MODEL + n0 + fq * 4) = o;
}

// ---------------------------------------------------------------------------
extern "C" void kernel_launch(void* const* d_in, const int* in_sizes, int n_in,
                              void* d_out, int out_size, void* d_ws, size_t ws_size,
                              hipStream_t stream) {
  const float* u        = (const float*)d_in[0];
  const float* support  = (const float*)d_in[1];
  const float* W_in     = (const float*)d_in[2];
  const float* W_in_b   = (const float*)d_in[3];
  const float* conv_w   = (const float*)d_in[4];
  const float* conv_b   = (const float*)d_in[5];
  const float* conv_w_b = (const float*)d_in[6];
  const float* conv_b_b = (const float*)d_in[7];
  const float* dt_bias  = (const float*)d_in[8];
  const float* A_log    = (const float*)d_in[9];
  const float* Dvec     = (const float*)d_in[10];
  const float* norm_w   = (const float*)d_in[11];
  const float* W_out    = (const float*)d_in[12];
  float* out = (float*)d_out;
  char* wsb  = (char*)d_ws;

  unsigned short* Wi_b  = (unsigned short*)(wsb);
  unsigned short* Wo_b  = Wi_b + (size_t)D_IN_PROJ * D_MODEL;
  unsigned short* Wib_b = Wo_b + (size_t)D_MODEL * D_INNER;
  unsigned short* zbuf  = Wib_b + (size_t)D_STATE * D_MODEL;
  unsigned short* xT    = zbuf + (size_t)ROWS * D_INNER;
  unsigned short* Braw  = xT + (size_t)ROWS * D_INNER;
  unsigned short* draw  = Braw + (size_t)ROWS * D_STATE;
  unsigned short* craw  = draw + (size_t)ROWS * NHEADS;
  unsigned short* Bo    = craw + (size_t)ROWS * D_STATE;
  unsigned short* Co    = Bo + (size_t)ROWS * D_STATE;
  unsigned short* YdT   = Co + (size_t)ROWS * D_STATE;
  float* dtoT  = (float*)(YdT + (size_t)ROWS * D_INNER);
  float* acum  = dtoT  + (size_t)ROWS * NHEADS;
  float* csum  = acum  + (size_t)BATCH * NHEADS * SEQLEN;
  float* stloc = csum  + (size_t)BATCH * NHEADS * NCHUNKS;
  float* stpre = stloc + (size_t)BATCH * NCHUNKS * NHEADS * 256;

  cvt3_kernel<<<224, 256, 0, stream>>>(W_in, Wi_b, (long)D_IN_PROJ * D_MODEL,
                                       W_out, Wo_b, (long)D_MODEL * D_INNER,
                                       W_in_b, Wib_b, (long)D_STATE * D_MODEL,
                                       norm_w);
  gemm_in_merged<<<dim3(8, ROWS / 128), 256, 0, stream>>>(
      u, Wi_b, support, Wib_b, craw, zbuf, xT, Braw, draw);
  conv_bcdt<<<CBC_NB + CDT_NB, 256, 0, stream>>>(
      Braw, craw, draw, conv_w, conv_b, conv_w_b, conv_b_b, dt_bias, Bo, Co, dtoT);
  ssd_mfma_kernel<<<NHEADS * NCHUNKS * BATCH, 512, 0, stream>>>(
      xT, Bo, Co, dtoT, A_log, conv_w, conv_b, Dvec, YdT, acum, csum, stloc);
  chunk_scan_kernel<<<BATCH * NHEADS, 256, 0, stream>>>(stloc, csum, stpre);
  yoff_norm_gemm<<<ROWS / TT, 768, 0, stream>>>(YdT, Co, acum, stpre, zbuf,
                                                Wo_b, out);
}